// Round 1
// baseline (1538.696 us; speedup 1.0000x reference)
//
#include <hip/hip_runtime.h>
#include <math.h>

#define Bsz 4
#define Lseq 1024
#define Dm 256
#define Hh 16
#define HDm 16
#define DIm 512
#define Ssz 64
#define KCm 4
#define DTRm 16

static __device__ __forceinline__ float wave_sum(float v) {
    #pragma unroll
    for (int m = 32; m >= 1; m >>= 1) v += __shfl_xor(v, m, 64);
    return v;
}

// ---------------- LayerNorm ----------------
__global__ __launch_bounds__(256) void ln_kernel(const float* __restrict__ x,
                                                 const float* __restrict__ g,
                                                 const float* __restrict__ b,
                                                 float* __restrict__ xn) {
    int row = blockIdx.x;
    int tid = threadIdx.x;
    __shared__ float red[8];
    float v = x[(size_t)row * Dm + tid];
    float s = wave_sum(v);
    int wid = tid >> 6, lane = tid & 63;
    if (lane == 0) red[wid] = s;
    __syncthreads();
    float mean = (red[0] + red[1] + red[2] + red[3]) * (1.0f / Dm);
    float dv = v - mean;
    float s2 = wave_sum(dv * dv);
    if (lane == 0) red[4 + wid] = s2;
    __syncthreads();
    float var = (red[4] + red[5] + red[6] + red[7]) * (1.0f / Dm);
    float inv = rsqrtf(var + 1e-5f);
    xn[(size_t)row * Dm + tid] = dv * inv * g[tid] + b[tid];
}

// ---------------- avg-pool by 2 along t ----------------
__global__ void halve_kernel(const float* __restrict__ in, float* __restrict__ out, int Lo) {
    int idx = blockIdx.x * blockDim.x + threadIdx.x;
    int total = Bsz * Lo * Dm;
    if (idx >= total) return;
    int d = idx % Dm;
    int j = (idx / Dm) % Lo;
    int b = idx / (Dm * Lo);
    const float* p = in + ((size_t)(b * 2 * Lo + 2 * j) * Dm + d);
    out[idx] = 0.5f * (p[0] + p[Dm]);
}

// ---------------- linear interpolation back to L, write into qcat segment ----------------
__global__ void interp_kernel(const float* __restrict__ qd, float* __restrict__ qcat,
                              int Lin, int seg) {
    int idx = blockIdx.x * blockDim.x + threadIdx.x;
    if (idx >= Bsz * Lseq * Dm) return;
    int d = idx % Dm;
    int t = (idx / Dm) % Lseq;
    int b = idx / (Dm * Lseq);
    float pos = (t + 0.5f) * ((float)Lin / (float)Lseq) - 0.5f;
    pos = fminf(fmaxf(pos, 0.0f), (float)(Lin - 1));
    int lo = (int)floorf(pos);
    int hi = min(lo + 1, Lin - 1);
    float w = pos - (float)lo;
    float v = qd[((size_t)(b * Lin + lo)) * Dm + d] * (1.0f - w)
            + qd[((size_t)(b * Lin + hi)) * Dm + d] * w;
    qcat[((size_t)(b * Lseq + t)) * (4 * Dm) + seg * Dm + d] = v;
}

// ---------------- causal depthwise conv + SiLU ----------------
__global__ void conv_silu_kernel(const float* __restrict__ xz, const float* __restrict__ cw,
                                 const float* __restrict__ cb, float* __restrict__ xc) {
    int idx = blockIdx.x * blockDim.x + threadIdx.x;
    if (idx >= Bsz * Lseq * DIm) return;
    int c = idx % DIm;
    int t = (idx / DIm) % Lseq;
    int b = idx / (DIm * Lseq);
    float acc = cb[c];
    #pragma unroll
    for (int kk = 0; kk < KCm; kk++) {
        int tt = t + kk - (KCm - 1);
        if (tt >= 0) acc += xz[((size_t)(b * Lseq + tt)) * (2 * DIm) + c] * cw[c * KCm + kk];
    }
    xc[idx] = acc / (1.0f + expf(-acc));
}

// ---------------- generic tiled fp32 GEMM: C = A(M,K) * W(N,K)^T + bias ----------------
// A addressed as A[m*lda_m + k*lda_k]  (supports transposed storage for the scan output)
// act: 0 = none, 1 = softplus.  accum: C += result
__global__ __launch_bounds__(256) void gemm_f32(const float* __restrict__ A, int lda_m, int lda_k,
                                                const float* __restrict__ W, int ldw,
                                                const float* __restrict__ bias,
                                                float* __restrict__ C, int ldc,
                                                int M, int N, int K, int act, int accum) {
    __shared__ float As[16][72];
    __shared__ float Ws[16][72];
    int tid = threadIdx.x;
    int m0 = blockIdx.y * 64, n0 = blockIdx.x * 64;
    int tx = tid & 15, ty = tid >> 4;
    float acc[4][4] = {};
    for (int k0 = 0; k0 < K; k0 += 16) {
        if (lda_k == 1) {
            int ml = tid >> 2, kl = (tid & 3) * 4;
            const float4 av = *(const float4*)(A + (size_t)(m0 + ml) * lda_m + k0 + kl);
            As[kl + 0][ml] = av.x; As[kl + 1][ml] = av.y;
            As[kl + 2][ml] = av.z; As[kl + 3][ml] = av.w;
        } else {
            int kl = tid >> 4, ml = (tid & 15) * 4;
            const float4 av = *(const float4*)(A + (size_t)(k0 + kl) * lda_k + (m0 + ml));
            *(float4*)&As[kl][ml] = av;
        }
        {
            int nl = tid >> 2, kl = (tid & 3) * 4;
            float4 wv;
            if (n0 + nl < N) wv = *(const float4*)(W + (size_t)(n0 + nl) * ldw + k0 + kl);
            else wv = make_float4(0.f, 0.f, 0.f, 0.f);
            Ws[kl + 0][nl] = wv.x; Ws[kl + 1][nl] = wv.y;
            Ws[kl + 2][nl] = wv.z; Ws[kl + 3][nl] = wv.w;
        }
        __syncthreads();
        #pragma unroll
        for (int kk = 0; kk < 16; kk++) {
            float4 av = *(const float4*)&As[kk][ty * 4];
            float4 bv = *(const float4*)&Ws[kk][tx * 4];
            float a[4] = {av.x, av.y, av.z, av.w};
            float bb[4] = {bv.x, bv.y, bv.z, bv.w};
            #pragma unroll
            for (int im = 0; im < 4; im++)
                #pragma unroll
                for (int in = 0; in < 4; in++)
                    acc[im][in] = fmaf(a[im], bb[in], acc[im][in]);
        }
        __syncthreads();
    }
    #pragma unroll
    for (int im = 0; im < 4; im++) {
        int m = m0 + ty * 4 + im;
        #pragma unroll
        for (int in = 0; in < 4; in++) {
            int n = n0 + tx * 4 + in;
            if (n >= N) continue;
            float v = acc[im][in];
            if (bias) v += bias[n];
            if (act == 1) v = fmaxf(v, 0.0f) + log1pf(expf(-fabsf(v)));
            float* cp = C + (size_t)m * ldc + n;
            if (accum) v += *cp;
            *cp = v;
        }
    }
}

// ---------------- selective scan: one wave per (b, d) channel, lane = state s ----------------
__global__ __launch_bounds__(256) void scan_kernel(const float* __restrict__ xc,
                                                   const float* __restrict__ dtm,
                                                   const float* __restrict__ xz,
                                                   const float* __restrict__ dbc,
                                                   const float* __restrict__ A_log,
                                                   const float* __restrict__ D_ssm,
                                                   float* __restrict__ yT) {
    int wid = threadIdx.x >> 6, lane = threadIdx.x & 63;
    int ch = blockIdx.x * 4 + wid;    // 0..2047
    int b = ch >> 9, d = ch & (DIm - 1);
    float As = -expf(A_log[d * Ssz + lane]);
    float Dd = D_ssm[d];
    float h = 0.0f, ybuf = 0.0f;
    const float* dbcB = dbc + DTRm;
    const float* dbcC = dbc + DTRm + Ssz;
    for (int t = 0; t < Lseq; t++) {
        size_t base = (size_t)(b * Lseq + t);
        float dtv = dtm[base * DIm + d];
        float xv  = xc[base * DIm + d];
        float zv  = xz[base * (2 * DIm) + DIm + d];
        float Bt  = dbcB[base * 144 + lane];
        float Ct  = dbcC[base * 144 + lane];
        float dA  = expf(dtv * As);
        h = fmaf(dA, h, dtv * xv * Bt);
        float p = wave_sum(h * Ct);
        float yg = (p + xv * Dd) * (zv / (1.0f + expf(-zv)));
        if ((t & 63) == lane) ybuf = yg;
        if ((t & 63) == 63) yT[(size_t)d * 4096 + b * Lseq + (t - 63) + lane] = ybuf;
    }
}

// ---------------- decay-masked attention (analytic denom, no softmax) ----------------
__global__ __launch_bounds__(256) void attn_kernel(const float* __restrict__ q,
                                                   const float* __restrict__ k,
                                                   const float* __restrict__ v,
                                                   const float* __restrict__ log_tau,
                                                   float* __restrict__ out) {
    __shared__ float Ks[128][16];
    __shared__ float Vs[128][16];
    int bh = blockIdx.x >> 2;
    int qc = blockIdx.x & 3;
    int b = bh >> 4, h = bh & 15;
    int i = qc * 256 + threadIdx.x;
    float inv_tau = expf(-log_tau[h]);       // 1/tau
    float qv[16];
    const float* qp = q + ((size_t)(b * Lseq + i)) * Dm + h * HDm;
    #pragma unroll
    for (int j = 0; j < 16; j++) qv[j] = qp[j];
    // denom(i) = (L-1-i) + sum_{d=0..i} r^d,  r = exp(-1/tau)
    float r = expf(-inv_tau);
    float geom;
    if (1.0f - r > 1e-8f) geom = (1.0f - expf(-inv_tau * (float)(i + 1))) / (1.0f - r);
    else geom = (float)(i + 1);
    float denom = fmaxf((float)(Lseq - 1 - i) + geom, 1e-6f);
    float acc[16];
    #pragma unroll
    for (int j = 0; j < 16; j++) acc[j] = 0.0f;
    for (int kc = 0; kc < Lseq; kc += 128) {
        int krow = threadIdx.x >> 1;
        int cb = (threadIdx.x & 1) * 8;
        const float* kp = k + ((size_t)(b * Lseq + kc + krow)) * Dm + h * HDm + cb;
        const float* vp = v + ((size_t)(b * Lseq + kc + krow)) * Dm + h * HDm + cb;
        *(float4*)&Ks[krow][cb]     = *(const float4*)kp;
        *(float4*)&Ks[krow][cb + 4] = *(const float4*)(kp + 4);
        *(float4*)&Vs[krow][cb]     = *(const float4*)vp;
        *(float4*)&Vs[krow][cb + 4] = *(const float4*)(vp + 4);
        __syncthreads();
        for (int kk = 0; kk < 128; kk++) {
            int kg = kc + kk;
            float dot = 0.0f;
            #pragma unroll
            for (int j = 0; j < 16; j++) dot = fmaf(qv[j], Ks[kk][j], dot);
            float w = expf(fminf((float)(kg - i), 0.0f) * inv_tau);
            float dw = dot * w;
            #pragma unroll
            for (int j = 0; j < 16; j++) acc[j] = fmaf(dw, Vs[kk][j], acc[j]);
        }
        __syncthreads();
    }
    float sc = 0.25f / denom;
    float* op = out + ((size_t)(b * Lseq + i)) * Dm + h * HDm;
    #pragma unroll
    for (int j = 0; j < 16; j++) op[j] = acc[j] * sc;
}

// ---------------- gate + residual ----------------
__global__ void final_kernel(const float* __restrict__ x, const float* __restrict__ gpre,
                             const float* __restrict__ ssm, const float* __restrict__ ssd,
                             float* __restrict__ out) {
    int idx = blockIdx.x * blockDim.x + threadIdx.x;
    if (idx >= Bsz * Lseq * Dm) return;
    float g = 1.0f / (1.0f + expf(-gpre[idx]));
    out[idx] = x[idx] + g * ssm[idx] + (1.0f - g) * ssd[idx];
}

extern "C" void kernel_launch(void* const* d_in, const int* in_sizes, int n_in,
                              void* d_out, int out_size, void* d_ws, size_t ws_size,
                              hipStream_t stream) {
    const float* x        = (const float*)d_in[0];
    const float* ln_g     = (const float*)d_in[1];
    const float* ln_b     = (const float*)d_in[2];
    const float* mq_w     = (const float*)d_in[3];
    const float* mq_b     = (const float*)d_in[4];
    const float* fuse_w   = (const float*)d_in[5];
    const float* fuse_b   = (const float*)d_in[6];
    const float* in_proj_w= (const float*)d_in[7];
    const float* conv_w   = (const float*)d_in[8];
    const float* conv_b   = (const float*)d_in[9];
    const float* x_proj_w = (const float*)d_in[10];
    const float* dt_w     = (const float*)d_in[11];
    const float* dt_b     = (const float*)d_in[12];
    const float* A_log    = (const float*)d_in[13];
    const float* D_ssm    = (const float*)d_in[14];
    const float* out_w    = (const float*)d_in[15];
    const float* k_w      = (const float*)d_in[16];
    const float* k_b      = (const float*)d_in[17];
    const float* v_w      = (const float*)d_in[18];
    const float* v_b      = (const float*)d_in[19];
    const float* o_w      = (const float*)d_in[20];
    const float* o_b      = (const float*)d_in[21];
    const float* log_tau  = (const float*)d_in[22];
    const float* gate_w   = (const float*)d_in[23];
    const float* gate_b   = (const float*)d_in[24];
    float* outp = (float*)d_out;

    const int M = Bsz * Lseq;          // 4096
    float* ws = (float*)d_ws;
    size_t off = 0;
    float* xn    = ws + off; off += (size_t)M * Dm;        // 4096*256
    float* xz    = ws + off; off += (size_t)M * 2 * DIm;   // 4096*1024
    float* xc    = ws + off; off += (size_t)M * DIm;       // 4096*512
    float* dbc   = ws + off; off += (size_t)M * 144;
    float* dtm   = ws + off; off += (size_t)M * DIm;
    float* yT    = ws + off; off += (size_t)DIm * M;
    float* xd2   = ws + off; off += (size_t)Bsz * 512 * Dm;
    float* xd4   = ws + off; off += (size_t)Bsz * 256 * Dm;
    float* xd8   = ws + off; off += (size_t)Bsz * 128 * Dm;
    float* qd2   = ws + off; off += (size_t)Bsz * 512 * Dm;
    float* qd4   = ws + off; off += (size_t)Bsz * 256 * Dm;
    float* qd8   = ws + off; off += (size_t)Bsz * 128 * Dm;
    float* qcat  = ws + off; off += (size_t)M * 4 * Dm;
    float* qbuf  = ws + off; off += (size_t)M * Dm;
    float* kmat  = ws + off; off += (size_t)M * Dm;
    float* vmat  = ws + off; off += (size_t)M * Dm;
    float* attn  = ws + off; off += (size_t)M * Dm;
    float* ssm_o = ws + off; off += (size_t)M * Dm;
    float* ssd_o = ws + off; off += (size_t)M * Dm;
    float* gpre  = ws + off; off += (size_t)M * Dm;

    // 1. LayerNorm
    ln_kernel<<<M, 256, 0, stream>>>(x, ln_g, ln_b, xn);

    // 2. in_proj GEMM: xz = xn @ in_proj_w^T   (4096 x 1024, K=256)
    gemm_f32<<<dim3(1024 / 64, M / 64), 256, 0, stream>>>(xn, Dm, 1, in_proj_w, Dm,
        nullptr, xz, 2 * DIm, M, 2 * DIm, Dm, 0, 0);

    // 3. k / v projections
    gemm_f32<<<dim3(4, M / 64), 256, 0, stream>>>(xn, Dm, 1, k_w, Dm, k_b, kmat, Dm, M, Dm, Dm, 0, 0);
    gemm_f32<<<dim3(4, M / 64), 256, 0, stream>>>(xn, Dm, 1, v_w, Dm, v_b, vmat, Dm, M, Dm, Dm, 0, 0);

    // 4. multi-scale: scale-1 projection straight into qcat seg 0
    gemm_f32<<<dim3(4, M / 64), 256, 0, stream>>>(xn, Dm, 1, mq_w, Dm, mq_b, qcat, 4 * Dm, M, Dm, Dm, 0, 0);
    // pooled versions
    halve_kernel<<<(Bsz * 512 * Dm + 255) / 256, 256, 0, stream>>>(xn, xd2, 512);
    halve_kernel<<<(Bsz * 256 * Dm + 255) / 256, 256, 0, stream>>>(xd2, xd4, 256);
    halve_kernel<<<(Bsz * 128 * Dm + 255) / 256, 256, 0, stream>>>(xd4, xd8, 128);
    gemm_f32<<<dim3(4, (Bsz * 512) / 64), 256, 0, stream>>>(xd2, Dm, 1, mq_w + 1 * Dm * Dm, Dm,
        mq_b + 1 * Dm, qd2, Dm, Bsz * 512, Dm, Dm, 0, 0);
    gemm_f32<<<dim3(4, (Bsz * 256) / 64), 256, 0, stream>>>(xd4, Dm, 1, mq_w + 2 * Dm * Dm, Dm,
        mq_b + 2 * Dm, qd4, Dm, Bsz * 256, Dm, Dm, 0, 0);
    gemm_f32<<<dim3(4, (Bsz * 128) / 64), 256, 0, stream>>>(xd8, Dm, 1, mq_w + 3 * Dm * Dm, Dm,
        mq_b + 3 * Dm, qd8, Dm, Bsz * 128, Dm, Dm, 0, 0);
    // interpolate back into qcat segments 1..3
    interp_kernel<<<(M * Dm + 255) / 256, 256, 0, stream>>>(qd2, qcat, 512, 1);
    interp_kernel<<<(M * Dm + 255) / 256, 256, 0, stream>>>(qd4, qcat, 256, 2);
    interp_kernel<<<(M * Dm + 255) / 256, 256, 0, stream>>>(qd8, qcat, 128, 3);
    // fuse GEMM: q = qcat @ fuse_w^T + fuse_b  (K=1024)
    gemm_f32<<<dim3(4, M / 64), 256, 0, stream>>>(qcat, 4 * Dm, 1, fuse_w, 4 * Dm,
        fuse_b, qbuf, Dm, M, Dm, 4 * Dm, 0, 0);

    // 5. causal conv + SiLU
    conv_silu_kernel<<<(M * DIm + 255) / 256, 256, 0, stream>>>(xz, conv_w, conv_b, xc);

    // 6. x_proj GEMM: dbc = xc @ x_proj_w^T  (N=144, K=512)
    gemm_f32<<<dim3((144 + 63) / 64, M / 64), 256, 0, stream>>>(xc, DIm, 1, x_proj_w, DIm,
        nullptr, dbc, 144, M, 144, DIm, 0, 0);

    // 7. dt GEMM + softplus: dtm = softplus(dbc[:, :16] @ dt_w^T + dt_b)
    gemm_f32<<<dim3(DIm / 64, M / 64), 256, 0, stream>>>(dbc, 144, 1, dt_w, DTRm,
        dt_b, dtm, DIm, M, DIm, DTRm, 1, 0);

    // 8. selective scan (fused with D-skip + z-gate), transposed output yT (DI, B*L)
    scan_kernel<<<512, 256, 0, stream>>>(xc, dtm, xz, dbc, A_log, D_ssm, yT);

    // 9. out GEMM: ssm_o = y @ out_w^T  (A transposed storage)
    gemm_f32<<<dim3(4, M / 64), 256, 0, stream>>>(yT, 1, M, out_w, DIm,
        nullptr, ssm_o, Dm, M, Dm, DIm, 0, 0);

    // 10. attention
    attn_kernel<<<Bsz * Hh * 4, 256, 0, stream>>>(qbuf, kmat, vmat, log_tau, attn);

    // 11. o GEMM
    gemm_f32<<<dim3(4, M / 64), 256, 0, stream>>>(attn, Dm, 1, o_w, Dm, o_b, ssd_o, Dm, M, Dm, Dm, 0, 0);

    // 12. gate GEMMs: gpre = ssm_o @ gw[:, :256]^T + gate_b ; gpre += ssd_o @ gw[:, 256:]^T
    gemm_f32<<<dim3(4, M / 64), 256, 0, stream>>>(ssm_o, Dm, 1, gate_w, 2 * Dm,
        gate_b, gpre, Dm, M, Dm, Dm, 0, 0);
    gemm_f32<<<dim3(4, M / 64), 256, 0, stream>>>(ssd_o, Dm, 1, gate_w + Dm, 2 * Dm,
        nullptr, gpre, Dm, M, Dm, Dm, 0, 1);

    // 13. sigmoid gate + residual
    final_kernel<<<(M * Dm + 255) / 256, 256, 0, stream>>>(x, gpre, ssm_o, ssd_o, outp);
}

// Round 2
// 898.325 us; speedup vs baseline: 1.7128x; 1.7128x over previous
//
#include <hip/hip_runtime.h>
#include <math.h>

#define Bsz 4
#define Lseq 1024
#define Dm 256
#define Hh 16
#define HDm 16
#define DIm 512
#define Ssz 64
#define KCm 4
#define DTRm 16
#define NCH (Bsz * DIm)      // 2048 channels
#define CHK 64               // chunk length
#define NCHK (Lseq / CHK)    // 16 chunks

static __device__ __forceinline__ float wave_sum(float v) {
    #pragma unroll
    for (int m = 32; m >= 1; m >>= 1) v += __shfl_xor(v, m, 64);
    return v;
}

// ---------------- LayerNorm ----------------
__global__ __launch_bounds__(256) void ln_kernel(const float* __restrict__ x,
                                                 const float* __restrict__ g,
                                                 const float* __restrict__ b,
                                                 float* __restrict__ xn) {
    int row = blockIdx.x;
    int tid = threadIdx.x;
    __shared__ float red[8];
    float v = x[(size_t)row * Dm + tid];
    float s = wave_sum(v);
    int wid = tid >> 6, lane = tid & 63;
    if (lane == 0) red[wid] = s;
    __syncthreads();
    float mean = (red[0] + red[1] + red[2] + red[3]) * (1.0f / Dm);
    float dv = v - mean;
    float s2 = wave_sum(dv * dv);
    if (lane == 0) red[4 + wid] = s2;
    __syncthreads();
    float var = (red[4] + red[5] + red[6] + red[7]) * (1.0f / Dm);
    float inv = rsqrtf(var + 1e-5f);
    xn[(size_t)row * Dm + tid] = dv * inv * g[tid] + b[tid];
}

// ---------------- avg-pool by 2 along t ----------------
__global__ void halve_kernel(const float* __restrict__ in, float* __restrict__ out, int Lo) {
    int idx = blockIdx.x * blockDim.x + threadIdx.x;
    int total = Bsz * Lo * Dm;
    if (idx >= total) return;
    int d = idx % Dm;
    int j = (idx / Dm) % Lo;
    int b = idx / (Dm * Lo);
    const float* p = in + ((size_t)(b * 2 * Lo + 2 * j) * Dm + d);
    out[idx] = 0.5f * (p[0] + p[Dm]);
}

// ---------------- linear interpolation back to L, write into qcat segment ----------------
__global__ void interp_kernel(const float* __restrict__ qd, float* __restrict__ qcat,
                              int Lin, int seg) {
    int idx = blockIdx.x * blockDim.x + threadIdx.x;
    if (idx >= Bsz * Lseq * Dm) return;
    int d = idx % Dm;
    int t = (idx / Dm) % Lseq;
    int b = idx / (Dm * Lseq);
    float pos = (t + 0.5f) * ((float)Lin / (float)Lseq) - 0.5f;
    pos = fminf(fmaxf(pos, 0.0f), (float)(Lin - 1));
    int lo = (int)floorf(pos);
    int hi = min(lo + 1, Lin - 1);
    float w = pos - (float)lo;
    float v = qd[((size_t)(b * Lin + lo)) * Dm + d] * (1.0f - w)
            + qd[((size_t)(b * Lin + hi)) * Dm + d] * w;
    qcat[((size_t)(b * Lseq + t)) * (4 * Dm) + seg * Dm + d] = v;
}

// ---------------- causal depthwise conv + SiLU ----------------
__global__ void conv_silu_kernel(const float* __restrict__ xz, const float* __restrict__ cw,
                                 const float* __restrict__ cb, float* __restrict__ xc) {
    int idx = blockIdx.x * blockDim.x + threadIdx.x;
    if (idx >= Bsz * Lseq * DIm) return;
    int c = idx % DIm;
    int t = (idx / DIm) % Lseq;
    int b = idx / (DIm * Lseq);
    float acc = cb[c];
    #pragma unroll
    for (int kk = 0; kk < KCm; kk++) {
        int tt = t + kk - (KCm - 1);
        if (tt >= 0) acc += xz[((size_t)(b * Lseq + tt)) * (2 * DIm) + c] * cw[c * KCm + kk];
    }
    xc[idx] = acc / (1.0f + expf(-acc));
}

// ---------------- generic tiled fp32 GEMM: C = A(M,K) * W(N,K)^T + bias ----------------
__global__ __launch_bounds__(256) void gemm_f32(const float* __restrict__ A, int lda_m, int lda_k,
                                                const float* __restrict__ W, int ldw,
                                                const float* __restrict__ bias,
                                                float* __restrict__ C, int ldc,
                                                int M, int N, int K, int act, int accum) {
    __shared__ float As[16][72];
    __shared__ float Ws[16][72];
    int tid = threadIdx.x;
    int m0 = blockIdx.y * 64, n0 = blockIdx.x * 64;
    int tx = tid & 15, ty = tid >> 4;
    float acc[4][4] = {};
    for (int k0 = 0; k0 < K; k0 += 16) {
        if (lda_k == 1) {
            int ml = tid >> 2, kl = (tid & 3) * 4;
            const float4 av = *(const float4*)(A + (size_t)(m0 + ml) * lda_m + k0 + kl);
            As[kl + 0][ml] = av.x; As[kl + 1][ml] = av.y;
            As[kl + 2][ml] = av.z; As[kl + 3][ml] = av.w;
        } else {
            int kl = tid >> 4, ml = (tid & 15) * 4;
            const float4 av = *(const float4*)(A + (size_t)(k0 + kl) * lda_k + (m0 + ml));
            *(float4*)&As[kl][ml] = av;
        }
        {
            int nl = tid >> 2, kl = (tid & 3) * 4;
            float4 wv;
            if (n0 + nl < N) wv = *(const float4*)(W + (size_t)(n0 + nl) * ldw + k0 + kl);
            else wv = make_float4(0.f, 0.f, 0.f, 0.f);
            Ws[kl + 0][nl] = wv.x; Ws[kl + 1][nl] = wv.y;
            Ws[kl + 2][nl] = wv.z; Ws[kl + 3][nl] = wv.w;
        }
        __syncthreads();
        #pragma unroll
        for (int kk = 0; kk < 16; kk++) {
            float4 av = *(const float4*)&As[kk][ty * 4];
            float4 bv = *(const float4*)&Ws[kk][tx * 4];
            float a[4] = {av.x, av.y, av.z, av.w};
            float bb[4] = {bv.x, bv.y, bv.z, bv.w};
            #pragma unroll
            for (int im = 0; im < 4; im++)
                #pragma unroll
                for (int in = 0; in < 4; in++)
                    acc[im][in] = fmaf(a[im], bb[in], acc[im][in]);
        }
        __syncthreads();
    }
    #pragma unroll
    for (int im = 0; im < 4; im++) {
        int m = m0 + ty * 4 + im;
        #pragma unroll
        for (int in = 0; in < 4; in++) {
            int n = n0 + tx * 4 + in;
            if (n >= N) continue;
            float v = acc[im][in];
            if (bias) v += bias[n];
            if (act == 1) v = fmaxf(v, 0.0f) + log1pf(expf(-fabsf(v)));
            float* cp = C + (size_t)m * ldc + n;
            if (accum) v += *cp;
            *cp = v;
        }
    }
}

// ======== chunk-parallel selective scan ========
// Pass 1: per (channel, chunk) wave, scan 64 steps from h=0; emit h_loc and P=prod(dA).
__global__ __launch_bounds__(256) void scan_pass1(const float* __restrict__ xc,
                                                  const float* __restrict__ dtm,
                                                  const float* __restrict__ dbc,
                                                  const float* __restrict__ A_log,
                                                  float* __restrict__ hloc,
                                                  float* __restrict__ Pc) {
    int wave = blockIdx.x * 4 + (threadIdx.x >> 6);   // 0..32767
    int lane = threadIdx.x & 63;
    int ch = wave & (NCH - 1);                        // channel varies fastest (L2 reuse)
    int c  = wave >> 11;                              // chunk
    int b = ch >> 9, d = ch & (DIm - 1);
    float As = -expf(A_log[d * Ssz + lane]);
    int t0 = c * CHK;
    const float* dtp = dtm + (size_t)(b * Lseq + t0) * DIm + d;
    const float* xp  = xc  + (size_t)(b * Lseq + t0) * DIm + d;
    const float* Bp  = dbc + (size_t)(b * Lseq + t0) * 144 + DTRm + lane;
    float h = 0.0f, P = 1.0f;
    #pragma unroll 4
    for (int t = 0; t < CHK; t++) {
        float dtv = *dtp; dtp += DIm;
        float xv  = *xp;  xp  += DIm;
        float Bt  = *Bp;  Bp  += 144;
        float dA = expf(dtv * As);
        h = fmaf(dA, h, dtv * xv * Bt);
        P *= dA;
    }
    size_t o = ((size_t)ch * NCHK + c) * Ssz + lane;
    hloc[o] = h;
    Pc[o] = P;
}

// Pass 2: combine 16 chunks per channel -> initial state per chunk.
__global__ __launch_bounds__(256) void scan_combine(const float* __restrict__ hloc,
                                                    const float* __restrict__ Pc,
                                                    float* __restrict__ Hinit) {
    int wave = blockIdx.x * 4 + (threadIdx.x >> 6);   // 0..2047
    int lane = threadIdx.x & 63;
    size_t base = (size_t)wave * NCHK * Ssz + lane;
    float H = 0.0f;
    #pragma unroll
    for (int c = 0; c < NCHK; c++) {
        size_t o = base + (size_t)c * Ssz;
        Hinit[o] = H;
        H = fmaf(Pc[o], H, hloc[o]);
    }
}

// Pass 3: re-scan each chunk from Hinit, emit y (fused D-skip + z-gate), transposed store.
__global__ __launch_bounds__(256) void scan_pass3(const float* __restrict__ xc,
                                                  const float* __restrict__ dtm,
                                                  const float* __restrict__ xz,
                                                  const float* __restrict__ dbc,
                                                  const float* __restrict__ A_log,
                                                  const float* __restrict__ D_ssm,
                                                  const float* __restrict__ Hinit,
                                                  float* __restrict__ yT) {
    int wave = blockIdx.x * 4 + (threadIdx.x >> 6);   // 0..32767
    int lane = threadIdx.x & 63;
    int ch = wave & (NCH - 1);
    int c  = wave >> 11;
    int b = ch >> 9, d = ch & (DIm - 1);
    float As = -expf(A_log[d * Ssz + lane]);
    float Dd = D_ssm[d];
    int t0 = c * CHK;
    const float* dtp = dtm + (size_t)(b * Lseq + t0) * DIm + d;
    const float* xp  = xc  + (size_t)(b * Lseq + t0) * DIm + d;
    const float* zp  = xz  + (size_t)(b * Lseq + t0) * (2 * DIm) + DIm + d;
    const float* Bp  = dbc + (size_t)(b * Lseq + t0) * 144 + DTRm + lane;
    const float* Cp  = Bp + Ssz;
    float h = Hinit[((size_t)ch * NCHK + c) * Ssz + lane];
    float ybuf = 0.0f;
    #pragma unroll 4
    for (int tb = 0; tb < CHK / 4; tb++) {
        float hc[4], xvv[4], zvv[4];
        #pragma unroll
        for (int j = 0; j < 4; j++) {
            float dtv = *dtp; dtp += DIm;
            float xv  = *xp;  xp  += DIm;
            float zv  = *zp;  zp  += 2 * DIm;
            float Bt  = *Bp;  Bp  += 144;
            float Ct  = *Cp;  Cp  += 144;
            float dA = expf(dtv * As);
            h = fmaf(dA, h, dtv * xv * Bt);
            hc[j] = h * Ct;
            xvv[j] = xv; zvv[j] = zv;
        }
        // 4 independent butterfly reductions, interleaved for ILP on the shuffle chain
        #pragma unroll
        for (int m = 32; m >= 1; m >>= 1) {
            #pragma unroll
            for (int j = 0; j < 4; j++) hc[j] += __shfl_xor(hc[j], m, 64);
        }
        #pragma unroll
        for (int j = 0; j < 4; j++) {
            float yg = (hc[j] + xvv[j] * Dd) * (zvv[j] / (1.0f + expf(-zvv[j])));
            if (lane == tb * 4 + j) ybuf = yg;
        }
    }
    yT[(size_t)d * (Bsz * Lseq) + b * Lseq + t0 + lane] = ybuf;
}

// ---------------- decay-masked attention (analytic denom, no softmax) ----------------
__global__ __launch_bounds__(256) void attn_kernel(const float* __restrict__ q,
                                                   const float* __restrict__ k,
                                                   const float* __restrict__ v,
                                                   const float* __restrict__ log_tau,
                                                   float* __restrict__ out) {
    __shared__ float Ks[128][16];
    __shared__ float Vs[128][16];
    int bh = blockIdx.x >> 2;
    int qc = blockIdx.x & 3;
    int b = bh >> 4, h = bh & 15;
    int i = qc * 256 + threadIdx.x;
    float inv_tau = expf(-log_tau[h]);       // 1/tau
    float qv[16];
    const float* qp = q + ((size_t)(b * Lseq + i)) * Dm + h * HDm;
    #pragma unroll
    for (int j = 0; j < 16; j++) qv[j] = qp[j];
    float r = expf(-inv_tau);
    float geom;
    if (1.0f - r > 1e-8f) geom = (1.0f - expf(-inv_tau * (float)(i + 1))) / (1.0f - r);
    else geom = (float)(i + 1);
    float denom = fmaxf((float)(Lseq - 1 - i) + geom, 1e-6f);
    float acc[16];
    #pragma unroll
    for (int j = 0; j < 16; j++) acc[j] = 0.0f;
    for (int kc = 0; kc < Lseq; kc += 128) {
        int krow = threadIdx.x >> 1;
        int cb = (threadIdx.x & 1) * 8;
        const float* kp = k + ((size_t)(b * Lseq + kc + krow)) * Dm + h * HDm + cb;
        const float* vp = v + ((size_t)(b * Lseq + kc + krow)) * Dm + h * HDm + cb;
        *(float4*)&Ks[krow][cb]     = *(const float4*)kp;
        *(float4*)&Ks[krow][cb + 4] = *(const float4*)(kp + 4);
        *(float4*)&Vs[krow][cb]     = *(const float4*)vp;
        *(float4*)&Vs[krow][cb + 4] = *(const float4*)(vp + 4);
        __syncthreads();
        for (int kk = 0; kk < 128; kk++) {
            int kg = kc + kk;
            float dot = 0.0f;
            #pragma unroll
            for (int j = 0; j < 16; j++) dot = fmaf(qv[j], Ks[kk][j], dot);
            float w = expf(fminf((float)(kg - i), 0.0f) * inv_tau);
            float dw = dot * w;
            #pragma unroll
            for (int j = 0; j < 16; j++) acc[j] = fmaf(dw, Vs[kk][j], acc[j]);
        }
        __syncthreads();
    }
    float sc = 0.25f / denom;
    float* op = out + ((size_t)(b * Lseq + i)) * Dm + h * HDm;
    #pragma unroll
    for (int j = 0; j < 16; j++) op[j] = acc[j] * sc;
}

// ---------------- gate + residual ----------------
__global__ void final_kernel(const float* __restrict__ x, const float* __restrict__ gpre,
                             const float* __restrict__ ssm, const float* __restrict__ ssd,
                             float* __restrict__ out) {
    int idx = blockIdx.x * blockDim.x + threadIdx.x;
    if (idx >= Bsz * Lseq * Dm) return;
    float g = 1.0f / (1.0f + expf(-gpre[idx]));
    out[idx] = x[idx] + g * ssm[idx] + (1.0f - g) * ssd[idx];
}

extern "C" void kernel_launch(void* const* d_in, const int* in_sizes, int n_in,
                              void* d_out, int out_size, void* d_ws, size_t ws_size,
                              hipStream_t stream) {
    const float* x        = (const float*)d_in[0];
    const float* ln_g     = (const float*)d_in[1];
    const float* ln_b     = (const float*)d_in[2];
    const float* mq_w     = (const float*)d_in[3];
    const float* mq_b     = (const float*)d_in[4];
    const float* fuse_w   = (const float*)d_in[5];
    const float* fuse_b   = (const float*)d_in[6];
    const float* in_proj_w= (const float*)d_in[7];
    const float* conv_w   = (const float*)d_in[8];
    const float* conv_b   = (const float*)d_in[9];
    const float* x_proj_w = (const float*)d_in[10];
    const float* dt_w     = (const float*)d_in[11];
    const float* dt_b     = (const float*)d_in[12];
    const float* A_log    = (const float*)d_in[13];
    const float* D_ssm    = (const float*)d_in[14];
    const float* out_w    = (const float*)d_in[15];
    const float* k_w      = (const float*)d_in[16];
    const float* k_b      = (const float*)d_in[17];
    const float* v_w      = (const float*)d_in[18];
    const float* v_b      = (const float*)d_in[19];
    const float* o_w      = (const float*)d_in[20];
    const float* o_b      = (const float*)d_in[21];
    const float* log_tau  = (const float*)d_in[22];
    const float* gate_w   = (const float*)d_in[23];
    const float* gate_b   = (const float*)d_in[24];
    float* outp = (float*)d_out;

    const int M = Bsz * Lseq;          // 4096
    float* ws = (float*)d_ws;
    size_t off = 0;
    float* xn    = ws + off; off += (size_t)M * Dm;
    float* xz    = ws + off; off += (size_t)M * 2 * DIm;
    float* xc    = ws + off; off += (size_t)M * DIm;
    float* dbc   = ws + off; off += (size_t)M * 144;
    float* dtm   = ws + off; off += (size_t)M * DIm;
    float* yT    = ws + off; off += (size_t)DIm * M;
    float* xd2   = ws + off; off += (size_t)Bsz * 512 * Dm;
    float* xd4   = ws + off; off += (size_t)Bsz * 256 * Dm;
    float* xd8   = ws + off; off += (size_t)Bsz * 128 * Dm;
    float* qd2   = ws + off; off += (size_t)Bsz * 512 * Dm;
    float* qd4   = ws + off; off += (size_t)Bsz * 256 * Dm;
    float* qd8   = ws + off; off += (size_t)Bsz * 128 * Dm;
    float* qcat  = ws + off; off += (size_t)M * 4 * Dm;   // reused: hloc + Pc after fuse GEMM
    float* qbuf  = ws + off; off += (size_t)M * Dm;       // reused (w/ kmat): Hinit after attn
    float* kmat  = ws + off; off += (size_t)M * Dm;
    float* vmat  = ws + off; off += (size_t)M * Dm;
    float* attn  = ws + off; off += (size_t)M * Dm;
    float* ssm_o = ws + off; off += (size_t)M * Dm;
    float* ssd_o = ws + off; off += (size_t)M * Dm;
    float* gpre  = ws + off; off += (size_t)M * Dm;

    // 1. LayerNorm
    ln_kernel<<<M, 256, 0, stream>>>(x, ln_g, ln_b, xn);

    // 2. in_proj GEMM
    gemm_f32<<<dim3(1024 / 64, M / 64), 256, 0, stream>>>(xn, Dm, 1, in_proj_w, Dm,
        nullptr, xz, 2 * DIm, M, 2 * DIm, Dm, 0, 0);

    // 3. k / v projections
    gemm_f32<<<dim3(4, M / 64), 256, 0, stream>>>(xn, Dm, 1, k_w, Dm, k_b, kmat, Dm, M, Dm, Dm, 0, 0);
    gemm_f32<<<dim3(4, M / 64), 256, 0, stream>>>(xn, Dm, 1, v_w, Dm, v_b, vmat, Dm, M, Dm, Dm, 0, 0);

    // 4. multi-scale q
    gemm_f32<<<dim3(4, M / 64), 256, 0, stream>>>(xn, Dm, 1, mq_w, Dm, mq_b, qcat, 4 * Dm, M, Dm, Dm, 0, 0);
    halve_kernel<<<(Bsz * 512 * Dm + 255) / 256, 256, 0, stream>>>(xn, xd2, 512);
    halve_kernel<<<(Bsz * 256 * Dm + 255) / 256, 256, 0, stream>>>(xd2, xd4, 256);
    halve_kernel<<<(Bsz * 128 * Dm + 255) / 256, 256, 0, stream>>>(xd4, xd8, 128);
    gemm_f32<<<dim3(4, (Bsz * 512) / 64), 256, 0, stream>>>(xd2, Dm, 1, mq_w + 1 * Dm * Dm, Dm,
        mq_b + 1 * Dm, qd2, Dm, Bsz * 512, Dm, Dm, 0, 0);
    gemm_f32<<<dim3(4, (Bsz * 256) / 64), 256, 0, stream>>>(xd4, Dm, 1, mq_w + 2 * Dm * Dm, Dm,
        mq_b + 2 * Dm, qd4, Dm, Bsz * 256, Dm, Dm, 0, 0);
    gemm_f32<<<dim3(4, (Bsz * 128) / 64), 256, 0, stream>>>(xd8, Dm, 1, mq_w + 3 * Dm * Dm, Dm,
        mq_b + 3 * Dm, qd8, Dm, Bsz * 128, Dm, Dm, 0, 0);
    interp_kernel<<<(M * Dm + 255) / 256, 256, 0, stream>>>(qd2, qcat, 512, 1);
    interp_kernel<<<(M * Dm + 255) / 256, 256, 0, stream>>>(qd4, qcat, 256, 2);
    interp_kernel<<<(M * Dm + 255) / 256, 256, 0, stream>>>(qd8, qcat, 128, 3);
    gemm_f32<<<dim3(4, M / 64), 256, 0, stream>>>(qcat, 4 * Dm, 1, fuse_w, 4 * Dm,
        fuse_b, qbuf, Dm, M, Dm, 4 * Dm, 0, 0);

    // 5. causal conv + SiLU
    conv_silu_kernel<<<(M * DIm + 255) / 256, 256, 0, stream>>>(xz, conv_w, conv_b, xc);

    // 6. x_proj GEMM
    gemm_f32<<<dim3((144 + 63) / 64, M / 64), 256, 0, stream>>>(xc, DIm, 1, x_proj_w, DIm,
        nullptr, dbc, 144, M, 144, DIm, 0, 0);

    // 7. dt GEMM + softplus
    gemm_f32<<<dim3(DIm / 64, M / 64), 256, 0, stream>>>(dbc, 144, 1, dt_w, DTRm,
        dt_b, dtm, DIm, M, DIm, DTRm, 1, 0);

    // 8. attention FIRST (frees qbuf/qcat regions for scan scratch)
    attn_kernel<<<Bsz * Hh * 4, 256, 0, stream>>>(qbuf, kmat, vmat, log_tau, attn);
    gemm_f32<<<dim3(4, M / 64), 256, 0, stream>>>(attn, Dm, 1, o_w, Dm, o_b, ssd_o, Dm, M, Dm, Dm, 0, 0);

    // 9. chunk-parallel selective scan (scratch reuses qcat + qbuf/kmat)
    float* hloc  = qcat;                                   // NCH*NCHK*64 = 2M floats
    float* Pc    = qcat + (size_t)NCH * NCHK * Ssz;        // 2M floats (qcat holds 4M)
    float* Hinit = qbuf;                                   // 2M floats (qbuf+kmat)
    scan_pass1<<<(NCH * NCHK) / 4, 256, 0, stream>>>(xc, dtm, dbc, A_log, hloc, Pc);
    scan_combine<<<NCH / 4, 256, 0, stream>>>(hloc, Pc, Hinit);
    scan_pass3<<<(NCH * NCHK) / 4, 256, 0, stream>>>(xc, dtm, xz, dbc, A_log, D_ssm, Hinit, yT);

    // 10. out GEMM (A transposed storage)
    gemm_f32<<<dim3(4, M / 64), 256, 0, stream>>>(yT, 1, M, out_w, DIm,
        nullptr, ssm_o, Dm, M, Dm, DIm, 0, 0);

    // 11. gate GEMMs
    gemm_f32<<<dim3(4, M / 64), 256, 0, stream>>>(ssm_o, Dm, 1, gate_w, 2 * Dm,
        gate_b, gpre, Dm, M, Dm, Dm, 0, 0);
    gemm_f32<<<dim3(4, M / 64), 256, 0, stream>>>(ssd_o, Dm, 1, gate_w + Dm, 2 * Dm,
        nullptr, gpre, Dm, M, Dm, Dm, 0, 1);

    // 12. sigmoid gate + residual
    final_kernel<<<(M * Dm + 255) / 256, 256, 0, stream>>>(x, gpre, ssm_o, ssd_o, outp);
}

// Round 3
// 663.518 us; speedup vs baseline: 2.3190x; 1.3539x over previous
//
#include <hip/hip_runtime.h>
#include <math.h>

#define Bsz 4
#define Lseq 1024
#define Dm 256
#define Hh 16
#define HDm 16
#define DIm 512
#define Ssz 64
#define KCm 4
#define DTRm 16
#define NCH (Bsz * DIm)      // 2048 channels
#define CHK 64               // chunk length
#define NCHK (Lseq / CHK)    // 16 chunks

typedef __attribute__((ext_vector_type(8))) short s8v;
typedef __attribute__((ext_vector_type(4))) float f4v;

static __device__ __forceinline__ float wave_sum(float v) {
    #pragma unroll
    for (int m = 32; m >= 1; m >>= 1) v += __shfl_xor(v, m, 64);
    return v;
}

static __device__ __forceinline__ short f2bf(float f) {
    unsigned int u = __float_as_uint(f);
    u = (u + 0x7fffu + ((u >> 16) & 1u)) >> 16;
    return (short)u;
}

static __device__ __forceinline__ s8v pack8(float4 a, float4 b) {
    s8v v;
    v[0] = f2bf(a.x); v[1] = f2bf(a.y); v[2] = f2bf(a.z); v[3] = f2bf(a.w);
    v[4] = f2bf(b.x); v[5] = f2bf(b.y); v[6] = f2bf(b.z); v[7] = f2bf(b.w);
    return v;
}

// ---------------- LayerNorm ----------------
__global__ __launch_bounds__(256) void ln_kernel(const float* __restrict__ x,
                                                 const float* __restrict__ g,
                                                 const float* __restrict__ b,
                                                 float* __restrict__ xn) {
    int row = blockIdx.x;
    int tid = threadIdx.x;
    __shared__ float red[8];
    float v = x[(size_t)row * Dm + tid];
    float s = wave_sum(v);
    int wid = tid >> 6, lane = tid & 63;
    if (lane == 0) red[wid] = s;
    __syncthreads();
    float mean = (red[0] + red[1] + red[2] + red[3]) * (1.0f / Dm);
    float dv = v - mean;
    float s2 = wave_sum(dv * dv);
    if (lane == 0) red[4 + wid] = s2;
    __syncthreads();
    float var = (red[4] + red[5] + red[6] + red[7]) * (1.0f / Dm);
    float inv = rsqrtf(var + 1e-5f);
    xn[(size_t)row * Dm + tid] = dv * inv * g[tid] + b[tid];
}

// ---------------- avg-pool by 2 along t ----------------
__global__ void halve_kernel(const float* __restrict__ in, float* __restrict__ out, int Lo) {
    int idx = blockIdx.x * blockDim.x + threadIdx.x;
    int total = Bsz * Lo * Dm;
    if (idx >= total) return;
    int d = idx % Dm;
    int j = (idx / Dm) % Lo;
    int b = idx / (Dm * Lo);
    const float* p = in + ((size_t)(b * 2 * Lo + 2 * j) * Dm + d);
    out[idx] = 0.5f * (p[0] + p[Dm]);
}

// ---------------- linear interpolation back to L ----------------
__global__ void interp_kernel(const float* __restrict__ qd, float* __restrict__ qcat,
                              int Lin, int seg) {
    int idx = blockIdx.x * blockDim.x + threadIdx.x;
    if (idx >= Bsz * Lseq * Dm) return;
    int d = idx % Dm;
    int t = (idx / Dm) % Lseq;
    int b = idx / (Dm * Lseq);
    float pos = (t + 0.5f) * ((float)Lin / (float)Lseq) - 0.5f;
    pos = fminf(fmaxf(pos, 0.0f), (float)(Lin - 1));
    int lo = (int)floorf(pos);
    int hi = min(lo + 1, Lin - 1);
    float w = pos - (float)lo;
    float v = qd[((size_t)(b * Lin + lo)) * Dm + d] * (1.0f - w)
            + qd[((size_t)(b * Lin + hi)) * Dm + d] * w;
    qcat[((size_t)(b * Lseq + t)) * (4 * Dm) + seg * Dm + d] = v;
}

// ---------------- causal depthwise conv + SiLU ----------------
__global__ void conv_silu_kernel(const float* __restrict__ xz, const float* __restrict__ cw,
                                 const float* __restrict__ cb, float* __restrict__ xc) {
    int idx = blockIdx.x * blockDim.x + threadIdx.x;
    if (idx >= Bsz * Lseq * DIm) return;
    int c = idx % DIm;
    int t = (idx / DIm) % Lseq;
    int b = idx / (DIm * Lseq);
    float acc = cb[c];
    #pragma unroll
    for (int kk = 0; kk < KCm; kk++) {
        int tt = t + kk - (KCm - 1);
        if (tt >= 0) acc += xz[((size_t)(b * Lseq + tt)) * (2 * DIm) + c] * cw[c * KCm + kk];
    }
    xc[idx] = acc / (1.0f + __expf(-acc));
}

// ======= bf16 MFMA GEMM: C = A(M,K) * W(N,K)^T + bias =======
// A fp32 addressed A[m*lda_m + k*lda_k]; converted RNE to bf16 during LDS staging.
// K must be a multiple of 32, M a multiple of 64. N guarded.
__global__ __launch_bounds__(256) void gemm_bf16(const float* __restrict__ A, int lda_m, int lda_k,
                                                 const float* __restrict__ W, int ldw,
                                                 const float* __restrict__ bias,
                                                 float* __restrict__ C, int ldc,
                                                 int M, int N, int K, int accum) {
    __shared__ unsigned short As[64][40];   // pad to 40 (80B rows, 16B aligned)
    __shared__ unsigned short Ws[64][40];
    int tid = threadIdx.x;
    int wave = tid >> 6, lane = tid & 63;
    int quad = lane >> 4, r = lane & 15;
    int m0 = blockIdx.y * 64, n0 = blockIdx.x * 64;
    int mo = (wave >> 1) * 32, no = (wave & 1) * 32;
    f4v acc[2][2];
    #pragma unroll
    for (int i = 0; i < 2; i++)
        #pragma unroll
        for (int j = 0; j < 2; j++) acc[i][j] = (f4v){0.f, 0.f, 0.f, 0.f};

    for (int k0 = 0; k0 < K; k0 += 32) {
        // ---- stage A tile (64 x 32) ----
        if (lda_k == 1) {
            int m = tid >> 2, kk = (tid & 3) * 8;
            const float* ap = A + (size_t)(m0 + m) * lda_m + k0 + kk;
            float4 a0 = *(const float4*)ap;
            float4 a1 = *(const float4*)(ap + 4);
            *(s8v*)&As[m][kk] = pack8(a0, a1);
        } else {
            int k = tid >> 3, m8 = (tid & 7) * 8;
            const float* ap = A + (size_t)(k0 + k) * lda_k + m0 + m8;
            float4 a0 = *(const float4*)ap;
            float4 a1 = *(const float4*)(ap + 4);
            float av[8] = {a0.x, a0.y, a0.z, a0.w, a1.x, a1.y, a1.z, a1.w};
            #pragma unroll
            for (int i = 0; i < 8; i++) As[m8 + i][k] = (unsigned short)f2bf(av[i]);
        }
        // ---- stage W tile (64 x 32) with N guard ----
        {
            int n = tid >> 2, kk = (tid & 3) * 8;
            s8v pv;
            if (n0 + n < N) {
                const float* wp = W + (size_t)(n0 + n) * ldw + k0 + kk;
                float4 w0 = *(const float4*)wp;
                float4 w1 = *(const float4*)(wp + 4);
                pv = pack8(w0, w1);
            } else {
                pv = (s8v){0, 0, 0, 0, 0, 0, 0, 0};
            }
            *(s8v*)&Ws[n][kk] = pv;
        }
        __syncthreads();
        s8v af[2], bf[2];
        #pragma unroll
        for (int i = 0; i < 2; i++) af[i] = *(const s8v*)&As[mo + i * 16 + r][quad * 8];
        #pragma unroll
        for (int j = 0; j < 2; j++) bf[j] = *(const s8v*)&Ws[no + j * 16 + r][quad * 8];
        #pragma unroll
        for (int i = 0; i < 2; i++)
            #pragma unroll
            for (int j = 0; j < 2; j++)
                acc[i][j] = __builtin_amdgcn_mfma_f32_16x16x32_bf16(af[i], bf[j], acc[i][j], 0, 0, 0);
        __syncthreads();
    }
    // ---- epilogue: D layout col=lane&15, row=quad*4+reg ----
    #pragma unroll
    for (int i = 0; i < 2; i++)
        #pragma unroll
        for (int j = 0; j < 2; j++)
            #pragma unroll
            for (int reg = 0; reg < 4; reg++) {
                int m = m0 + mo + i * 16 + quad * 4 + reg;
                int n = n0 + no + j * 16 + r;
                if (n >= N) continue;
                float v = acc[i][j][reg];
                if (bias) v += bias[n];
                float* cp = C + (size_t)m * ldc + n;
                if (accum) v += *cp;
                *cp = v;
            }
}

// ---------------- small fp32 GEMM (K=16 dt projection) ----------------
__global__ __launch_bounds__(256) void gemm_f32(const float* __restrict__ A, int lda_m, int lda_k,
                                                const float* __restrict__ W, int ldw,
                                                const float* __restrict__ bias,
                                                float* __restrict__ C, int ldc,
                                                int M, int N, int K, int act, int accum) {
    __shared__ float As[16][72];
    __shared__ float Ws[16][72];
    int tid = threadIdx.x;
    int m0 = blockIdx.y * 64, n0 = blockIdx.x * 64;
    int tx = tid & 15, ty = tid >> 4;
    float acc[4][4] = {};
    for (int k0 = 0; k0 < K; k0 += 16) {
        {
            int ml = tid >> 2, kl = (tid & 3) * 4;
            const float4 av = *(const float4*)(A + (size_t)(m0 + ml) * lda_m + k0 + kl);
            As[kl + 0][ml] = av.x; As[kl + 1][ml] = av.y;
            As[kl + 2][ml] = av.z; As[kl + 3][ml] = av.w;
        }
        {
            int nl = tid >> 2, kl = (tid & 3) * 4;
            float4 wv;
            if (n0 + nl < N) wv = *(const float4*)(W + (size_t)(n0 + nl) * ldw + k0 + kl);
            else wv = make_float4(0.f, 0.f, 0.f, 0.f);
            Ws[kl + 0][nl] = wv.x; Ws[kl + 1][nl] = wv.y;
            Ws[kl + 2][nl] = wv.z; Ws[kl + 3][nl] = wv.w;
        }
        __syncthreads();
        #pragma unroll
        for (int kk = 0; kk < 16; kk++) {
            float4 av = *(const float4*)&As[kk][ty * 4];
            float4 bv = *(const float4*)&Ws[kk][tx * 4];
            float a[4] = {av.x, av.y, av.z, av.w};
            float bb[4] = {bv.x, bv.y, bv.z, bv.w};
            #pragma unroll
            for (int im = 0; im < 4; im++)
                #pragma unroll
                for (int in = 0; in < 4; in++)
                    acc[im][in] = fmaf(a[im], bb[in], acc[im][in]);
        }
        __syncthreads();
    }
    #pragma unroll
    for (int im = 0; im < 4; im++) {
        int m = m0 + ty * 4 + im;
        #pragma unroll
        for (int in = 0; in < 4; in++) {
            int n = n0 + tx * 4 + in;
            if (n >= N) continue;
            float v = acc[im][in];
            if (bias) v += bias[n];
            if (act == 1) v = fmaxf(v, 0.0f) + log1pf(expf(-fabsf(v)));
            float* cp = C + (size_t)m * ldc + n;
            if (accum) v += *cp;
            *cp = v;
        }
    }
}

// ======== chunk-parallel selective scan ========
__global__ __launch_bounds__(256) void scan_pass1(const float* __restrict__ xc,
                                                  const float* __restrict__ dtm,
                                                  const float* __restrict__ dbc,
                                                  const float* __restrict__ A_log,
                                                  float* __restrict__ hloc,
                                                  float* __restrict__ Pc) {
    int wave = blockIdx.x * 4 + (threadIdx.x >> 6);
    int lane = threadIdx.x & 63;
    int ch = wave & (NCH - 1);
    int c  = wave >> 11;
    int b = ch >> 9, d = ch & (DIm - 1);
    float As = -__expf(A_log[d * Ssz + lane]);
    int t0 = c * CHK;
    const float* dtp = dtm + (size_t)(b * Lseq + t0) * DIm + d;
    const float* xp  = xc  + (size_t)(b * Lseq + t0) * DIm + d;
    const float* Bp  = dbc + (size_t)(b * Lseq + t0) * 144 + DTRm + lane;
    float h = 0.0f, P = 1.0f;
    #pragma unroll 4
    for (int t = 0; t < CHK; t++) {
        float dtv = *dtp; dtp += DIm;
        float xv  = *xp;  xp  += DIm;
        float Bt  = *Bp;  Bp  += 144;
        float dA = __expf(dtv * As);
        h = fmaf(dA, h, dtv * xv * Bt);
        P *= dA;
    }
    size_t o = ((size_t)ch * NCHK + c) * Ssz + lane;
    hloc[o] = h;
    Pc[o] = P;
}

__global__ __launch_bounds__(256) void scan_combine(const float* __restrict__ hloc,
                                                    const float* __restrict__ Pc,
                                                    float* __restrict__ Hinit) {
    int wave = blockIdx.x * 4 + (threadIdx.x >> 6);
    int lane = threadIdx.x & 63;
    size_t base = (size_t)wave * NCHK * Ssz + lane;
    float H = 0.0f;
    #pragma unroll
    for (int c = 0; c < NCHK; c++) {
        size_t o = base + (size_t)c * Ssz;
        Hinit[o] = H;
        H = fmaf(Pc[o], H, hloc[o]);
    }
}

__global__ __launch_bounds__(256) void scan_pass3(const float* __restrict__ xc,
                                                  const float* __restrict__ dtm,
                                                  const float* __restrict__ xz,
                                                  const float* __restrict__ dbc,
                                                  const float* __restrict__ A_log,
                                                  const float* __restrict__ D_ssm,
                                                  const float* __restrict__ Hinit,
                                                  float* __restrict__ yT) {
    int wave = blockIdx.x * 4 + (threadIdx.x >> 6);
    int lane = threadIdx.x & 63;
    int ch = wave & (NCH - 1);
    int c  = wave >> 11;
    int b = ch >> 9, d = ch & (DIm - 1);
    float As = -__expf(A_log[d * Ssz + lane]);
    float Dd = D_ssm[d];
    int t0 = c * CHK;
    const float* dtp = dtm + (size_t)(b * Lseq + t0) * DIm + d;
    const float* xp  = xc  + (size_t)(b * Lseq + t0) * DIm + d;
    const float* zp  = xz  + (size_t)(b * Lseq + t0) * (2 * DIm) + DIm + d;
    const float* Bp  = dbc + (size_t)(b * Lseq + t0) * 144 + DTRm + lane;
    const float* Cp  = Bp + Ssz;
    float h = Hinit[((size_t)ch * NCHK + c) * Ssz + lane];
    float ybuf = 0.0f;
    #pragma unroll 4
    for (int tb = 0; tb < CHK / 4; tb++) {
        float hc[4], xvv[4], zvv[4];
        #pragma unroll
        for (int j = 0; j < 4; j++) {
            float dtv = *dtp; dtp += DIm;
            float xv  = *xp;  xp  += DIm;
            float zv  = *zp;  zp  += 2 * DIm;
            float Bt  = *Bp;  Bp  += 144;
            float Ct  = *Cp;  Cp  += 144;
            float dA = __expf(dtv * As);
            h = fmaf(dA, h, dtv * xv * Bt);
            hc[j] = h * Ct;
            xvv[j] = xv; zvv[j] = zv;
        }
        #pragma unroll
        for (int m = 32; m >= 1; m >>= 1) {
            #pragma unroll
            for (int j = 0; j < 4; j++) hc[j] += __shfl_xor(hc[j], m, 64);
        }
        #pragma unroll
        for (int j = 0; j < 4; j++) {
            float yg = (hc[j] + xvv[j] * Dd) * (zvv[j] / (1.0f + __expf(-zvv[j])));
            if (lane == tb * 4 + j) ybuf = yg;
        }
    }
    yT[(size_t)d * (Bsz * Lseq) + b * Lseq + t0 + lane] = ybuf;
}

// ---------------- decay-masked attention ----------------
__global__ __launch_bounds__(256) void attn_kernel(const float* __restrict__ q,
                                                   const float* __restrict__ k,
                                                   const float* __restrict__ v,
                                                   const float* __restrict__ log_tau,
                                                   float* __restrict__ out) {
    __shared__ float Ks[128][16];
    __shared__ float Vs[128][16];
    int bh = blockIdx.x >> 2;
    int qc = blockIdx.x & 3;
    int b = bh >> 4, h = bh & 15;
    int i = qc * 256 + threadIdx.x;
    float inv_tau = __expf(-log_tau[h]);
    float qv[16];
    const float* qp = q + ((size_t)(b * Lseq + i)) * Dm + h * HDm;
    #pragma unroll
    for (int j = 0; j < 16; j++) qv[j] = qp[j];
    float r = __expf(-inv_tau);
    float geom;
    if (1.0f - r > 1e-8f) geom = (1.0f - __expf(-inv_tau * (float)(i + 1))) / (1.0f - r);
    else geom = (float)(i + 1);
    float denom = fmaxf((float)(Lseq - 1 - i) + geom, 1e-6f);
    float acc[16];
    #pragma unroll
    for (int j = 0; j < 16; j++) acc[j] = 0.0f;
    for (int kc = 0; kc < Lseq; kc += 128) {
        int krow = threadIdx.x >> 1;
        int cb = (threadIdx.x & 1) * 8;
        const float* kp = k + ((size_t)(b * Lseq + kc + krow)) * Dm + h * HDm + cb;
        const float* vp = v + ((size_t)(b * Lseq + kc + krow)) * Dm + h * HDm + cb;
        *(float4*)&Ks[krow][cb]     = *(const float4*)kp;
        *(float4*)&Ks[krow][cb + 4] = *(const float4*)(kp + 4);
        *(float4*)&Vs[krow][cb]     = *(const float4*)vp;
        *(float4*)&Vs[krow][cb + 4] = *(const float4*)(vp + 4);
        __syncthreads();
        for (int kk = 0; kk < 128; kk++) {
            int kg = kc + kk;
            float dot = 0.0f;
            #pragma unroll
            for (int j = 0; j < 16; j++) dot = fmaf(qv[j], Ks[kk][j], dot);
            float w = __expf(fminf((float)(kg - i), 0.0f) * inv_tau);
            float dw = dot * w;
            #pragma unroll
            for (int j = 0; j < 16; j++) acc[j] = fmaf(dw, Vs[kk][j], acc[j]);
        }
        __syncthreads();
    }
    float sc = 0.25f / denom;
    float* op = out + ((size_t)(b * Lseq + i)) * Dm + h * HDm;
    #pragma unroll
    for (int j = 0; j < 16; j++) op[j] = acc[j] * sc;
}

// ---------------- gate + residual (reads from cat2 [ssm | ssd]) ----------------
__global__ void final_kernel(const float* __restrict__ x, const float* __restrict__ gpre,
                             const float* __restrict__ cat2, float* __restrict__ out) {
    int idx = blockIdx.x * blockDim.x + threadIdx.x;
    if (idx >= Bsz * Lseq * Dm) return;
    int m = idx >> 8, d = idx & 255;
    float g = 1.0f / (1.0f + __expf(-gpre[idx]));
    float ssm = cat2[(size_t)m * 512 + d];
    float ssd = cat2[(size_t)m * 512 + 256 + d];
    out[idx] = x[idx] + g * ssm + (1.0f - g) * ssd;
}

extern "C" void kernel_launch(void* const* d_in, const int* in_sizes, int n_in,
                              void* d_out, int out_size, void* d_ws, size_t ws_size,
                              hipStream_t stream) {
    const float* x        = (const float*)d_in[0];
    const float* ln_g     = (const float*)d_in[1];
    const float* ln_b     = (const float*)d_in[2];
    const float* mq_w     = (const float*)d_in[3];
    const float* mq_b     = (const float*)d_in[4];
    const float* fuse_w   = (const float*)d_in[5];
    const float* fuse_b   = (const float*)d_in[6];
    const float* in_proj_w= (const float*)d_in[7];
    const float* conv_w   = (const float*)d_in[8];
    const float* conv_b   = (const float*)d_in[9];
    const float* x_proj_w = (const float*)d_in[10];
    const float* dt_w     = (const float*)d_in[11];
    const float* dt_b     = (const float*)d_in[12];
    const float* A_log    = (const float*)d_in[13];
    const float* D_ssm    = (const float*)d_in[14];
    const float* out_w    = (const float*)d_in[15];
    const float* k_w      = (const float*)d_in[16];
    const float* k_b      = (const float*)d_in[17];
    const float* v_w      = (const float*)d_in[18];
    const float* v_b      = (const float*)d_in[19];
    const float* o_w      = (const float*)d_in[20];
    const float* o_b      = (const float*)d_in[21];
    const float* log_tau  = (const float*)d_in[22];
    const float* gate_w   = (const float*)d_in[23];
    const float* gate_b   = (const float*)d_in[24];
    float* outp = (float*)d_out;

    const int M = Bsz * Lseq;          // 4096
    float* ws = (float*)d_ws;
    size_t off = 0;
    float* xn    = ws + off; off += (size_t)M * Dm;
    float* xz    = ws + off; off += (size_t)M * 2 * DIm;
    float* xc    = ws + off; off += (size_t)M * DIm;
    float* dbc   = ws + off; off += (size_t)M * 144;
    float* dtm   = ws + off; off += (size_t)M * DIm;
    float* yT    = ws + off; off += (size_t)DIm * M;
    float* xd2   = ws + off; off += (size_t)Bsz * 512 * Dm;
    float* xd4   = ws + off; off += (size_t)Bsz * 256 * Dm;
    float* xd8   = ws + off; off += (size_t)Bsz * 128 * Dm;
    float* qd2   = ws + off; off += (size_t)Bsz * 512 * Dm;
    float* qd4   = ws + off; off += (size_t)Bsz * 256 * Dm;
    float* qd8   = ws + off; off += (size_t)Bsz * 128 * Dm;
    float* qcat  = ws + off; off += (size_t)M * 4 * Dm;   // reused: hloc + Pc for scan
    float* qbuf  = ws + off; off += (size_t)M * Dm;       // reused (w/ kmat): Hinit
    float* kmat  = ws + off; off += (size_t)M * Dm;
    float* vmat  = ws + off; off += (size_t)M * Dm;
    float* attn  = ws + off; off += (size_t)M * Dm;
    float* cat2  = ws + off; off += (size_t)M * 2 * Dm;   // [ssm_o | ssd_o]
    float* gpre  = ws + off; off += (size_t)M * Dm;

    // 1. LayerNorm
    ln_kernel<<<M, 256, 0, stream>>>(x, ln_g, ln_b, xn);

    // 2. in_proj GEMM (M=4096, N=1024, K=256)
    gemm_bf16<<<dim3(16, 64), 256, 0, stream>>>(xn, Dm, 1, in_proj_w, Dm,
        nullptr, xz, 2 * DIm, M, 2 * DIm, Dm, 0);

    // 3. k / v projections
    gemm_bf16<<<dim3(4, 64), 256, 0, stream>>>(xn, Dm, 1, k_w, Dm, k_b, kmat, Dm, M, Dm, Dm, 0);
    gemm_bf16<<<dim3(4, 64), 256, 0, stream>>>(xn, Dm, 1, v_w, Dm, v_b, vmat, Dm, M, Dm, Dm, 0);

    // 4. multi-scale q
    gemm_bf16<<<dim3(4, 64), 256, 0, stream>>>(xn, Dm, 1, mq_w, Dm, mq_b, qcat, 4 * Dm, M, Dm, Dm, 0);
    halve_kernel<<<(Bsz * 512 * Dm + 255) / 256, 256, 0, stream>>>(xn, xd2, 512);
    halve_kernel<<<(Bsz * 256 * Dm + 255) / 256, 256, 0, stream>>>(xd2, xd4, 256);
    halve_kernel<<<(Bsz * 128 * Dm + 255) / 256, 256, 0, stream>>>(xd4, xd8, 128);
    gemm_bf16<<<dim3(4, 32), 256, 0, stream>>>(xd2, Dm, 1, mq_w + 1 * Dm * Dm, Dm,
        mq_b + 1 * Dm, qd2, Dm, Bsz * 512, Dm, Dm, 0);
    gemm_bf16<<<dim3(4, 16), 256, 0, stream>>>(xd4, Dm, 1, mq_w + 2 * Dm * Dm, Dm,
        mq_b + 2 * Dm, qd4, Dm, Bsz * 256, Dm, Dm, 0);
    gemm_bf16<<<dim3(4, 8), 256, 0, stream>>>(xd8, Dm, 1, mq_w + 3 * Dm * Dm, Dm,
        mq_b + 3 * Dm, qd8, Dm, Bsz * 128, Dm, Dm, 0);
    interp_kernel<<<(M * Dm + 255) / 256, 256, 0, stream>>>(qd2, qcat, 512, 1);
    interp_kernel<<<(M * Dm + 255) / 256, 256, 0, stream>>>(qd4, qcat, 256, 2);
    interp_kernel<<<(M * Dm + 255) / 256, 256, 0, stream>>>(qd8, qcat, 128, 3);
    gemm_bf16<<<dim3(4, 64), 256, 0, stream>>>(qcat, 4 * Dm, 1, fuse_w, 4 * Dm,
        fuse_b, qbuf, Dm, M, Dm, 4 * Dm, 0);

    // 5. causal conv + SiLU
    conv_silu_kernel<<<(M * DIm + 255) / 256, 256, 0, stream>>>(xz, conv_w, conv_b, xc);

    // 6. x_proj GEMM (N=144, K=512)
    gemm_bf16<<<dim3(3, 64), 256, 0, stream>>>(xc, DIm, 1, x_proj_w, DIm,
        nullptr, dbc, 144, M, 144, DIm, 0);

    // 7. dt GEMM + softplus (K=16, fp32)
    gemm_f32<<<dim3(8, 64), 256, 0, stream>>>(dbc, 144, 1, dt_w, DTRm,
        dt_b, dtm, DIm, M, DIm, DTRm, 1, 0);

    // 8. attention (frees qbuf/qcat for scan scratch afterwards)
    attn_kernel<<<Bsz * Hh * 4, 256, 0, stream>>>(qbuf, kmat, vmat, log_tau, attn);
    gemm_bf16<<<dim3(4, 64), 256, 0, stream>>>(attn, Dm, 1, o_w, Dm, o_b,
        cat2 + 256, 2 * Dm, M, Dm, Dm, 0);

    // 9. chunk-parallel selective scan
    float* hloc  = qcat;
    float* Pc    = qcat + (size_t)NCH * NCHK * Ssz;
    float* Hinit = qbuf;
    scan_pass1<<<(NCH * NCHK) / 4, 256, 0, stream>>>(xc, dtm, dbc, A_log, hloc, Pc);
    scan_combine<<<NCH / 4, 256, 0, stream>>>(hloc, Pc, Hinit);
    scan_pass3<<<(NCH * NCHK) / 4, 256, 0, stream>>>(xc, dtm, xz, dbc, A_log, D_ssm, Hinit, yT);

    // 10. out GEMM (A transposed storage yT (DI, B*L)) -> cat2 cols 0..255
    gemm_bf16<<<dim3(4, 64), 256, 0, stream>>>(yT, 1, M, out_w, DIm,
        nullptr, cat2, 2 * Dm, M, Dm, DIm, 0);

    // 11. single gate GEMM over concat [ssm|ssd] (K=512)
    gemm_bf16<<<dim3(4, 64), 256, 0, stream>>>(cat2, 2 * Dm, 1, gate_w, 2 * Dm,
        gate_b, gpre, Dm, M, Dm, 2 * Dm, 0);

    // 12. sigmoid gate + residual
    final_kernel<<<(M * Dm + 255) / 256, 256, 0, stream>>>(x, gpre, cat2, outp);
}

// Round 4
// 558.646 us; speedup vs baseline: 2.7543x; 1.1877x over previous
//
#include <hip/hip_runtime.h>
#include <math.h>

#define Bsz 4
#define Lseq 1024
#define Dm 256
#define Hh 16
#define HDm 16
#define DIm 512
#define Ssz 64
#define KCm 4
#define DTRm 16
#define NCH (Bsz * DIm)      // 2048 channels
#define CHK 64               // chunk length
#define NCHK (Lseq / CHK)    // 16 chunks

typedef __attribute__((ext_vector_type(8))) short s8v;
typedef __attribute__((ext_vector_type(4))) float f4v;

static __device__ __forceinline__ float wave_sum(float v) {
    #pragma unroll
    for (int m = 32; m >= 1; m >>= 1) v += __shfl_xor(v, m, 64);
    return v;
}

static __device__ __forceinline__ short f2bf(float f) {
    unsigned int u = __float_as_uint(f);
    u = (u + 0x7fffu + ((u >> 16) & 1u)) >> 16;
    return (short)u;
}

static __device__ __forceinline__ s8v pack8(float4 a, float4 b) {
    s8v v;
    v[0] = f2bf(a.x); v[1] = f2bf(a.y); v[2] = f2bf(a.z); v[3] = f2bf(a.w);
    v[4] = f2bf(b.x); v[5] = f2bf(b.y); v[6] = f2bf(b.z); v[7] = f2bf(b.w);
    return v;
}

// ---------------- LayerNorm ----------------
__global__ __launch_bounds__(256) void ln_kernel(const float* __restrict__ x,
                                                 const float* __restrict__ g,
                                                 const float* __restrict__ b,
                                                 float* __restrict__ xn) {
    int row = blockIdx.x;
    int tid = threadIdx.x;
    __shared__ float red[8];
    float v = x[(size_t)row * Dm + tid];
    float s = wave_sum(v);
    int wid = tid >> 6, lane = tid & 63;
    if (lane == 0) red[wid] = s;
    __syncthreads();
    float mean = (red[0] + red[1] + red[2] + red[3]) * (1.0f / Dm);
    float dv = v - mean;
    float s2 = wave_sum(dv * dv);
    if (lane == 0) red[4 + wid] = s2;
    __syncthreads();
    float var = (red[4] + red[5] + red[6] + red[7]) * (1.0f / Dm);
    float inv = rsqrtf(var + 1e-5f);
    xn[(size_t)row * Dm + tid] = dv * inv * g[tid] + b[tid];
}

// ---------------- avg-pool by 2 along t ----------------
__global__ void halve_kernel(const float* __restrict__ in, float* __restrict__ out, int Lo) {
    int idx = blockIdx.x * blockDim.x + threadIdx.x;
    int total = Bsz * Lo * Dm;
    if (idx >= total) return;
    int d = idx % Dm;
    int j = (idx / Dm) % Lo;
    int b = idx / (Dm * Lo);
    const float* p = in + ((size_t)(b * 2 * Lo + 2 * j) * Dm + d);
    out[idx] = 0.5f * (p[0] + p[Dm]);
}

// ---------------- linear interpolation back to L ----------------
__global__ void interp_kernel(const float* __restrict__ qd, float* __restrict__ qcat,
                              int Lin, int seg) {
    int idx = blockIdx.x * blockDim.x + threadIdx.x;
    if (idx >= Bsz * Lseq * Dm) return;
    int d = idx % Dm;
    int t = (idx / Dm) % Lseq;
    int b = idx / (Dm * Lseq);
    float pos = (t + 0.5f) * ((float)Lin / (float)Lseq) - 0.5f;
    pos = fminf(fmaxf(pos, 0.0f), (float)(Lin - 1));
    int lo = (int)floorf(pos);
    int hi = min(lo + 1, Lin - 1);
    float w = pos - (float)lo;
    float v = qd[((size_t)(b * Lin + lo)) * Dm + d] * (1.0f - w)
            + qd[((size_t)(b * Lin + hi)) * Dm + d] * w;
    qcat[((size_t)(b * Lseq + t)) * (4 * Dm) + seg * Dm + d] = v;
}

// ---------------- causal depthwise conv + SiLU ----------------
__global__ void conv_silu_kernel(const float* __restrict__ xz, const float* __restrict__ cw,
                                 const float* __restrict__ cb, float* __restrict__ xc) {
    int idx = blockIdx.x * blockDim.x + threadIdx.x;
    if (idx >= Bsz * Lseq * DIm) return;
    int c = idx % DIm;
    int t = (idx / DIm) % Lseq;
    int b = idx / (DIm * Lseq);
    float acc = cb[c];
    #pragma unroll
    for (int kk = 0; kk < KCm; kk++) {
        int tt = t + kk - (KCm - 1);
        if (tt >= 0) acc += xz[((size_t)(b * Lseq + tt)) * (2 * DIm) + c] * cw[c * KCm + kk];
    }
    xc[idx] = acc / (1.0f + __expf(-acc));
}

// ======= bf16 MFMA GEMM: C = A(M,K) * W(N,K)^T + bias =======
__global__ __launch_bounds__(256) void gemm_bf16(const float* __restrict__ A, int lda_m, int lda_k,
                                                 const float* __restrict__ W, int ldw,
                                                 const float* __restrict__ bias,
                                                 float* __restrict__ C, int ldc,
                                                 int M, int N, int K, int accum) {
    __shared__ unsigned short As[64][40];
    __shared__ unsigned short Ws[64][40];
    int tid = threadIdx.x;
    int wave = tid >> 6, lane = tid & 63;
    int quad = lane >> 4, r = lane & 15;
    int m0 = blockIdx.y * 64, n0 = blockIdx.x * 64;
    int mo = (wave >> 1) * 32, no = (wave & 1) * 32;
    f4v acc[2][2];
    #pragma unroll
    for (int i = 0; i < 2; i++)
        #pragma unroll
        for (int j = 0; j < 2; j++) acc[i][j] = (f4v){0.f, 0.f, 0.f, 0.f};

    for (int k0 = 0; k0 < K; k0 += 32) {
        if (lda_k == 1) {
            int m = tid >> 2, kk = (tid & 3) * 8;
            const float* ap = A + (size_t)(m0 + m) * lda_m + k0 + kk;
            float4 a0 = *(const float4*)ap;
            float4 a1 = *(const float4*)(ap + 4);
            *(s8v*)&As[m][kk] = pack8(a0, a1);
        } else {
            int k = tid >> 3, m8 = (tid & 7) * 8;
            const float* ap = A + (size_t)(k0 + k) * lda_k + m0 + m8;
            float4 a0 = *(const float4*)ap;
            float4 a1 = *(const float4*)(ap + 4);
            float av[8] = {a0.x, a0.y, a0.z, a0.w, a1.x, a1.y, a1.z, a1.w};
            #pragma unroll
            for (int i = 0; i < 8; i++) As[m8 + i][k] = (unsigned short)f2bf(av[i]);
        }
        {
            int n = tid >> 2, kk = (tid & 3) * 8;
            s8v pv;
            if (n0 + n < N) {
                const float* wp = W + (size_t)(n0 + n) * ldw + k0 + kk;
                float4 w0 = *(const float4*)wp;
                float4 w1 = *(const float4*)(wp + 4);
                pv = pack8(w0, w1);
            } else {
                pv = (s8v){0, 0, 0, 0, 0, 0, 0, 0};
            }
            *(s8v*)&Ws[n][kk] = pv;
        }
        __syncthreads();
        s8v af[2], bf[2];
        #pragma unroll
        for (int i = 0; i < 2; i++) af[i] = *(const s8v*)&As[mo + i * 16 + r][quad * 8];
        #pragma unroll
        for (int j = 0; j < 2; j++) bf[j] = *(const s8v*)&Ws[no + j * 16 + r][quad * 8];
        #pragma unroll
        for (int i = 0; i < 2; i++)
            #pragma unroll
            for (int j = 0; j < 2; j++)
                acc[i][j] = __builtin_amdgcn_mfma_f32_16x16x32_bf16(af[i], bf[j], acc[i][j], 0, 0, 0);
        __syncthreads();
    }
    #pragma unroll
    for (int i = 0; i < 2; i++)
        #pragma unroll
        for (int j = 0; j < 2; j++)
            #pragma unroll
            for (int reg = 0; reg < 4; reg++) {
                int m = m0 + mo + i * 16 + quad * 4 + reg;
                int n = n0 + no + j * 16 + r;
                if (n >= N) continue;
                float v = acc[i][j][reg];
                if (bias) v += bias[n];
                float* cp = C + (size_t)m * ldc + n;
                if (accum) v += *cp;
                *cp = v;
            }
}

// ---------------- small fp32 GEMM (K=16 dt projection) ----------------
__global__ __launch_bounds__(256) void gemm_f32(const float* __restrict__ A, int lda_m, int lda_k,
                                                const float* __restrict__ W, int ldw,
                                                const float* __restrict__ bias,
                                                float* __restrict__ C, int ldc,
                                                int M, int N, int K, int act, int accum) {
    __shared__ float As[16][72];
    __shared__ float Ws[16][72];
    int tid = threadIdx.x;
    int m0 = blockIdx.y * 64, n0 = blockIdx.x * 64;
    int tx = tid & 15, ty = tid >> 4;
    float acc[4][4] = {};
    for (int k0 = 0; k0 < K; k0 += 16) {
        {
            int ml = tid >> 2, kl = (tid & 3) * 4;
            const float4 av = *(const float4*)(A + (size_t)(m0 + ml) * lda_m + k0 + kl);
            As[kl + 0][ml] = av.x; As[kl + 1][ml] = av.y;
            As[kl + 2][ml] = av.z; As[kl + 3][ml] = av.w;
        }
        {
            int nl = tid >> 2, kl = (tid & 3) * 4;
            float4 wv;
            if (n0 + nl < N) wv = *(const float4*)(W + (size_t)(n0 + nl) * ldw + k0 + kl);
            else wv = make_float4(0.f, 0.f, 0.f, 0.f);
            Ws[kl + 0][nl] = wv.x; Ws[kl + 1][nl] = wv.y;
            Ws[kl + 2][nl] = wv.z; Ws[kl + 3][nl] = wv.w;
        }
        __syncthreads();
        #pragma unroll
        for (int kk = 0; kk < 16; kk++) {
            float4 av = *(const float4*)&As[kk][ty * 4];
            float4 bv = *(const float4*)&Ws[kk][tx * 4];
            float a[4] = {av.x, av.y, av.z, av.w};
            float bb[4] = {bv.x, bv.y, bv.z, bv.w};
            #pragma unroll
            for (int im = 0; im < 4; im++)
                #pragma unroll
                for (int in = 0; in < 4; in++)
                    acc[im][in] = fmaf(a[im], bb[in], acc[im][in]);
        }
        __syncthreads();
    }
    #pragma unroll
    for (int im = 0; im < 4; im++) {
        int m = m0 + ty * 4 + im;
        #pragma unroll
        for (int in = 0; in < 4; in++) {
            int n = n0 + tx * 4 + in;
            if (n >= N) continue;
            float v = acc[im][in];
            if (bias) v += bias[n];
            if (act == 1) v = fmaxf(v, 0.0f) + log1pf(expf(-fabsf(v)));
            float* cp = C + (size_t)m * ldc + n;
            if (accum) v += *cp;
            *cp = v;
        }
    }
}

// ======== chunk-parallel selective scan ========
__global__ __launch_bounds__(256) void scan_pass1(const float* __restrict__ xc,
                                                  const float* __restrict__ dtm,
                                                  const float* __restrict__ dbc,
                                                  const float* __restrict__ A_log,
                                                  float* __restrict__ hloc,
                                                  float* __restrict__ Pc) {
    int wave = blockIdx.x * 4 + (threadIdx.x >> 6);
    int lane = threadIdx.x & 63;
    int ch = wave & (NCH - 1);
    int c  = wave >> 11;
    int b = ch >> 9, d = ch & (DIm - 1);
    float As = -__expf(A_log[d * Ssz + lane]);
    int t0 = c * CHK;
    const float* dtp = dtm + (size_t)(b * Lseq + t0) * DIm + d;
    const float* xp  = xc  + (size_t)(b * Lseq + t0) * DIm + d;
    const float* Bp  = dbc + (size_t)(b * Lseq + t0) * 144 + DTRm + lane;
    float h = 0.0f, P = 1.0f;
    #pragma unroll 4
    for (int t = 0; t < CHK; t++) {
        float dtv = *dtp; dtp += DIm;
        float xv  = *xp;  xp  += DIm;
        float Bt  = *Bp;  Bp  += 144;
        float dA = __expf(dtv * As);
        h = fmaf(dA, h, dtv * xv * Bt);
        P *= dA;
    }
    size_t o = ((size_t)ch * NCHK + c) * Ssz + lane;
    hloc[o] = h;
    Pc[o] = P;
}

__global__ __launch_bounds__(256) void scan_combine(const float* __restrict__ hloc,
                                                    const float* __restrict__ Pc,
                                                    float* __restrict__ Hinit) {
    int wave = blockIdx.x * 4 + (threadIdx.x >> 6);
    int lane = threadIdx.x & 63;
    size_t base = (size_t)wave * NCHK * Ssz + lane;
    float H = 0.0f;
    #pragma unroll
    for (int c = 0; c < NCHK; c++) {
        size_t o = base + (size_t)c * Ssz;
        Hinit[o] = H;
        H = fmaf(Pc[o], H, hloc[o]);
    }
}

// Pass 3 with LDS-transposed batched reduction (16-step batches, wave-private tile)
__global__ __launch_bounds__(256) void scan_pass3(const float* __restrict__ xc,
                                                  const float* __restrict__ dtm,
                                                  const float* __restrict__ xz,
                                                  const float* __restrict__ dbc,
                                                  const float* __restrict__ A_log,
                                                  const float* __restrict__ D_ssm,
                                                  const float* __restrict__ Hinit,
                                                  float* __restrict__ yT) {
    __shared__ float hCs[4][16][68];   // wave-private [wid]; pad 68 to spread banks
    int wid = threadIdx.x >> 6;
    int lane = threadIdx.x & 63;
    int wave = blockIdx.x * 4 + wid;
    int ch = wave & (NCH - 1);
    int c  = wave >> 11;
    int b = ch >> 9, d = ch & (DIm - 1);
    float As = -__expf(A_log[d * Ssz + lane]);
    float Dd = D_ssm[d];
    int t0 = c * CHK;
    const float* dtp = dtm + (size_t)(b * Lseq + t0) * DIm + d;
    const float* xp  = xc  + (size_t)(b * Lseq + t0) * DIm + d;
    const float* zp  = xz  + (size_t)(b * Lseq + t0) * (2 * DIm) + DIm + d;
    const float* Bp  = dbc + (size_t)(b * Lseq + t0) * 144 + DTRm + lane;
    const float* Cp  = Bp + Ssz;
    float h = Hinit[((size_t)ch * NCHK + c) * Ssz + lane];
    float xown = 0.0f, zown = 0.0f, yred = 0.0f;
    int tl = lane >> 2;             // timestep within batch this lane reduces
    int so = (lane & 3) * 16;       // state sub-range
    for (int tb = 0; tb < 4; tb++) {
        #pragma unroll
        for (int j = 0; j < 16; j++) {
            float dtv = *dtp; dtp += DIm;
            float xv  = *xp;  xp  += DIm;
            float zv  = *zp;  zp  += 2 * DIm;
            float Bt  = *Bp;  Bp  += 144;
            float Ct  = *Cp;  Cp  += 144;
            float dA = __expf(dtv * As);
            h = fmaf(dA, h, dtv * xv * Bt);
            hCs[wid][j][lane] = h * Ct;
            if (lane == tb * 16 + j) { xown = xv; zown = zv; }
        }
        // reduce: 4 lanes per timestep, 16 states each, then 2-level butterfly
        const float* bp = &hCs[wid][tl][so];
        float4 a0 = *(const float4*)(bp + 0);
        float4 a1 = *(const float4*)(bp + 4);
        float4 a2 = *(const float4*)(bp + 8);
        float4 a3 = *(const float4*)(bp + 12);
        float part = ((a0.x + a0.y) + (a0.z + a0.w)) + ((a1.x + a1.y) + (a1.z + a1.w))
                   + ((a2.x + a2.y) + (a2.z + a2.w)) + ((a3.x + a3.y) + (a3.z + a3.w));
        part += __shfl_xor(part, 1, 64);
        part += __shfl_xor(part, 2, 64);
        // gather to owner lane: lane L in [tb*16, tb*16+16) takes from lane 4*(L - tb*16)
        float got = __shfl(part, ((lane - tb * 16) << 2) & 63, 64);
        if ((lane >> 4) == tb) yred = got;
    }
    float yg = (yred + xown * Dd) * (zown / (1.0f + __expf(-zown)));
    yT[(size_t)d * (Bsz * Lseq) + b * Lseq + t0 + lane] = yg;
}

// ---------------- decay-masked attention, 4-way K-split (unscaled partials) ----------------
__global__ __launch_bounds__(256) void attn_split(const float* __restrict__ q,
                                                  const float* __restrict__ k,
                                                  const float* __restrict__ v,
                                                  const float* __restrict__ log_tau,
                                                  float* __restrict__ pbuf) {
    __shared__ float Ks[128][16];
    __shared__ float Vs[128][16];
    int p  = blockIdx.x & 3;
    int qc = (blockIdx.x >> 2) & 3;
    int bh = blockIdx.x >> 4;
    int b = bh >> 4, h = bh & 15;
    int i = qc * 256 + threadIdx.x;
    float inv_tau = __expf(-log_tau[h]);
    float qv[16];
    const float* qp = q + ((size_t)(b * Lseq + i)) * Dm + h * HDm;
    #pragma unroll
    for (int j = 0; j < 16; j++) qv[j] = qp[j];
    float acc[16];
    #pragma unroll
    for (int j = 0; j < 16; j++) acc[j] = 0.0f;
    for (int kc = p * 256; kc < p * 256 + 256; kc += 128) {
        int krow = threadIdx.x >> 1;
        int cb = (threadIdx.x & 1) * 8;
        const float* kp = k + ((size_t)(b * Lseq + kc + krow)) * Dm + h * HDm + cb;
        const float* vp = v + ((size_t)(b * Lseq + kc + krow)) * Dm + h * HDm + cb;
        *(float4*)&Ks[krow][cb]     = *(const float4*)kp;
        *(float4*)&Ks[krow][cb + 4] = *(const float4*)(kp + 4);
        *(float4*)&Vs[krow][cb]     = *(const float4*)vp;
        *(float4*)&Vs[krow][cb + 4] = *(const float4*)(vp + 4);
        __syncthreads();
        for (int kk = 0; kk < 128; kk++) {
            int kg = kc + kk;
            float dot = 0.0f;
            #pragma unroll
            for (int j = 0; j < 16; j++) dot = fmaf(qv[j], Ks[kk][j], dot);
            float w = __expf(fminf((float)(kg - i), 0.0f) * inv_tau);
            float dw = dot * w;
            #pragma unroll
            for (int j = 0; j < 16; j++) acc[j] = fmaf(dw, Vs[kk][j], acc[j]);
        }
        __syncthreads();
    }
    float* op = pbuf + (size_t)p * (Bsz * Lseq * Dm) + ((size_t)(b * Lseq + i)) * Dm + h * HDm;
    #pragma unroll
    for (int j = 0; j < 16; j++) op[j] = acc[j];
}

__global__ void attn_combine(const float* __restrict__ pbuf,
                             const float* __restrict__ log_tau,
                             float* __restrict__ out) {
    int idx = blockIdx.x * blockDim.x + threadIdx.x;
    const int tot = Bsz * Lseq * Dm;
    if (idx >= tot) return;
    int m = idx >> 8;
    int i = m & (Lseq - 1);
    int d = idx & 255;
    int h = d >> 4;
    float inv_tau = __expf(-log_tau[h]);
    float r = __expf(-inv_tau);
    float geom = (1.0f - r > 1e-8f)
               ? (1.0f - __expf(-inv_tau * (float)(i + 1))) / (1.0f - r)
               : (float)(i + 1);
    float denom = fmaxf((float)(Lseq - 1 - i) + geom, 1e-6f);
    float s = pbuf[idx] + pbuf[idx + (size_t)tot] + pbuf[idx + 2 * (size_t)tot]
            + pbuf[idx + 3 * (size_t)tot];
    out[idx] = s * (0.25f / denom);
}

// ---------------- gate + residual (reads from cat2 [ssm | ssd]) ----------------
__global__ void final_kernel(const float* __restrict__ x, const float* __restrict__ gpre,
                             const float* __restrict__ cat2, float* __restrict__ out) {
    int idx = blockIdx.x * blockDim.x + threadIdx.x;
    if (idx >= Bsz * Lseq * Dm) return;
    int m = idx >> 8, d = idx & 255;
    float g = 1.0f / (1.0f + __expf(-gpre[idx]));
    float ssm = cat2[(size_t)m * 512 + d];
    float ssd = cat2[(size_t)m * 512 + 256 + d];
    out[idx] = x[idx] + g * ssm + (1.0f - g) * ssd;
}

extern "C" void kernel_launch(void* const* d_in, const int* in_sizes, int n_in,
                              void* d_out, int out_size, void* d_ws, size_t ws_size,
                              hipStream_t stream) {
    const float* x        = (const float*)d_in[0];
    const float* ln_g     = (const float*)d_in[1];
    const float* ln_b     = (const float*)d_in[2];
    const float* mq_w     = (const float*)d_in[3];
    const float* mq_b     = (const float*)d_in[4];
    const float* fuse_w   = (const float*)d_in[5];
    const float* fuse_b   = (const float*)d_in[6];
    const float* in_proj_w= (const float*)d_in[7];
    const float* conv_w   = (const float*)d_in[8];
    const float* conv_b   = (const float*)d_in[9];
    const float* x_proj_w = (const float*)d_in[10];
    const float* dt_w     = (const float*)d_in[11];
    const float* dt_b     = (const float*)d_in[12];
    const float* A_log    = (const float*)d_in[13];
    const float* D_ssm    = (const float*)d_in[14];
    const float* out_w    = (const float*)d_in[15];
    const float* k_w      = (const float*)d_in[16];
    const float* k_b      = (const float*)d_in[17];
    const float* v_w      = (const float*)d_in[18];
    const float* v_b      = (const float*)d_in[19];
    const float* o_w      = (const float*)d_in[20];
    const float* o_b      = (const float*)d_in[21];
    const float* log_tau  = (const float*)d_in[22];
    const float* gate_w   = (const float*)d_in[23];
    const float* gate_b   = (const float*)d_in[24];
    float* outp = (float*)d_out;

    const int M = Bsz * Lseq;          // 4096
    float* ws = (float*)d_ws;
    size_t off = 0;
    float* xn    = ws + off; off += (size_t)M * Dm;
    float* xz    = ws + off; off += (size_t)M * 2 * DIm;
    float* xc    = ws + off; off += (size_t)M * DIm;
    float* dbc   = ws + off; off += (size_t)M * 144;
    float* dtm   = ws + off; off += (size_t)M * DIm;
    float* yT    = ws + off; off += (size_t)DIm * M;
    float* xd2   = ws + off; off += (size_t)Bsz * 512 * Dm;
    float* xd4   = ws + off; off += (size_t)Bsz * 256 * Dm;
    float* xd8   = ws + off; off += (size_t)Bsz * 128 * Dm;
    float* qd2   = ws + off; off += (size_t)Bsz * 512 * Dm;
    float* qd4   = ws + off; off += (size_t)Bsz * 256 * Dm;
    float* qd8   = ws + off; off += (size_t)Bsz * 128 * Dm;
    float* qcat  = ws + off; off += (size_t)M * 4 * Dm;   // reused: attn partials, then scan hloc/Pc
    float* qbuf  = ws + off; off += (size_t)M * Dm;       // reused (w/ kmat): Hinit
    float* kmat  = ws + off; off += (size_t)M * Dm;
    float* vmat  = ws + off; off += (size_t)M * Dm;
    float* attn  = ws + off; off += (size_t)M * Dm;
    float* cat2  = ws + off; off += (size_t)M * 2 * Dm;   // [ssm_o | ssd_o]
    float* gpre  = ws + off; off += (size_t)M * Dm;

    // 1. LayerNorm
    ln_kernel<<<M, 256, 0, stream>>>(x, ln_g, ln_b, xn);

    // 2. in_proj GEMM (M=4096, N=1024, K=256)
    gemm_bf16<<<dim3(16, 64), 256, 0, stream>>>(xn, Dm, 1, in_proj_w, Dm,
        nullptr, xz, 2 * DIm, M, 2 * DIm, Dm, 0);

    // 3. k / v projections
    gemm_bf16<<<dim3(4, 64), 256, 0, stream>>>(xn, Dm, 1, k_w, Dm, k_b, kmat, Dm, M, Dm, Dm, 0);
    gemm_bf16<<<dim3(4, 64), 256, 0, stream>>>(xn, Dm, 1, v_w, Dm, v_b, vmat, Dm, M, Dm, Dm, 0);

    // 4. multi-scale q
    gemm_bf16<<<dim3(4, 64), 256, 0, stream>>>(xn, Dm, 1, mq_w, Dm, mq_b, qcat, 4 * Dm, M, Dm, Dm, 0);
    halve_kernel<<<(Bsz * 512 * Dm + 255) / 256, 256, 0, stream>>>(xn, xd2, 512);
    halve_kernel<<<(Bsz * 256 * Dm + 255) / 256, 256, 0, stream>>>(xd2, xd4, 256);
    halve_kernel<<<(Bsz * 128 * Dm + 255) / 256, 256, 0, stream>>>(xd4, xd8, 128);
    gemm_bf16<<<dim3(4, 32), 256, 0, stream>>>(xd2, Dm, 1, mq_w + 1 * Dm * Dm, Dm,
        mq_b + 1 * Dm, qd2, Dm, Bsz * 512, Dm, Dm, 0);
    gemm_bf16<<<dim3(4, 16), 256, 0, stream>>>(xd4, Dm, 1, mq_w + 2 * Dm * Dm, Dm,
        mq_b + 2 * Dm, qd4, Dm, Bsz * 256, Dm, Dm, 0);
    gemm_bf16<<<dim3(4, 8), 256, 0, stream>>>(xd8, Dm, 1, mq_w + 3 * Dm * Dm, Dm,
        mq_b + 3 * Dm, qd8, Dm, Bsz * 128, Dm, Dm, 0);
    interp_kernel<<<(M * Dm + 255) / 256, 256, 0, stream>>>(qd2, qcat, 512, 1);
    interp_kernel<<<(M * Dm + 255) / 256, 256, 0, stream>>>(qd4, qcat, 256, 2);
    interp_kernel<<<(M * Dm + 255) / 256, 256, 0, stream>>>(qd8, qcat, 128, 3);
    gemm_bf16<<<dim3(4, 64), 256, 0, stream>>>(qcat, 4 * Dm, 1, fuse_w, 4 * Dm,
        fuse_b, qbuf, Dm, M, Dm, 4 * Dm, 0);

    // 5. causal conv + SiLU
    conv_silu_kernel<<<(M * DIm + 255) / 256, 256, 0, stream>>>(xz, conv_w, conv_b, xc);

    // 6. x_proj GEMM (N=144, K=512)
    gemm_bf16<<<dim3(3, 64), 256, 0, stream>>>(xc, DIm, 1, x_proj_w, DIm,
        nullptr, dbc, 144, M, 144, DIm, 0);

    // 7. dt GEMM + softplus (K=16, fp32)
    gemm_f32<<<dim3(8, 64), 256, 0, stream>>>(dbc, 144, 1, dt_w, DTRm,
        dt_b, dtm, DIm, M, DIm, DTRm, 1, 0);

    // 8. attention, 4-way K-split (partials in dead qcat) + combine
    attn_split<<<Bsz * Hh * 4 * 4, 256, 0, stream>>>(qbuf, kmat, vmat, log_tau, qcat);
    attn_combine<<<(M * Dm + 255) / 256, 256, 0, stream>>>(qcat, log_tau, attn);
    gemm_bf16<<<dim3(4, 64), 256, 0, stream>>>(attn, Dm, 1, o_w, Dm, o_b,
        cat2 + 256, 2 * Dm, M, Dm, Dm, 0);

    // 9. chunk-parallel selective scan (qcat free again after combine)
    float* hloc  = qcat;
    float* Pc    = qcat + (size_t)NCH * NCHK * Ssz;
    float* Hinit = qbuf;
    scan_pass1<<<(NCH * NCHK) / 4, 256, 0, stream>>>(xc, dtm, dbc, A_log, hloc, Pc);
    scan_combine<<<NCH / 4, 256, 0, stream>>>(hloc, Pc, Hinit);
    scan_pass3<<<(NCH * NCHK) / 4, 256, 0, stream>>>(xc, dtm, xz, dbc, A_log, D_ssm, Hinit, yT);

    // 10. out GEMM (A transposed storage yT (DI, B*L)) -> cat2 cols 0..255
    gemm_bf16<<<dim3(4, 64), 256, 0, stream>>>(yT, 1, M, out_w, DIm,
        nullptr, cat2, 2 * Dm, M, Dm, DIm, 0);

    // 11. single gate GEMM over concat [ssm|ssd] (K=512)
    gemm_bf16<<<dim3(4, 64), 256, 0, stream>>>(cat2, 2 * Dm, 1, gate_w, 2 * Dm,
        gate_b, gpre, Dm, M, Dm, 2 * Dm, 0);

    // 12. sigmoid gate + residual
    final_kernel<<<(M * Dm + 255) / 256, 256, 0, stream>>>(x, gpre, cat2, outp);
}

// Round 5
// 547.754 us; speedup vs baseline: 2.8091x; 1.0199x over previous
//
#include <hip/hip_runtime.h>
#include <math.h>

#define Bsz 4
#define Lseq 1024
#define Dm 256
#define Hh 16
#define HDm 16
#define DIm 512
#define Ssz 64
#define KCm 4
#define DTRm 16
#define NCH (Bsz * DIm)      // 2048 channels
#define CHK 64               // chunk length
#define NCHK (Lseq / CHK)    // 16 chunks

typedef __attribute__((ext_vector_type(8))) short s8v;
typedef __attribute__((ext_vector_type(4))) float f4v;

static __device__ __forceinline__ float wave_sum(float v) {
    #pragma unroll
    for (int m = 32; m >= 1; m >>= 1) v += __shfl_xor(v, m, 64);
    return v;
}

static __device__ __forceinline__ short f2bf(float f) {
    unsigned int u = __float_as_uint(f);
    u = (u + 0x7fffu + ((u >> 16) & 1u)) >> 16;
    return (short)u;
}

static __device__ __forceinline__ s8v pack8(float4 a, float4 b) {
    s8v v;
    v[0] = f2bf(a.x); v[1] = f2bf(a.y); v[2] = f2bf(a.z); v[3] = f2bf(a.w);
    v[4] = f2bf(b.x); v[5] = f2bf(b.y); v[6] = f2bf(b.z); v[7] = f2bf(b.w);
    return v;
}

// ---------------- LayerNorm ----------------
__global__ __launch_bounds__(256) void ln_kernel(const float* __restrict__ x,
                                                 const float* __restrict__ g,
                                                 const float* __restrict__ b,
                                                 float* __restrict__ xn) {
    int row = blockIdx.x;
    int tid = threadIdx.x;
    __shared__ float red[8];
    float v = x[(size_t)row * Dm + tid];
    float s = wave_sum(v);
    int wid = tid >> 6, lane = tid & 63;
    if (lane == 0) red[wid] = s;
    __syncthreads();
    float mean = (red[0] + red[1] + red[2] + red[3]) * (1.0f / Dm);
    float dv = v - mean;
    float s2 = wave_sum(dv * dv);
    if (lane == 0) red[4 + wid] = s2;
    __syncthreads();
    float var = (red[4] + red[5] + red[6] + red[7]) * (1.0f / Dm);
    float inv = rsqrtf(var + 1e-5f);
    xn[(size_t)row * Dm + tid] = dv * inv * g[tid] + b[tid];
}

// ---------------- avg-pool by 2 along t ----------------
__global__ void halve_kernel(const float* __restrict__ in, float* __restrict__ out, int Lo) {
    int idx = blockIdx.x * blockDim.x + threadIdx.x;
    int total = Bsz * Lo * Dm;
    if (idx >= total) return;
    int d = idx % Dm;
    int j = (idx / Dm) % Lo;
    int b = idx / (Dm * Lo);
    const float* p = in + ((size_t)(b * 2 * Lo + 2 * j) * Dm + d);
    out[idx] = 0.5f * (p[0] + p[Dm]);
}

// ---------------- linear interpolation back to L ----------------
__global__ void interp_kernel(const float* __restrict__ qd, float* __restrict__ qcat,
                              int Lin, int seg) {
    int idx = blockIdx.x * blockDim.x + threadIdx.x;
    if (idx >= Bsz * Lseq * Dm) return;
    int d = idx % Dm;
    int t = (idx / Dm) % Lseq;
    int b = idx / (Dm * Lseq);
    float pos = (t + 0.5f) * ((float)Lin / (float)Lseq) - 0.5f;
    pos = fminf(fmaxf(pos, 0.0f), (float)(Lin - 1));
    int lo = (int)floorf(pos);
    int hi = min(lo + 1, Lin - 1);
    float w = pos - (float)lo;
    float v = qd[((size_t)(b * Lin + lo)) * Dm + d] * (1.0f - w)
            + qd[((size_t)(b * Lin + hi)) * Dm + d] * w;
    qcat[((size_t)(b * Lseq + t)) * (4 * Dm) + seg * Dm + d] = v;
}

// ---------------- causal depthwise conv + SiLU; writes xc (row-major) AND xcT (time-major) ----------------
__global__ __launch_bounds__(256) void conv_silu_kernel(const float* __restrict__ xm,
                                                        const float* __restrict__ cw,
                                                        const float* __restrict__ cb,
                                                        float* __restrict__ xc,
                                                        float* __restrict__ xcT) {
    __shared__ float tile[64][65];
    int blk = blockIdx.x;           // 512 blocks
    int cblk = blk & 7;
    int tblk = (blk >> 3) & 15;
    int b = blk >> 7;
    int c0 = cblk * 64, t0 = tblk * 64;
    int cc = threadIdx.x & 63;
    int tw = threadIdx.x >> 6;
    int c = c0 + cc;
    float w0 = cw[c * 4 + 0], w1 = cw[c * 4 + 1], w2 = cw[c * 4 + 2], w3 = cw[c * 4 + 3];
    float bias = cb[c];
    #pragma unroll 4
    for (int i = 0; i < 16; i++) {
        int tl = tw * 16 + i;
        int t = t0 + tl;
        const float* base = xm + ((size_t)(b * Lseq + t)) * DIm + c;
        float acc = bias + base[0] * w3;
        if (t >= 3) {
            acc += base[-3 * DIm] * w0 + base[-2 * DIm] * w1 + base[-1 * DIm] * w2;
        } else {
            if (t >= 1) acc += base[-1 * DIm] * w2;
            if (t >= 2) acc += base[-2 * DIm] * w1;
        }
        float r = acc / (1.0f + __expf(-acc));
        xc[((size_t)(b * Lseq + t)) * DIm + c] = r;
        tile[tl][cc] = r;
    }
    __syncthreads();
    int tcol = threadIdx.x & 63;
    int crow0 = threadIdx.x >> 6;
    #pragma unroll 4
    for (int j = 0; j < 16; j++) {
        int crow = crow0 * 16 + j;
        xcT[((size_t)(c0 + crow)) * (Bsz * Lseq) + b * Lseq + t0 + tcol] = tile[tcol][crow];
    }
}

// ======= bf16 MFMA GEMM: C = A(M,K) * W(N,K)^T + bias;  transC: C[n*ldc + m] =======
__global__ __launch_bounds__(256) void gemm_bf16(const float* __restrict__ A, int lda_m, int lda_k,
                                                 const float* __restrict__ W, int ldw,
                                                 const float* __restrict__ bias,
                                                 float* __restrict__ C, int ldc,
                                                 int M, int N, int K, int accum, int transC) {
    __shared__ unsigned short As[64][40];
    __shared__ unsigned short Ws[64][40];
    int tid = threadIdx.x;
    int wave = tid >> 6, lane = tid & 63;
    int quad = lane >> 4, r = lane & 15;
    int m0 = blockIdx.y * 64, n0 = blockIdx.x * 64;
    int mo = (wave >> 1) * 32, no = (wave & 1) * 32;
    f4v acc[2][2];
    #pragma unroll
    for (int i = 0; i < 2; i++)
        #pragma unroll
        for (int j = 0; j < 2; j++) acc[i][j] = (f4v){0.f, 0.f, 0.f, 0.f};

    for (int k0 = 0; k0 < K; k0 += 32) {
        if (lda_k == 1) {
            int m = tid >> 2, kk = (tid & 3) * 8;
            const float* ap = A + (size_t)(m0 + m) * lda_m + k0 + kk;
            float4 a0 = *(const float4*)ap;
            float4 a1 = *(const float4*)(ap + 4);
            *(s8v*)&As[m][kk] = pack8(a0, a1);
        } else {
            int k = tid >> 3, m8 = (tid & 7) * 8;
            const float* ap = A + (size_t)(k0 + k) * lda_k + m0 + m8;
            float4 a0 = *(const float4*)ap;
            float4 a1 = *(const float4*)(ap + 4);
            float av[8] = {a0.x, a0.y, a0.z, a0.w, a1.x, a1.y, a1.z, a1.w};
            #pragma unroll
            for (int i = 0; i < 8; i++) As[m8 + i][k] = (unsigned short)f2bf(av[i]);
        }
        {
            int n = tid >> 2, kk = (tid & 3) * 8;
            s8v pv;
            if (n0 + n < N) {
                const float* wp = W + (size_t)(n0 + n) * ldw + k0 + kk;
                float4 w0 = *(const float4*)wp;
                float4 w1 = *(const float4*)(wp + 4);
                pv = pack8(w0, w1);
            } else {
                pv = (s8v){0, 0, 0, 0, 0, 0, 0, 0};
            }
            *(s8v*)&Ws[n][kk] = pv;
        }
        __syncthreads();
        s8v af[2], bf[2];
        #pragma unroll
        for (int i = 0; i < 2; i++) af[i] = *(const s8v*)&As[mo + i * 16 + r][quad * 8];
        #pragma unroll
        for (int j = 0; j < 2; j++) bf[j] = *(const s8v*)&Ws[no + j * 16 + r][quad * 8];
        #pragma unroll
        for (int i = 0; i < 2; i++)
            #pragma unroll
            for (int j = 0; j < 2; j++)
                acc[i][j] = __builtin_amdgcn_mfma_f32_16x16x32_bf16(af[i], bf[j], acc[i][j], 0, 0, 0);
        __syncthreads();
    }
    #pragma unroll
    for (int i = 0; i < 2; i++)
        #pragma unroll
        for (int j = 0; j < 2; j++)
            #pragma unroll
            for (int reg = 0; reg < 4; reg++) {
                int m = m0 + mo + i * 16 + quad * 4 + reg;
                int n = n0 + no + j * 16 + r;
                if (n >= N) continue;
                float v = acc[i][j][reg];
                if (bias) v += bias[n];
                float* cp = transC ? (C + (size_t)n * ldc + m) : (C + (size_t)m * ldc + n);
                if (accum) v += *cp;
                *cp = v;
            }
}

// ---------------- small fp32 GEMM (K=16 dt projection); transC supported ----------------
__global__ __launch_bounds__(256) void gemm_f32(const float* __restrict__ A, int lda_m, int lda_k,
                                                const float* __restrict__ W, int ldw,
                                                const float* __restrict__ bias,
                                                float* __restrict__ C, int ldc,
                                                int M, int N, int K, int act, int accum, int transC) {
    __shared__ float As[16][72];
    __shared__ float Ws[16][72];
    int tid = threadIdx.x;
    int m0 = blockIdx.y * 64, n0 = blockIdx.x * 64;
    int tx = tid & 15, ty = tid >> 4;
    float acc[4][4] = {};
    for (int k0 = 0; k0 < K; k0 += 16) {
        {
            int ml = tid >> 2, kl = (tid & 3) * 4;
            const float4 av = *(const float4*)(A + (size_t)(m0 + ml) * lda_m + k0 + kl);
            As[kl + 0][ml] = av.x; As[kl + 1][ml] = av.y;
            As[kl + 2][ml] = av.z; As[kl + 3][ml] = av.w;
        }
        {
            int nl = tid >> 2, kl = (tid & 3) * 4;
            float4 wv;
            if (n0 + nl < N) wv = *(const float4*)(W + (size_t)(n0 + nl) * ldw + k0 + kl);
            else wv = make_float4(0.f, 0.f, 0.f, 0.f);
            Ws[kl + 0][nl] = wv.x; Ws[kl + 1][nl] = wv.y;
            Ws[kl + 2][nl] = wv.z; Ws[kl + 3][nl] = wv.w;
        }
        __syncthreads();
        #pragma unroll
        for (int kk = 0; kk < 16; kk++) {
            float4 av = *(const float4*)&As[kk][ty * 4];
            float4 bv = *(const float4*)&Ws[kk][tx * 4];
            float a[4] = {av.x, av.y, av.z, av.w};
            float bb[4] = {bv.x, bv.y, bv.z, bv.w};
            #pragma unroll
            for (int im = 0; im < 4; im++)
                #pragma unroll
                for (int in = 0; in < 4; in++)
                    acc[im][in] = fmaf(a[im], bb[in], acc[im][in]);
        }
        __syncthreads();
    }
    #pragma unroll
    for (int in = 0; in < 4; in++) {
        int n = n0 + tx * 4 + in;
        if (n >= N) continue;
        #pragma unroll
        for (int im = 0; im < 4; im++) {
            int m = m0 + ty * 4 + im;
            float v = acc[im][in];
            if (bias) v += bias[n];
            if (act == 1) v = fmaxf(v, 0.0f) + log1pf(expf(-fabsf(v)));
            float* cp = transC ? (C + (size_t)n * ldc + m) : (C + (size_t)m * ldc + n);
            if (accum) v += *cp;
            *cp = v;
        }
    }
}

// ======== chunk-parallel selective scan (time-major operands) ========
__global__ __launch_bounds__(256) void scan_pass1(const float* __restrict__ xcT,
                                                  const float* __restrict__ dtmT,
                                                  const float* __restrict__ dbc,
                                                  const float* __restrict__ A_log,
                                                  float* __restrict__ hloc,
                                                  float* __restrict__ Pc) {
    int wave = blockIdx.x * 4 + (threadIdx.x >> 6);
    int lane = threadIdx.x & 63;
    int ch = wave & (NCH - 1);
    int c  = wave >> 11;
    int b = ch >> 9, d = ch & (DIm - 1);
    float As = -__expf(A_log[d * Ssz + lane]);
    int base_m = b * Lseq + c * CHK;
    float dt_vec = dtmT[(size_t)d * (Bsz * Lseq) + base_m + lane];
    float x_vec  = xcT [(size_t)d * (Bsz * Lseq) + base_m + lane];
    float ux = dt_vec * x_vec;
    const float* Bp = dbc + (size_t)base_m * 144 + DTRm + lane;
    float h = 0.0f, P = 1.0f;
    #pragma unroll 8
    for (int t = 0; t < CHK; t++) {
        float Bt = *Bp; Bp += 144;
        float dtv = __shfl(dt_vec, t, 64);
        float u   = __shfl(ux, t, 64);
        float dA = __expf(dtv * As);
        h = fmaf(dA, h, u * Bt);
        P *= dA;
    }
    size_t o = ((size_t)ch * NCHK + c) * Ssz + lane;
    hloc[o] = h;
    Pc[o] = P;
}

__global__ __launch_bounds__(256) void scan_combine(const float* __restrict__ hloc,
                                                    const float* __restrict__ Pc,
                                                    float* __restrict__ Hinit) {
    int wave = blockIdx.x * 4 + (threadIdx.x >> 6);
    int lane = threadIdx.x & 63;
    size_t base = (size_t)wave * NCHK * Ssz + lane;
    float H = 0.0f;
    #pragma unroll
    for (int c = 0; c < NCHK; c++) {
        size_t o = base + (size_t)c * Ssz;
        Hinit[o] = H;
        H = fmaf(Pc[o], H, hloc[o]);
    }
}

__global__ __launch_bounds__(256) void scan_pass3(const float* __restrict__ xcT,
                                                  const float* __restrict__ dtmT,
                                                  const float* __restrict__ zT,
                                                  const float* __restrict__ dbc,
                                                  const float* __restrict__ A_log,
                                                  const float* __restrict__ D_ssm,
                                                  const float* __restrict__ Hinit,
                                                  float* __restrict__ yT) {
    __shared__ float hCs[4][16][68];
    int wid = threadIdx.x >> 6;
    int lane = threadIdx.x & 63;
    int wave = blockIdx.x * 4 + wid;
    int ch = wave & (NCH - 1);
    int c  = wave >> 11;
    int b = ch >> 9, d = ch & (DIm - 1);
    float As = -__expf(A_log[d * Ssz + lane]);
    float Dd = D_ssm[d];
    int base_m = b * Lseq + c * CHK;
    float dt_vec = dtmT[(size_t)d * (Bsz * Lseq) + base_m + lane];
    float x_vec  = xcT [(size_t)d * (Bsz * Lseq) + base_m + lane];
    float zown   = zT  [(size_t)d * (Bsz * Lseq) + base_m + lane];
    float ux = dt_vec * x_vec;
    const float* Bp = dbc + (size_t)base_m * 144 + DTRm + lane;
    const float* Cp = Bp + Ssz;
    float h = Hinit[((size_t)ch * NCHK + c) * Ssz + lane];
    float yred = 0.0f;
    int tl = lane >> 2;
    int so = (lane & 3) * 16;
    for (int tb = 0; tb < 4; tb++) {
        #pragma unroll
        for (int j = 0; j < 16; j++) {
            int t = tb * 16 + j;
            float Bt = *Bp; Bp += 144;
            float Ct = *Cp; Cp += 144;
            float dtv = __shfl(dt_vec, t, 64);
            float u   = __shfl(ux, t, 64);
            float dA = __expf(dtv * As);
            h = fmaf(dA, h, u * Bt);
            hCs[wid][j][lane] = h * Ct;
        }
        const float* bp = &hCs[wid][tl][so];
        float4 a0 = *(const float4*)(bp + 0);
        float4 a1 = *(const float4*)(bp + 4);
        float4 a2 = *(const float4*)(bp + 8);
        float4 a3 = *(const float4*)(bp + 12);
        float part = ((a0.x + a0.y) + (a0.z + a0.w)) + ((a1.x + a1.y) + (a1.z + a1.w))
                   + ((a2.x + a2.y) + (a2.z + a2.w)) + ((a3.x + a3.y) + (a3.z + a3.w));
        part += __shfl_xor(part, 1, 64);
        part += __shfl_xor(part, 2, 64);
        float got = __shfl(part, ((lane - tb * 16) << 2) & 63, 64);
        if ((lane >> 4) == tb) yred = got;
    }
    float yg = (yred + x_vec * Dd) * (zown / (1.0f + __expf(-zown)));
    yT[(size_t)d * (Bsz * Lseq) + base_m + lane] = yg;
}

// ---------------- decay-masked attention, 4-way K-split (unscaled partials) ----------------
__global__ __launch_bounds__(256) void attn_split(const float* __restrict__ q,
                                                  const float* __restrict__ k,
                                                  const float* __restrict__ v,
                                                  const float* __restrict__ log_tau,
                                                  float* __restrict__ pbuf) {
    __shared__ float Ks[128][16];
    __shared__ float Vs[128][16];
    int p  = blockIdx.x & 3;
    int qc = (blockIdx.x >> 2) & 3;
    int bh = blockIdx.x >> 4;
    int b = bh >> 4, h = bh & 15;
    int i = qc * 256 + threadIdx.x;
    float inv_tau = __expf(-log_tau[h]);
    float qv[16];
    const float* qp = q + ((size_t)(b * Lseq + i)) * Dm + h * HDm;
    #pragma unroll
    for (int j = 0; j < 16; j++) qv[j] = qp[j];
    float acc[16];
    #pragma unroll
    for (int j = 0; j < 16; j++) acc[j] = 0.0f;
    for (int kc = p * 256; kc < p * 256 + 256; kc += 128) {
        int krow = threadIdx.x >> 1;
        int cb = (threadIdx.x & 1) * 8;
        const float* kp = k + ((size_t)(b * Lseq + kc + krow)) * Dm + h * HDm + cb;
        const float* vp = v + ((size_t)(b * Lseq + kc + krow)) * Dm + h * HDm + cb;
        *(float4*)&Ks[krow][cb]     = *(const float4*)kp;
        *(float4*)&Ks[krow][cb + 4] = *(const float4*)(kp + 4);
        *(float4*)&Vs[krow][cb]     = *(const float4*)vp;
        *(float4*)&Vs[krow][cb + 4] = *(const float4*)(vp + 4);
        __syncthreads();
        for (int kk = 0; kk < 128; kk++) {
            int kg = kc + kk;
            float dot = 0.0f;
            #pragma unroll
            for (int j = 0; j < 16; j++) dot = fmaf(qv[j], Ks[kk][j], dot);
            float w = __expf(fminf((float)(kg - i), 0.0f) * inv_tau);
            float dw = dot * w;
            #pragma unroll
            for (int j = 0; j < 16; j++) acc[j] = fmaf(dw, Vs[kk][j], acc[j]);
        }
        __syncthreads();
    }
    float* op = pbuf + (size_t)p * (Bsz * Lseq * Dm) + ((size_t)(b * Lseq + i)) * Dm + h * HDm;
    #pragma unroll
    for (int j = 0; j < 16; j++) op[j] = acc[j];
}

__global__ void attn_combine(const float* __restrict__ pbuf,
                             const float* __restrict__ log_tau,
                             float* __restrict__ out) {
    int idx = blockIdx.x * blockDim.x + threadIdx.x;
    const int tot = Bsz * Lseq * Dm;
    if (idx >= tot) return;
    int m = idx >> 8;
    int i = m & (Lseq - 1);
    int d = idx & 255;
    int h = d >> 4;
    float inv_tau = __expf(-log_tau[h]);
    float r = __expf(-inv_tau);
    float geom = (1.0f - r > 1e-8f)
               ? (1.0f - __expf(-inv_tau * (float)(i + 1))) / (1.0f - r)
               : (float)(i + 1);
    float denom = fmaxf((float)(Lseq - 1 - i) + geom, 1e-6f);
    float s = pbuf[idx] + pbuf[idx + (size_t)tot] + pbuf[idx + 2 * (size_t)tot]
            + pbuf[idx + 3 * (size_t)tot];
    out[idx] = s * (0.25f / denom);
}

// ---------------- gate + residual (reads from cat2 [ssm | ssd]) ----------------
__global__ void final_kernel(const float* __restrict__ x, const float* __restrict__ gpre,
                             const float* __restrict__ cat2, float* __restrict__ out) {
    int idx = blockIdx.x * blockDim.x + threadIdx.x;
    if (idx >= Bsz * Lseq * Dm) return;
    int m = idx >> 8, d = idx & 255;
    float g = 1.0f / (1.0f + __expf(-gpre[idx]));
    float ssm = cat2[(size_t)m * 512 + d];
    float ssd = cat2[(size_t)m * 512 + 256 + d];
    out[idx] = x[idx] + g * ssm + (1.0f - g) * ssd;
}

extern "C" void kernel_launch(void* const* d_in, const int* in_sizes, int n_in,
                              void* d_out, int out_size, void* d_ws, size_t ws_size,
                              hipStream_t stream) {
    const float* x        = (const float*)d_in[0];
    const float* ln_g     = (const float*)d_in[1];
    const float* ln_b     = (const float*)d_in[2];
    const float* mq_w     = (const float*)d_in[3];
    const float* mq_b     = (const float*)d_in[4];
    const float* fuse_w   = (const float*)d_in[5];
    const float* fuse_b   = (const float*)d_in[6];
    const float* in_proj_w= (const float*)d_in[7];
    const float* conv_w   = (const float*)d_in[8];
    const float* conv_b   = (const float*)d_in[9];
    const float* x_proj_w = (const float*)d_in[10];
    const float* dt_w     = (const float*)d_in[11];
    const float* dt_b     = (const float*)d_in[12];
    const float* A_log    = (const float*)d_in[13];
    const float* D_ssm    = (const float*)d_in[14];
    const float* out_w    = (const float*)d_in[15];
    const float* k_w      = (const float*)d_in[16];
    const float* k_b      = (const float*)d_in[17];
    const float* v_w      = (const float*)d_in[18];
    const float* v_b      = (const float*)d_in[19];
    const float* o_w      = (const float*)d_in[20];
    const float* o_b      = (const float*)d_in[21];
    const float* log_tau  = (const float*)d_in[22];
    const float* gate_w   = (const float*)d_in[23];
    const float* gate_b   = (const float*)d_in[24];
    float* outp = (float*)d_out;

    const int M = Bsz * Lseq;          // 4096
    float* ws = (float*)d_ws;
    size_t off = 0;
    float* xn    = ws + off; off += (size_t)M * Dm;
    float* xm    = ws + off; off += (size_t)M * DIm;      // in_proj first half, row-major
    float* zT    = ws + off; off += (size_t)DIm * M;      // in_proj second half, time-major
    float* xcT   = ws + off; off += (size_t)DIm * M;      // conv output, time-major
    float* dbc   = ws + off; off += (size_t)M * 144;
    float* dtmT  = ws + off; off += (size_t)DIm * M;      // dt, time-major
    float* yT    = ws + off; off += (size_t)DIm * M;
    float* xd2   = ws + off; off += (size_t)Bsz * 512 * Dm;
    float* xd4   = ws + off; off += (size_t)Bsz * 256 * Dm;
    float* xd8   = ws + off; off += (size_t)Bsz * 128 * Dm;
    float* qd2   = ws + off; off += (size_t)Bsz * 512 * Dm;
    float* qd4   = ws + off; off += (size_t)Bsz * 256 * Dm;
    float* qd8   = ws + off; off += (size_t)Bsz * 128 * Dm;
    float* qcat  = ws + off; off += (size_t)M * 4 * Dm;   // reused: attn partials, then scan hloc/Pc
    float* qbuf  = ws + off; off += (size_t)M * Dm;       // reused (w/ kmat): Hinit
    float* kmat  = ws + off; off += (size_t)M * Dm;
    float* vmat  = ws + off; off += (size_t)M * Dm;
    float* attn  = ws + off; off += (size_t)M * Dm;
    float* cat2  = ws + off; off += (size_t)M * 2 * Dm;   // [ssm_o | ssd_o]; xc row-major aliases here
    float* gpre  = ws + off; off += (size_t)M * Dm;
    float* xc    = cat2;    // row-major conv output, dead before cat2 is first written (step 8)

    // 1. LayerNorm
    ln_kernel<<<M, 256, 0, stream>>>(x, ln_g, ln_b, xn);

    // 2. in_proj GEMM, split: xm row-major; z time-major (transC)
    gemm_bf16<<<dim3(8, 64), 256, 0, stream>>>(xn, Dm, 1, in_proj_w, Dm,
        nullptr, xm, DIm, M, DIm, Dm, 0, 0);
    gemm_bf16<<<dim3(8, 64), 256, 0, stream>>>(xn, Dm, 1, in_proj_w + (size_t)DIm * Dm, Dm,
        nullptr, zT, M, M, DIm, Dm, 0, 1);

    // 3. k / v projections
    gemm_bf16<<<dim3(4, 64), 256, 0, stream>>>(xn, Dm, 1, k_w, Dm, k_b, kmat, Dm, M, Dm, Dm, 0, 0);
    gemm_bf16<<<dim3(4, 64), 256, 0, stream>>>(xn, Dm, 1, v_w, Dm, v_b, vmat, Dm, M, Dm, Dm, 0, 0);

    // 4. multi-scale q
    gemm_bf16<<<dim3(4, 64), 256, 0, stream>>>(xn, Dm, 1, mq_w, Dm, mq_b, qcat, 4 * Dm, M, Dm, Dm, 0, 0);
    halve_kernel<<<(Bsz * 512 * Dm + 255) / 256, 256, 0, stream>>>(xn, xd2, 512);
    halve_kernel<<<(Bsz * 256 * Dm + 255) / 256, 256, 0, stream>>>(xd2, xd4, 256);
    halve_kernel<<<(Bsz * 128 * Dm + 255) / 256, 256, 0, stream>>>(xd4, xd8, 128);
    gemm_bf16<<<dim3(4, 32), 256, 0, stream>>>(xd2, Dm, 1, mq_w + 1 * Dm * Dm, Dm,
        mq_b + 1 * Dm, qd2, Dm, Bsz * 512, Dm, Dm, 0, 0);
    gemm_bf16<<<dim3(4, 16), 256, 0, stream>>>(xd4, Dm, 1, mq_w + 2 * Dm * Dm, Dm,
        mq_b + 2 * Dm, qd4, Dm, Bsz * 256, Dm, Dm, 0, 0);
    gemm_bf16<<<dim3(4, 8), 256, 0, stream>>>(xd8, Dm, 1, mq_w + 3 * Dm * Dm, Dm,
        mq_b + 3 * Dm, qd8, Dm, Bsz * 128, Dm, Dm, 0, 0);
    interp_kernel<<<(M * Dm + 255) / 256, 256, 0, stream>>>(qd2, qcat, 512, 1);
    interp_kernel<<<(M * Dm + 255) / 256, 256, 0, stream>>>(qd4, qcat, 256, 2);
    interp_kernel<<<(M * Dm + 255) / 256, 256, 0, stream>>>(qd8, qcat, 128, 3);
    gemm_bf16<<<dim3(4, 64), 256, 0, stream>>>(qcat, 4 * Dm, 1, fuse_w, 4 * Dm,
        fuse_b, qbuf, Dm, M, Dm, 4 * Dm, 0, 0);

    // 5. causal conv + SiLU (xc row-major into cat2 alias + xcT time-major)
    conv_silu_kernel<<<512, 256, 0, stream>>>(xm, conv_w, conv_b, xc, xcT);

    // 6. x_proj GEMM (N=144, K=512), reads xc row-major
    gemm_bf16<<<dim3(3, 64), 256, 0, stream>>>(xc, DIm, 1, x_proj_w, DIm,
        nullptr, dbc, 144, M, 144, DIm, 0, 0);

    // 7. dt GEMM + softplus (K=16, fp32), time-major output
    gemm_f32<<<dim3(8, 64), 256, 0, stream>>>(dbc, 144, 1, dt_w, DTRm,
        dt_b, dtmT, M, M, DIm, DTRm, 1, 0, 1);

    // 8. attention, 4-way K-split (partials in dead qcat) + combine
    attn_split<<<Bsz * Hh * 4 * 4, 256, 0, stream>>>(qbuf, kmat, vmat, log_tau, qcat);
    attn_combine<<<(M * Dm + 255) / 256, 256, 0, stream>>>(qcat, log_tau, attn);
    gemm_bf16<<<dim3(4, 64), 256, 0, stream>>>(attn, Dm, 1, o_w, Dm, o_b,
        cat2 + 256, 2 * Dm, M, Dm, Dm, 0, 0);

    // 9. chunk-parallel selective scan (time-major operands)
    float* hloc  = qcat;
    float* Pc    = qcat + (size_t)NCH * NCHK * Ssz;
    float* Hinit = qbuf;
    scan_pass1<<<(NCH * NCHK) / 4, 256, 0, stream>>>(xcT, dtmT, dbc, A_log, hloc, Pc);
    scan_combine<<<NCH / 4, 256, 0, stream>>>(hloc, Pc, Hinit);
    scan_pass3<<<(NCH * NCHK) / 4, 256, 0, stream>>>(xcT, dtmT, zT, dbc, A_log, D_ssm, Hinit, yT);

    // 10. out GEMM (A transposed storage yT (DI, B*L)) -> cat2 cols 0..255
    gemm_bf16<<<dim3(4, 64), 256, 0, stream>>>(yT, 1, M, out_w, DIm,
        nullptr, cat2, 2 * Dm, M, Dm, DIm, 0, 0);

    // 11. single gate GEMM over concat [ssm|ssd] (K=512)
    gemm_bf16<<<dim3(4, 64), 256, 0, stream>>>(cat2, 2 * Dm, 1, gate_w, 2 * Dm,
        gate_b, gpre, Dm, M, Dm, 2 * Dm, 0, 0);

    // 12. sigmoid gate + residual
    final_kernel<<<(M * Dm + 255) / 256, 256, 0, stream>>>(x, gpre, cat2, outp);
}

// Round 6
// 487.093 us; speedup vs baseline: 3.1589x; 1.1245x over previous
//
#include <hip/hip_runtime.h>
#include <math.h>

#define Bsz 4
#define Lseq 1024
#define Dm 256
#define Hh 16
#define HDm 16
#define DIm 512
#define Ssz 64
#define KCm 4
#define DTRm 16
#define NCH (Bsz * DIm)      // 2048 channels
#define CHK 64               // mamba-scan chunk length
#define NCHK (Lseq / CHK)    // 16 chunks
#define CHA 32               // attention-scan chunk length
#define NCA (Lseq / CHA)     // 32 chunks

typedef __attribute__((ext_vector_type(8))) short s8v;
typedef __attribute__((ext_vector_type(4))) float f4v;

static __device__ __forceinline__ float wave_sum(float v) {
    #pragma unroll
    for (int m = 32; m >= 1; m >>= 1) v += __shfl_xor(v, m, 64);
    return v;
}

static __device__ __forceinline__ short f2bf(float f) {
    unsigned int u = __float_as_uint(f);
    u = (u + 0x7fffu + ((u >> 16) & 1u)) >> 16;
    return (short)u;
}

static __device__ __forceinline__ s8v pack8(float4 a, float4 b) {
    s8v v;
    v[0] = f2bf(a.x); v[1] = f2bf(a.y); v[2] = f2bf(a.z); v[3] = f2bf(a.w);
    v[4] = f2bf(b.x); v[5] = f2bf(b.y); v[6] = f2bf(b.z); v[7] = f2bf(b.w);
    return v;
}

// ---------------- LayerNorm ----------------
__global__ __launch_bounds__(256) void ln_kernel(const float* __restrict__ x,
                                                 const float* __restrict__ g,
                                                 const float* __restrict__ b,
                                                 float* __restrict__ xn) {
    int row = blockIdx.x;
    int tid = threadIdx.x;
    __shared__ float red[8];
    float v = x[(size_t)row * Dm + tid];
    float s = wave_sum(v);
    int wid = tid >> 6, lane = tid & 63;
    if (lane == 0) red[wid] = s;
    __syncthreads();
    float mean = (red[0] + red[1] + red[2] + red[3]) * (1.0f / Dm);
    float dv = v - mean;
    float s2 = wave_sum(dv * dv);
    if (lane == 0) red[4 + wid] = s2;
    __syncthreads();
    float var = (red[4] + red[5] + red[6] + red[7]) * (1.0f / Dm);
    float inv = rsqrtf(var + 1e-5f);
    xn[(size_t)row * Dm + tid] = dv * inv * g[tid] + b[tid];
}

// ---------------- avg-pool by 2 along t ----------------
__global__ void halve_kernel(const float* __restrict__ in, float* __restrict__ out, int Lo) {
    int idx = blockIdx.x * blockDim.x + threadIdx.x;
    int total = Bsz * Lo * Dm;
    if (idx >= total) return;
    int d = idx % Dm;
    int j = (idx / Dm) % Lo;
    int b = idx / (Dm * Lo);
    const float* p = in + ((size_t)(b * 2 * Lo + 2 * j) * Dm + d);
    out[idx] = 0.5f * (p[0] + p[Dm]);
}

// ---------------- linear interpolation back to L ----------------
__global__ void interp_kernel(const float* __restrict__ qd, float* __restrict__ qcat,
                              int Lin, int seg) {
    int idx = blockIdx.x * blockDim.x + threadIdx.x;
    if (idx >= Bsz * Lseq * Dm) return;
    int d = idx % Dm;
    int t = (idx / Dm) % Lseq;
    int b = idx / (Dm * Lseq);
    float pos = (t + 0.5f) * ((float)Lin / (float)Lseq) - 0.5f;
    pos = fminf(fmaxf(pos, 0.0f), (float)(Lin - 1));
    int lo = (int)floorf(pos);
    int hi = min(lo + 1, Lin - 1);
    float w = pos - (float)lo;
    float v = qd[((size_t)(b * Lin + lo)) * Dm + d] * (1.0f - w)
            + qd[((size_t)(b * Lin + hi)) * Dm + d] * w;
    qcat[((size_t)(b * Lseq + t)) * (4 * Dm) + seg * Dm + d] = v;
}

// ---------------- causal depthwise conv + SiLU; writes xc (row-major) AND xcT (time-major) ----------------
__global__ __launch_bounds__(256) void conv_silu_kernel(const float* __restrict__ xm,
                                                        const float* __restrict__ cw,
                                                        const float* __restrict__ cb,
                                                        float* __restrict__ xc,
                                                        float* __restrict__ xcT) {
    __shared__ float tile[64][65];
    int blk = blockIdx.x;           // 512 blocks
    int cblk = blk & 7;
    int tblk = (blk >> 3) & 15;
    int b = blk >> 7;
    int c0 = cblk * 64, t0 = tblk * 64;
    int cc = threadIdx.x & 63;
    int tw = threadIdx.x >> 6;
    int c = c0 + cc;
    float w0 = cw[c * 4 + 0], w1 = cw[c * 4 + 1], w2 = cw[c * 4 + 2], w3 = cw[c * 4 + 3];
    float bias = cb[c];
    #pragma unroll 4
    for (int i = 0; i < 16; i++) {
        int tl = tw * 16 + i;
        int t = t0 + tl;
        const float* base = xm + ((size_t)(b * Lseq + t)) * DIm + c;
        float acc = bias + base[0] * w3;
        if (t >= 3) {
            acc += base[-3 * DIm] * w0 + base[-2 * DIm] * w1 + base[-1 * DIm] * w2;
        } else {
            if (t >= 1) acc += base[-1 * DIm] * w2;
            if (t >= 2) acc += base[-2 * DIm] * w1;
        }
        float r = acc / (1.0f + __expf(-acc));
        xc[((size_t)(b * Lseq + t)) * DIm + c] = r;
        tile[tl][cc] = r;
    }
    __syncthreads();
    int tcol = threadIdx.x & 63;
    int crow0 = threadIdx.x >> 6;
    #pragma unroll 4
    for (int j = 0; j < 16; j++) {
        int crow = crow0 * 16 + j;
        xcT[((size_t)(c0 + crow)) * (Bsz * Lseq) + b * Lseq + t0 + tcol] = tile[tcol][crow];
    }
}

// ======= bf16 MFMA GEMM: C = A(M,K) * W(N,K)^T + bias;  transC: C[n*ldc + m] =======
__global__ __launch_bounds__(256) void gemm_bf16(const float* __restrict__ A, int lda_m, int lda_k,
                                                 const float* __restrict__ W, int ldw,
                                                 const float* __restrict__ bias,
                                                 float* __restrict__ C, int ldc,
                                                 int M, int N, int K, int accum, int transC) {
    __shared__ unsigned short As[64][40];
    __shared__ unsigned short Ws[64][40];
    int tid = threadIdx.x;
    int wave = tid >> 6, lane = tid & 63;
    int quad = lane >> 4, r = lane & 15;
    int m0 = blockIdx.y * 64, n0 = blockIdx.x * 64;
    int mo = (wave >> 1) * 32, no = (wave & 1) * 32;
    f4v acc[2][2];
    #pragma unroll
    for (int i = 0; i < 2; i++)
        #pragma unroll
        for (int j = 0; j < 2; j++) acc[i][j] = (f4v){0.f, 0.f, 0.f, 0.f};

    for (int k0 = 0; k0 < K; k0 += 32) {
        if (lda_k == 1) {
            int m = tid >> 2, kk = (tid & 3) * 8;
            const float* ap = A + (size_t)(m0 + m) * lda_m + k0 + kk;
            float4 a0 = *(const float4*)ap;
            float4 a1 = *(const float4*)(ap + 4);
            *(s8v*)&As[m][kk] = pack8(a0, a1);
        } else {
            int k = tid >> 3, m8 = (tid & 7) * 8;
            const float* ap = A + (size_t)(k0 + k) * lda_k + m0 + m8;
            float4 a0 = *(const float4*)ap;
            float4 a1 = *(const float4*)(ap + 4);
            float av[8] = {a0.x, a0.y, a0.z, a0.w, a1.x, a1.y, a1.z, a1.w};
            #pragma unroll
            for (int i = 0; i < 8; i++) As[m8 + i][k] = (unsigned short)f2bf(av[i]);
        }
        {
            int n = tid >> 2, kk = (tid & 3) * 8;
            s8v pv;
            if (n0 + n < N) {
                const float* wp = W + (size_t)(n0 + n) * ldw + k0 + kk;
                float4 w0 = *(const float4*)wp;
                float4 w1 = *(const float4*)(wp + 4);
                pv = pack8(w0, w1);
            } else {
                pv = (s8v){0, 0, 0, 0, 0, 0, 0, 0};
            }
            *(s8v*)&Ws[n][kk] = pv;
        }
        __syncthreads();
        s8v af[2], bf[2];
        #pragma unroll
        for (int i = 0; i < 2; i++) af[i] = *(const s8v*)&As[mo + i * 16 + r][quad * 8];
        #pragma unroll
        for (int j = 0; j < 2; j++) bf[j] = *(const s8v*)&Ws[no + j * 16 + r][quad * 8];
        #pragma unroll
        for (int i = 0; i < 2; i++)
            #pragma unroll
            for (int j = 0; j < 2; j++)
                acc[i][j] = __builtin_amdgcn_mfma_f32_16x16x32_bf16(af[i], bf[j], acc[i][j], 0, 0, 0);
        __syncthreads();
    }
    #pragma unroll
    for (int i = 0; i < 2; i++)
        #pragma unroll
        for (int j = 0; j < 2; j++)
            #pragma unroll
            for (int reg = 0; reg < 4; reg++) {
                int m = m0 + mo + i * 16 + quad * 4 + reg;
                int n = n0 + no + j * 16 + r;
                if (n >= N) continue;
                float v = acc[i][j][reg];
                if (bias) v += bias[n];
                float* cp = transC ? (C + (size_t)n * ldc + m) : (C + (size_t)m * ldc + n);
                if (accum) v += *cp;
                *cp = v;
            }
}

// ---------------- small fp32 GEMM (K=16 dt projection); transC supported ----------------
__global__ __launch_bounds__(256) void gemm_f32(const float* __restrict__ A, int lda_m, int lda_k,
                                                const float* __restrict__ W, int ldw,
                                                const float* __restrict__ bias,
                                                float* __restrict__ C, int ldc,
                                                int M, int N, int K, int act, int accum, int transC) {
    __shared__ float As[16][72];
    __shared__ float Ws[16][72];
    int tid = threadIdx.x;
    int m0 = blockIdx.y * 64, n0 = blockIdx.x * 64;
    int tx = tid & 15, ty = tid >> 4;
    float acc[4][4] = {};
    for (int k0 = 0; k0 < K; k0 += 16) {
        {
            int ml = tid >> 2, kl = (tid & 3) * 4;
            const float4 av = *(const float4*)(A + (size_t)(m0 + ml) * lda_m + k0 + kl);
            As[kl + 0][ml] = av.x; As[kl + 1][ml] = av.y;
            As[kl + 2][ml] = av.z; As[kl + 3][ml] = av.w;
        }
        {
            int nl = tid >> 2, kl = (tid & 3) * 4;
            float4 wv;
            if (n0 + nl < N) wv = *(const float4*)(W + (size_t)(n0 + nl) * ldw + k0 + kl);
            else wv = make_float4(0.f, 0.f, 0.f, 0.f);
            Ws[kl + 0][nl] = wv.x; Ws[kl + 1][nl] = wv.y;
            Ws[kl + 2][nl] = wv.z; Ws[kl + 3][nl] = wv.w;
        }
        __syncthreads();
        #pragma unroll
        for (int kk = 0; kk < 16; kk++) {
            float4 av = *(const float4*)&As[kk][ty * 4];
            float4 bv = *(const float4*)&Ws[kk][tx * 4];
            float a[4] = {av.x, av.y, av.z, av.w};
            float bb[4] = {bv.x, bv.y, bv.z, bv.w};
            #pragma unroll
            for (int im = 0; im < 4; im++)
                #pragma unroll
                for (int in = 0; in < 4; in++)
                    acc[im][in] = fmaf(a[im], bb[in], acc[im][in]);
        }
        __syncthreads();
    }
    #pragma unroll
    for (int in = 0; in < 4; in++) {
        int n = n0 + tx * 4 + in;
        if (n >= N) continue;
        #pragma unroll
        for (int im = 0; im < 4; im++) {
            int m = m0 + ty * 4 + im;
            float v = acc[im][in];
            if (bias) v += bias[n];
            if (act == 1) v = fmaxf(v, 0.0f) + log1pf(expf(-fabsf(v)));
            float* cp = transC ? (C + (size_t)n * ldc + m) : (C + (size_t)m * ldc + n);
            if (accum) v += *cp;
            *cp = v;
        }
    }
}

// ======== chunk-parallel selective scan (time-major operands) ========
__global__ __launch_bounds__(256) void scan_pass1(const float* __restrict__ xcT,
                                                  const float* __restrict__ dtmT,
                                                  const float* __restrict__ dbc,
                                                  const float* __restrict__ A_log,
                                                  float* __restrict__ hloc,
                                                  float* __restrict__ Pc) {
    int wave = blockIdx.x * 4 + (threadIdx.x >> 6);
    int lane = threadIdx.x & 63;
    int ch = wave & (NCH - 1);
    int c  = wave >> 11;
    int b = ch >> 9, d = ch & (DIm - 1);
    float As = -__expf(A_log[d * Ssz + lane]);
    int base_m = b * Lseq + c * CHK;
    float dt_vec = dtmT[(size_t)d * (Bsz * Lseq) + base_m + lane];
    float x_vec  = xcT [(size_t)d * (Bsz * Lseq) + base_m + lane];
    float ux = dt_vec * x_vec;
    const float* Bp = dbc + (size_t)base_m * 144 + DTRm + lane;
    float h = 0.0f, P = 1.0f;
    #pragma unroll 8
    for (int t = 0; t < CHK; t++) {
        float Bt = *Bp; Bp += 144;
        float dtv = __shfl(dt_vec, t, 64);
        float u   = __shfl(ux, t, 64);
        float dA = __expf(dtv * As);
        h = fmaf(dA, h, u * Bt);
        P *= dA;
    }
    size_t o = ((size_t)ch * NCHK + c) * Ssz + lane;
    hloc[o] = h;
    Pc[o] = P;
}

__global__ __launch_bounds__(256) void scan_combine(const float* __restrict__ hloc,
                                                    const float* __restrict__ Pc,
                                                    float* __restrict__ Hinit) {
    int wave = blockIdx.x * 4 + (threadIdx.x >> 6);
    int lane = threadIdx.x & 63;
    size_t base = (size_t)wave * NCHK * Ssz + lane;
    float H = 0.0f;
    #pragma unroll
    for (int c = 0; c < NCHK; c++) {
        size_t o = base + (size_t)c * Ssz;
        Hinit[o] = H;
        H = fmaf(Pc[o], H, hloc[o]);
    }
}

__global__ __launch_bounds__(256) void scan_pass3(const float* __restrict__ xcT,
                                                  const float* __restrict__ dtmT,
                                                  const float* __restrict__ zT,
                                                  const float* __restrict__ dbc,
                                                  const float* __restrict__ A_log,
                                                  const float* __restrict__ D_ssm,
                                                  const float* __restrict__ Hinit,
                                                  float* __restrict__ yT) {
    __shared__ float hCs[4][16][68];
    int wid = threadIdx.x >> 6;
    int lane = threadIdx.x & 63;
    int wave = blockIdx.x * 4 + wid;
    int ch = wave & (NCH - 1);
    int c  = wave >> 11;
    int b = ch >> 9, d = ch & (DIm - 1);
    float As = -__expf(A_log[d * Ssz + lane]);
    float Dd = D_ssm[d];
    int base_m = b * Lseq + c * CHK;
    float dt_vec = dtmT[(size_t)d * (Bsz * Lseq) + base_m + lane];
    float x_vec  = xcT [(size_t)d * (Bsz * Lseq) + base_m + lane];
    float zown   = zT  [(size_t)d * (Bsz * Lseq) + base_m + lane];
    float ux = dt_vec * x_vec;
    const float* Bp = dbc + (size_t)base_m * 144 + DTRm + lane;
    const float* Cp = Bp + Ssz;
    float h = Hinit[((size_t)ch * NCHK + c) * Ssz + lane];
    float yred = 0.0f;
    int tl = lane >> 2;
    int so = (lane & 3) * 16;
    for (int tb = 0; tb < 4; tb++) {
        #pragma unroll
        for (int j = 0; j < 16; j++) {
            int t = tb * 16 + j;
            float Bt = *Bp; Bp += 144;
            float Ct = *Cp; Cp += 144;
            float dtv = __shfl(dt_vec, t, 64);
            float u   = __shfl(ux, t, 64);
            float dA = __expf(dtv * As);
            h = fmaf(dA, h, u * Bt);
            hCs[wid][j][lane] = h * Ct;
        }
        const float* bp = &hCs[wid][tl][so];
        float4 a0 = *(const float4*)(bp + 0);
        float4 a1 = *(const float4*)(bp + 4);
        float4 a2 = *(const float4*)(bp + 8);
        float4 a3 = *(const float4*)(bp + 12);
        float part = ((a0.x + a0.y) + (a0.z + a0.w)) + ((a1.x + a1.y) + (a1.z + a1.w))
                   + ((a2.x + a2.y) + (a2.z + a2.w)) + ((a3.x + a3.y) + (a3.z + a3.w));
        part += __shfl_xor(part, 1, 64);
        part += __shfl_xor(part, 2, 64);
        float got = __shfl(part, ((lane - tb * 16) << 2) & 63, 64);
        if ((lane >> 4) == tb) yred = got;
    }
    float yg = (yred + x_vec * Dd) * (zown / (1.0f + __expf(-zown)));
    yT[(size_t)d * (Bsz * Lseq) + base_m + lane] = yg;
}

// ======== linear-attention reformulation of the decay-masked SSD ========
// mask(i,j) = 1 for j>=i, r^(i-j) for j<i  (r = exp(-1/tau))
// out_i = q_i @ (KVtot - U_i + T_i) * scale / denom_i
// U_i = sum_{j<=i} k_j v_j^T (prefix), T_i = r*T_{i-1} + k_i v_i^T (decayed prefix)
// Lane layout: c = lane&15 (column), g = lane>>4; lane holds rows 4g..4g+3 of U,T,KV.
__global__ __launch_bounds__(256) void attn_p1(const float* __restrict__ k,
                                               const float* __restrict__ v,
                                               const float* __restrict__ log_tau,
                                               float* __restrict__ loc) {
    __shared__ float Ksh[4][CHA][20];
    __shared__ float Vsh[4][CHA][16];
    int wid = threadIdx.x >> 6, lane = threadIdx.x & 63;
    int wave = blockIdx.x * 4 + wid;     // 0..2047
    int bh = wave >> 5;
    int c  = wave & 31;
    int b = bh >> 4, h = bh & 15;
    float inv_tau = __expf(-log_tau[h]);
    float rdec = __expf(-inv_tau);
    int t0 = c * CHA;
    int row = lane >> 1, hf = (lane & 1) * 8;
    const float* kp = k + ((size_t)(b * Lseq + t0 + row)) * Dm + h * HDm + hf;
    const float* vp = v + ((size_t)(b * Lseq + t0 + row)) * Dm + h * HDm + hf;
    *(float4*)&Ksh[wid][row][hf]     = *(const float4*)kp;
    *(float4*)&Ksh[wid][row][hf + 4] = *(const float4*)(kp + 4);
    *(float4*)&Vsh[wid][row][hf]     = *(const float4*)vp;
    *(float4*)&Vsh[wid][row][hf + 4] = *(const float4*)(vp + 4);
    int g = lane >> 4, cc = lane & 15;
    float4 U = {0.f, 0.f, 0.f, 0.f}, T = {0.f, 0.f, 0.f, 0.f};
    #pragma unroll 8
    for (int s = 0; s < CHA; s++) {
        float4 kf = *(const float4*)&Ksh[wid][s][4 * g];
        float vv = Vsh[wid][s][cc];
        float u0 = kf.x * vv, u1 = kf.y * vv, u2 = kf.z * vv, u3 = kf.w * vv;
        U.x += u0; U.y += u1; U.z += u2; U.w += u3;
        T.x = fmaf(rdec, T.x, u0); T.y = fmaf(rdec, T.y, u1);
        T.z = fmaf(rdec, T.z, u2); T.w = fmaf(rdec, T.w, u3);
    }
    float* op = loc + ((size_t)bh * NCA + c) * 512;
    *(float4*)(op + lane * 4) = U;
    *(float4*)(op + 256 + lane * 4) = T;
}

__global__ __launch_bounds__(256) void attn_p2(const float* __restrict__ loc,
                                               const float* __restrict__ log_tau,
                                               float* __restrict__ init,
                                               float* __restrict__ kvtot) {
    int bh = blockIdx.x, e = threadIdx.x;
    float inv_tau = __expf(-log_tau[bh & 15]);
    float rp = __expf(-(float)CHA * inv_tau);   // r^CHA
    const float* lp = loc + (size_t)bh * NCA * 512;
    float* ip = init + (size_t)bh * NCA * 512;
    float Ua = 0.f, Ta = 0.f;
    #pragma unroll 8
    for (int c = 0; c < NCA; c++) {
        ip[c * 512 + e] = Ua;
        Ua += lp[c * 512 + e];
        ip[c * 512 + 256 + e] = Ta;
        Ta = fmaf(rp, Ta, lp[c * 512 + 256 + e]);
    }
    kvtot[bh * 256 + e] = Ua;
}

__global__ __launch_bounds__(256) void attn_p3(const float* __restrict__ q,
                                               const float* __restrict__ k,
                                               const float* __restrict__ v,
                                               const float* __restrict__ log_tau,
                                               const float* __restrict__ init,
                                               const float* __restrict__ kvtot,
                                               float* __restrict__ out) {
    __shared__ float Ksh[4][CHA][20];
    __shared__ float Qsh[4][CHA][20];
    __shared__ float Vsh[4][CHA][16];
    __shared__ float Ysh[4][CHA][16];
    int wid = threadIdx.x >> 6, lane = threadIdx.x & 63;
    int wave = blockIdx.x * 4 + wid;
    int bh = wave >> 5;
    int c  = wave & 31;
    int b = bh >> 4, h = bh & 15;
    float inv_tau = __expf(-log_tau[h]);
    float rdec = __expf(-inv_tau);
    int t0 = c * CHA;
    int row = lane >> 1, hf = (lane & 1) * 8;
    const float* kp = k + ((size_t)(b * Lseq + t0 + row)) * Dm + h * HDm + hf;
    const float* vp = v + ((size_t)(b * Lseq + t0 + row)) * Dm + h * HDm + hf;
    const float* qp = q + ((size_t)(b * Lseq + t0 + row)) * Dm + h * HDm + hf;
    *(float4*)&Ksh[wid][row][hf]     = *(const float4*)kp;
    *(float4*)&Ksh[wid][row][hf + 4] = *(const float4*)(kp + 4);
    *(float4*)&Vsh[wid][row][hf]     = *(const float4*)vp;
    *(float4*)&Vsh[wid][row][hf + 4] = *(const float4*)(vp + 4);
    *(float4*)&Qsh[wid][row][hf]     = *(const float4*)qp;
    *(float4*)&Qsh[wid][row][hf + 4] = *(const float4*)(qp + 4);
    int g = lane >> 4, cc = lane & 15;
    size_t ibase = ((size_t)bh * NCA + c) * 512;
    float4 U  = *(const float4*)(init + ibase + lane * 4);
    float4 T  = *(const float4*)(init + ibase + 256 + lane * 4);
    float4 KV = *(const float4*)(kvtot + bh * 256 + lane * 4);
    float om = 1.0f - rdec;
    float geom = (om > 1e-8f) ? (1.0f - __expf(-inv_tau * (float)t0)) / om : (float)t0; // geom_{t0-1}
    #pragma unroll 4
    for (int s = 0; s < CHA; s++) {
        int i = t0 + s;
        geom = fmaf(geom, rdec, 1.0f);           // geom_i
        float4 kf = *(const float4*)&Ksh[wid][s][4 * g];
        float4 qf = *(const float4*)&Qsh[wid][s][4 * g];
        float vv = Vsh[wid][s][cc];
        float u0 = kf.x * vv, u1 = kf.y * vv, u2 = kf.z * vv, u3 = kf.w * vv;
        U.x += u0; U.y += u1; U.z += u2; U.w += u3;
        T.x = fmaf(rdec, T.x, u0); T.y = fmaf(rdec, T.y, u1);
        T.z = fmaf(rdec, T.z, u2); T.w = fmaf(rdec, T.w, u3);
        float p;
        p = qf.x * (KV.x - U.x + T.x);
        p = fmaf(qf.y, KV.y - U.y + T.y, p);
        p = fmaf(qf.z, KV.z - U.z + T.z, p);
        p = fmaf(qf.w, KV.w - U.w + T.w, p);
        p += __shfl_xor(p, 16, 64);
        p += __shfl_xor(p, 32, 64);
        float deno = fmaxf((float)(Lseq - 1 - i) + geom, 1e-6f);
        float yv = p * (0.25f / deno);
        if (lane < 16) Ysh[wid][s][lane] = yv;
    }
    float* op = out + ((size_t)(b * Lseq + t0 + row)) * Dm + h * HDm + hf;
    *(float4*)op       = *(const float4*)&Ysh[wid][row][hf];
    *(float4*)(op + 4) = *(const float4*)&Ysh[wid][row][hf + 4];
}

// ---------------- gate + residual (reads from cat2 [ssm | ssd]) ----------------
__global__ void final_kernel(const float* __restrict__ x, const float* __restrict__ gpre,
                             const float* __restrict__ cat2, float* __restrict__ out) {
    int idx = blockIdx.x * blockDim.x + threadIdx.x;
    if (idx >= Bsz * Lseq * Dm) return;
    int m = idx >> 8, d = idx & 255;
    float g = 1.0f / (1.0f + __expf(-gpre[idx]));
    float ssm = cat2[(size_t)m * 512 + d];
    float ssd = cat2[(size_t)m * 512 + 256 + d];
    out[idx] = x[idx] + g * ssm + (1.0f - g) * ssd;
}

extern "C" void kernel_launch(void* const* d_in, const int* in_sizes, int n_in,
                              void* d_out, int out_size, void* d_ws, size_t ws_size,
                              hipStream_t stream) {
    const float* x        = (const float*)d_in[0];
    const float* ln_g     = (const float*)d_in[1];
    const float* ln_b     = (const float*)d_in[2];
    const float* mq_w     = (const float*)d_in[3];
    const float* mq_b     = (const float*)d_in[4];
    const float* fuse_w   = (const float*)d_in[5];
    const float* fuse_b   = (const float*)d_in[6];
    const float* in_proj_w= (const float*)d_in[7];
    const float* conv_w   = (const float*)d_in[8];
    const float* conv_b   = (const float*)d_in[9];
    const float* x_proj_w = (const float*)d_in[10];
    const float* dt_w     = (const float*)d_in[11];
    const float* dt_b     = (const float*)d_in[12];
    const float* A_log    = (const float*)d_in[13];
    const float* D_ssm    = (const float*)d_in[14];
    const float* out_w    = (const float*)d_in[15];
    const float* k_w      = (const float*)d_in[16];
    const float* k_b      = (const float*)d_in[17];
    const float* v_w      = (const float*)d_in[18];
    const float* v_b      = (const float*)d_in[19];
    const float* o_w      = (const float*)d_in[20];
    const float* o_b      = (const float*)d_in[21];
    const float* log_tau  = (const float*)d_in[22];
    const float* gate_w   = (const float*)d_in[23];
    const float* gate_b   = (const float*)d_in[24];
    float* outp = (float*)d_out;

    const int M = Bsz * Lseq;          // 4096
    float* ws = (float*)d_ws;
    size_t off = 0;
    float* xn    = ws + off; off += (size_t)M * Dm;
    float* xm    = ws + off; off += (size_t)M * DIm;      // in_proj first half, row-major
    float* zT    = ws + off; off += (size_t)DIm * M;      // in_proj second half, time-major
    float* xcT   = ws + off; off += (size_t)DIm * M;      // conv output, time-major
    float* dbc   = ws + off; off += (size_t)M * 144;
    float* dtmT  = ws + off; off += (size_t)DIm * M;      // dt, time-major
    float* yT    = ws + off; off += (size_t)DIm * M;
    float* xd2   = ws + off; off += (size_t)Bsz * 512 * Dm;
    float* xd4   = ws + off; off += (size_t)Bsz * 256 * Dm;
    float* xd8   = ws + off; off += (size_t)Bsz * 128 * Dm;
    float* qd2   = ws + off; off += (size_t)Bsz * 512 * Dm;
    float* qd4   = ws + off; off += (size_t)Bsz * 256 * Dm;
    float* qd8   = ws + off; off += (size_t)Bsz * 128 * Dm;
    float* qcat  = ws + off; off += (size_t)M * 4 * Dm;   // reused: attn states, then scan hloc/Pc
    float* qbuf  = ws + off; off += (size_t)M * Dm;       // reused (w/ kmat): Hinit
    float* kmat  = ws + off; off += (size_t)M * Dm;
    float* vmat  = ws + off; off += (size_t)M * Dm;
    float* attn  = ws + off; off += (size_t)M * Dm;
    float* cat2  = ws + off; off += (size_t)M * 2 * Dm;   // [ssm_o | ssd_o]; xc row-major aliases here
    float* gpre  = ws + off; off += (size_t)M * Dm;
    float* xc    = cat2;    // row-major conv output, dead before cat2 is first written (step 8)

    // 1. LayerNorm
    ln_kernel<<<M, 256, 0, stream>>>(x, ln_g, ln_b, xn);

    // 2. in_proj GEMM, split: xm row-major; z time-major (transC)
    gemm_bf16<<<dim3(8, 64), 256, 0, stream>>>(xn, Dm, 1, in_proj_w, Dm,
        nullptr, xm, DIm, M, DIm, Dm, 0, 0);
    gemm_bf16<<<dim3(8, 64), 256, 0, stream>>>(xn, Dm, 1, in_proj_w + (size_t)DIm * Dm, Dm,
        nullptr, zT, M, M, DIm, Dm, 0, 1);

    // 3. k / v projections
    gemm_bf16<<<dim3(4, 64), 256, 0, stream>>>(xn, Dm, 1, k_w, Dm, k_b, kmat, Dm, M, Dm, Dm, 0, 0);
    gemm_bf16<<<dim3(4, 64), 256, 0, stream>>>(xn, Dm, 1, v_w, Dm, v_b, vmat, Dm, M, Dm, Dm, 0, 0);

    // 4. multi-scale q
    gemm_bf16<<<dim3(4, 64), 256, 0, stream>>>(xn, Dm, 1, mq_w, Dm, mq_b, qcat, 4 * Dm, M, Dm, Dm, 0, 0);
    halve_kernel<<<(Bsz * 512 * Dm + 255) / 256, 256, 0, stream>>>(xn, xd2, 512);
    halve_kernel<<<(Bsz * 256 * Dm + 255) / 256, 256, 0, stream>>>(xd2, xd4, 256);
    halve_kernel<<<(Bsz * 128 * Dm + 255) / 256, 256, 0, stream>>>(xd4, xd8, 128);
    gemm_bf16<<<dim3(4, 32), 256, 0, stream>>>(xd2, Dm, 1, mq_w + 1 * Dm * Dm, Dm,
        mq_b + 1 * Dm, qd2, Dm, Bsz * 512, Dm, Dm, 0, 0);
    gemm_bf16<<<dim3(4, 16), 256, 0, stream>>>(xd4, Dm, 1, mq_w + 2 * Dm * Dm, Dm,
        mq_b + 2 * Dm, qd4, Dm, Bsz * 256, Dm, Dm, 0, 0);
    gemm_bf16<<<dim3(4, 8), 256, 0, stream>>>(xd8, Dm, 1, mq_w + 3 * Dm * Dm, Dm,
        mq_b + 3 * Dm, qd8, Dm, Bsz * 128, Dm, Dm, 0, 0);
    interp_kernel<<<(M * Dm + 255) / 256, 256, 0, stream>>>(qd2, qcat, 512, 1);
    interp_kernel<<<(M * Dm + 255) / 256, 256, 0, stream>>>(qd4, qcat, 256, 2);
    interp_kernel<<<(M * Dm + 255) / 256, 256, 0, stream>>>(qd8, qcat, 128, 3);
    gemm_bf16<<<dim3(4, 64), 256, 0, stream>>>(qcat, 4 * Dm, 1, fuse_w, 4 * Dm,
        fuse_b, qbuf, Dm, M, Dm, 4 * Dm, 0, 0);

    // 5. causal conv + SiLU (xc row-major into cat2 alias + xcT time-major)
    conv_silu_kernel<<<512, 256, 0, stream>>>(xm, conv_w, conv_b, xc, xcT);

    // 6. x_proj GEMM (N=144, K=512), reads xc row-major
    gemm_bf16<<<dim3(3, 64), 256, 0, stream>>>(xc, DIm, 1, x_proj_w, DIm,
        nullptr, dbc, 144, M, 144, DIm, 0, 0);

    // 7. dt GEMM + softplus (K=16, fp32), time-major output
    gemm_f32<<<dim3(8, 64), 256, 0, stream>>>(dbc, 144, 1, dt_w, DTRm,
        dt_b, dtmT, M, M, DIm, DTRm, 1, 0, 1);

    // 8. linear-attention (chunk-parallel, exact reformulation); states in dead qcat
    float* aloc  = qcat;                                   // 64*32*512 = 1M floats
    float* ainit = qcat + (size_t)64 * NCA * 512;          // 1M floats
    float* kvtot = qcat + (size_t)2 * 64 * NCA * 512;      // 16K floats
    attn_p1<<<512, 256, 0, stream>>>(kmat, vmat, log_tau, aloc);
    attn_p2<<<64, 256, 0, stream>>>(aloc, log_tau, ainit, kvtot);
    attn_p3<<<512, 256, 0, stream>>>(qbuf, kmat, vmat, log_tau, ainit, kvtot, attn);
    gemm_bf16<<<dim3(4, 64), 256, 0, stream>>>(attn, Dm, 1, o_w, Dm, o_b,
        cat2 + 256, 2 * Dm, M, Dm, Dm, 0, 0);

    // 9. chunk-parallel selective scan (time-major operands; qcat free after attn_p3)
    float* hloc  = qcat;
    float* Pc    = qcat + (size_t)NCH * NCHK * Ssz;
    float* Hinit = qbuf;
    scan_pass1<<<(NCH * NCHK) / 4, 256, 0, stream>>>(xcT, dtmT, dbc, A_log, hloc, Pc);
    scan_combine<<<NCH / 4, 256, 0, stream>>>(hloc, Pc, Hinit);
    scan_pass3<<<(NCH * NCHK) / 4, 256, 0, stream>>>(xcT, dtmT, zT, dbc, A_log, D_ssm, Hinit, yT);

    // 10. out GEMM (A transposed storage yT (DI, B*L)) -> cat2 cols 0..255
    gemm_bf16<<<dim3(4, 64), 256, 0, stream>>>(yT, 1, M, out_w, DIm,
        nullptr, cat2, 2 * Dm, M, Dm, DIm, 0, 0);

    // 11. single gate GEMM over concat [ssm|ssd] (K=512)
    gemm_bf16<<<dim3(4, 64), 256, 0, stream>>>(cat2, 2 * Dm, 1, gate_w, 2 * Dm,
        gate_b, gpre, Dm, M, Dm, 2 * Dm, 0, 0);

    // 12. sigmoid gate + residual
    final_kernel<<<(M * Dm + 255) / 256, 256, 0, stream>>>(x, gpre, cat2, outp);
}

// Round 7
// 409.316 us; speedup vs baseline: 3.7592x; 1.1900x over previous
//
#include <hip/hip_runtime.h>
#include <math.h>

#define Bsz 4
#define Lseq 1024
#define Dm 256
#define Hh 16
#define HDm 16
#define DIm 512
#define Ssz 64
#define KCm 4
#define DTRm 16
#define NCH (Bsz * DIm)      // 2048 channels
#define CHK 64               // mamba-scan chunk length
#define NCHK (Lseq / CHK)    // 16 chunks
#define CHA 32               // attention-scan chunk length
#define NCA (Lseq / CHA)     // 32 chunks

typedef __attribute__((ext_vector_type(8))) short s8v;
typedef __attribute__((ext_vector_type(4))) float f4v;

static __device__ __forceinline__ float wave_sum(float v) {
    #pragma unroll
    for (int m = 32; m >= 1; m >>= 1) v += __shfl_xor(v, m, 64);
    return v;
}

static __device__ __forceinline__ short f2bf(float f) {
    unsigned int u = __float_as_uint(f);
    u = (u + 0x7fffu + ((u >> 16) & 1u)) >> 16;
    return (short)u;
}

static __device__ __forceinline__ s8v pack8(float4 a, float4 b) {
    s8v v;
    v[0] = f2bf(a.x); v[1] = f2bf(a.y); v[2] = f2bf(a.z); v[3] = f2bf(a.w);
    v[4] = f2bf(b.x); v[5] = f2bf(b.y); v[6] = f2bf(b.z); v[7] = f2bf(b.w);
    return v;
}

// ---------------- LayerNorm ----------------
__global__ __launch_bounds__(256) void ln_kernel(const float* __restrict__ x,
                                                 const float* __restrict__ g,
                                                 const float* __restrict__ b,
                                                 float* __restrict__ xn) {
    int row = blockIdx.x;
    int tid = threadIdx.x;
    __shared__ float red[8];
    float v = x[(size_t)row * Dm + tid];
    float s = wave_sum(v);
    int wid = tid >> 6, lane = tid & 63;
    if (lane == 0) red[wid] = s;
    __syncthreads();
    float mean = (red[0] + red[1] + red[2] + red[3]) * (1.0f / Dm);
    float dv = v - mean;
    float s2 = wave_sum(dv * dv);
    if (lane == 0) red[4 + wid] = s2;
    __syncthreads();
    float var = (red[4] + red[5] + red[6] + red[7]) * (1.0f / Dm);
    float inv = rsqrtf(var + 1e-5f);
    xn[(size_t)row * Dm + tid] = dv * inv * g[tid] + b[tid];
}

// ---------------- fused 3-level avg-pool ----------------
__global__ void halve3_kernel(const float* __restrict__ xn, float* __restrict__ xd2,
                              float* __restrict__ xd4, float* __restrict__ xd8) {
    int idx = blockIdx.x * blockDim.x + threadIdx.x;
    if (idx < 524288) {                       // xd2 (B,512,256)
        int d = idx & 255, j = (idx >> 8) & 511, b = idx >> 17;
        const float* p = xn + ((size_t)(b * 1024 + 2 * j) * 256 + d);
        xd2[idx] = 0.5f * (p[0] + p[256]);
    } else if (idx < 786432) {                // xd4 (B,256,256)
        int i = idx - 524288;
        int d = i & 255, j = (i >> 8) & 255, b = i >> 16;
        const float* p = xn + ((size_t)(b * 1024 + 4 * j) * 256 + d);
        xd4[i] = 0.25f * ((p[0] + p[256]) + (p[512] + p[768]));
    } else if (idx < 917504) {                // xd8 (B,128,256)
        int i = idx - 786432;
        int d = i & 255, j = (i >> 8) & 127, b = i >> 15;
        const float* p = xn + ((size_t)(b * 1024 + 8 * j) * 256 + d);
        xd8[i] = 0.125f * (((p[0] + p[256]) + (p[512] + p[768]))
                         + ((p[1024] + p[1280]) + (p[1536] + p[1792])));
    }
}

// ---------------- fused 3-segment linear interpolation ----------------
__global__ void interp3_kernel(const float* __restrict__ qd2, const float* __restrict__ qd4,
                               const float* __restrict__ qd8, float* __restrict__ qcat) {
    int idx = blockIdx.x * blockDim.x + threadIdx.x;
    if (idx >= 3 * Bsz * Lseq * Dm) return;
    int seg = idx >> 20;                      // /1048576
    int rem = idx & 1048575;
    int d = rem & 255;
    int t = (rem >> 8) & 1023;
    int b = rem >> 18;
    int Lin = 512 >> seg;
    const float* qd = (seg == 0) ? qd2 : (seg == 1) ? qd4 : qd8;
    float pos = (t + 0.5f) * ((float)Lin / (float)Lseq) - 0.5f;
    pos = fminf(fmaxf(pos, 0.0f), (float)(Lin - 1));
    int lo = (int)floorf(pos);
    int hi = min(lo + 1, Lin - 1);
    float w = pos - (float)lo;
    float v = qd[((size_t)(b * Lin + lo)) * Dm + d] * (1.0f - w)
            + qd[((size_t)(b * Lin + hi)) * Dm + d] * w;
    qcat[((size_t)(b * Lseq + t)) * (4 * Dm) + (seg + 1) * Dm + d] = v;
}

// ---------------- causal depthwise conv + SiLU; writes xc (row-major) AND xcT (time-major) ----------------
__global__ __launch_bounds__(256) void conv_silu_kernel(const float* __restrict__ xm,
                                                        const float* __restrict__ cw,
                                                        const float* __restrict__ cb,
                                                        float* __restrict__ xc,
                                                        float* __restrict__ xcT) {
    __shared__ float tile[64][65];
    int blk = blockIdx.x;           // 512 blocks
    int cblk = blk & 7;
    int tblk = (blk >> 3) & 15;
    int b = blk >> 7;
    int c0 = cblk * 64, t0 = tblk * 64;
    int cc = threadIdx.x & 63;
    int tw = threadIdx.x >> 6;
    int c = c0 + cc;
    float w0 = cw[c * 4 + 0], w1 = cw[c * 4 + 1], w2 = cw[c * 4 + 2], w3 = cw[c * 4 + 3];
    float bias = cb[c];
    #pragma unroll 4
    for (int i = 0; i < 16; i++) {
        int tl = tw * 16 + i;
        int t = t0 + tl;
        const float* base = xm + ((size_t)(b * Lseq + t)) * DIm + c;
        float acc = bias + base[0] * w3;
        if (t >= 3) {
            acc += base[-3 * DIm] * w0 + base[-2 * DIm] * w1 + base[-1 * DIm] * w2;
        } else {
            if (t >= 1) acc += base[-1 * DIm] * w2;
            if (t >= 2) acc += base[-2 * DIm] * w1;
        }
        float r = acc / (1.0f + __expf(-acc));
        xc[((size_t)(b * Lseq + t)) * DIm + c] = r;
        tile[tl][cc] = r;
    }
    __syncthreads();
    int tcol = threadIdx.x & 63;
    int crow0 = threadIdx.x >> 6;
    #pragma unroll 4
    for (int j = 0; j < 16; j++) {
        int crow = crow0 * 16 + j;
        xcT[((size_t)(c0 + crow)) * (Bsz * Lseq) + b * Lseq + t0 + tcol] = tile[tcol][crow];
    }
}

// ======= batched projection GEMM: 8 outputs off xn/xd* in ONE dispatch (K=256, no N guard) =======
__global__ __launch_bounds__(256) void proj8(const float* __restrict__ xn,
                                             const float* __restrict__ xd2,
                                             const float* __restrict__ xd4,
                                             const float* __restrict__ xd8,
                                             const float* __restrict__ in_proj_w,
                                             const float* __restrict__ k_w, const float* __restrict__ k_b,
                                             const float* __restrict__ v_w, const float* __restrict__ v_b,
                                             const float* __restrict__ mq_w, const float* __restrict__ mq_b,
                                             float* __restrict__ xm, float* __restrict__ zT,
                                             float* __restrict__ kmat, float* __restrict__ vmat,
                                             float* __restrict__ qcat, float* __restrict__ qd2,
                                             float* __restrict__ qd4, float* __restrict__ qd8) {
    __shared__ unsigned short As[64][40];
    __shared__ unsigned short Ws[64][40];
    int bx = blockIdx.x;
    const float* A; const float* W; const float* bias; float* C;
    int ldc, transC = 0, n0, m0;
    if (bx < 512) {            // xm = xn @ in_proj[0:512]^T
        A = xn; W = in_proj_w; bias = nullptr; C = xm; ldc = DIm;
        n0 = (bx & 7) * 64; m0 = (bx >> 3) * 64;
    } else if (bx < 1024) {    // zT (transposed) = xn @ in_proj[512:1024]^T
        int l = bx - 512;
        A = xn; W = in_proj_w + 131072; bias = nullptr; C = zT; ldc = Bsz * Lseq; transC = 1;
        n0 = (l & 7) * 64; m0 = (l >> 3) * 64;
    } else if (bx < 1280) {    // kmat
        int l = bx - 1024;
        A = xn; W = k_w; bias = k_b; C = kmat; ldc = Dm;
        n0 = (l & 3) * 64; m0 = (l >> 2) * 64;
    } else if (bx < 1536) {    // vmat
        int l = bx - 1280;
        A = xn; W = v_w; bias = v_b; C = vmat; ldc = Dm;
        n0 = (l & 3) * 64; m0 = (l >> 2) * 64;
    } else if (bx < 1792) {    // qcat seg0
        int l = bx - 1536;
        A = xn; W = mq_w; bias = mq_b; C = qcat; ldc = 4 * Dm;
        n0 = (l & 3) * 64; m0 = (l >> 2) * 64;
    } else if (bx < 1920) {    // qd2 (M=2048)
        int l = bx - 1792;
        A = xd2; W = mq_w + 65536; bias = mq_b + 256; C = qd2; ldc = Dm;
        n0 = (l & 3) * 64; m0 = (l >> 2) * 64;
    } else if (bx < 1984) {    // qd4 (M=1024)
        int l = bx - 1920;
        A = xd4; W = mq_w + 131072; bias = mq_b + 512; C = qd4; ldc = Dm;
        n0 = (l & 3) * 64; m0 = (l >> 2) * 64;
    } else {                   // qd8 (M=512)
        int l = bx - 1984;
        A = xd8; W = mq_w + 196608; bias = mq_b + 768; C = qd8; ldc = Dm;
        n0 = (l & 3) * 64; m0 = (l >> 2) * 64;
    }
    int tid = threadIdx.x;
    int wave = tid >> 6, lane = tid & 63;
    int quad = lane >> 4, r = lane & 15;
    int mo = (wave >> 1) * 32, no = (wave & 1) * 32;
    f4v acc[2][2];
    #pragma unroll
    for (int i = 0; i < 2; i++)
        #pragma unroll
        for (int j = 0; j < 2; j++) acc[i][j] = (f4v){0.f, 0.f, 0.f, 0.f};
    for (int k0 = 0; k0 < 256; k0 += 32) {
        {
            int m = tid >> 2, kk = (tid & 3) * 8;
            const float* ap = A + (size_t)(m0 + m) * 256 + k0 + kk;
            float4 a0 = *(const float4*)ap;
            float4 a1 = *(const float4*)(ap + 4);
            *(s8v*)&As[m][kk] = pack8(a0, a1);
        }
        {
            int n = tid >> 2, kk = (tid & 3) * 8;
            const float* wp = W + (size_t)(n0 + n) * 256 + k0 + kk;
            float4 w0 = *(const float4*)wp;
            float4 w1 = *(const float4*)(wp + 4);
            *(s8v*)&Ws[n][kk] = pack8(w0, w1);
        }
        __syncthreads();
        s8v af[2], bf[2];
        #pragma unroll
        for (int i = 0; i < 2; i++) af[i] = *(const s8v*)&As[mo + i * 16 + r][quad * 8];
        #pragma unroll
        for (int j = 0; j < 2; j++) bf[j] = *(const s8v*)&Ws[no + j * 16 + r][quad * 8];
        #pragma unroll
        for (int i = 0; i < 2; i++)
            #pragma unroll
            for (int j = 0; j < 2; j++)
                acc[i][j] = __builtin_amdgcn_mfma_f32_16x16x32_bf16(af[i], bf[j], acc[i][j], 0, 0, 0);
        __syncthreads();
    }
    #pragma unroll
    for (int i = 0; i < 2; i++)
        #pragma unroll
        for (int j = 0; j < 2; j++)
            #pragma unroll
            for (int reg = 0; reg < 4; reg++) {
                int m = m0 + mo + i * 16 + quad * 4 + reg;
                int n = n0 + no + j * 16 + r;
                float v = acc[i][j][reg];
                if (bias) v += bias[n];
                float* cp = transC ? (C + (size_t)n * ldc + m) : (C + (size_t)m * ldc + n);
                *cp = v;
            }
}

// ======= bf16 MFMA GEMM: C = A(M,K) * W(N,K)^T + bias;  transC; optional fused gate-final =======
__global__ __launch_bounds__(256) void gemm_bf16(const float* __restrict__ A, int lda_m, int lda_k,
                                                 const float* __restrict__ W, int ldw,
                                                 const float* __restrict__ bias,
                                                 float* __restrict__ C, int ldc,
                                                 int M, int N, int K, int accum, int transC,
                                                 const float* __restrict__ xres,
                                                 float* __restrict__ fout) {
    __shared__ unsigned short As[64][40];
    __shared__ unsigned short Ws[64][40];
    int tid = threadIdx.x;
    int wave = tid >> 6, lane = tid & 63;
    int quad = lane >> 4, r = lane & 15;
    int m0 = blockIdx.y * 64, n0 = blockIdx.x * 64;
    int mo = (wave >> 1) * 32, no = (wave & 1) * 32;
    f4v acc[2][2];
    #pragma unroll
    for (int i = 0; i < 2; i++)
        #pragma unroll
        for (int j = 0; j < 2; j++) acc[i][j] = (f4v){0.f, 0.f, 0.f, 0.f};

    for (int k0 = 0; k0 < K; k0 += 32) {
        if (lda_k == 1) {
            int m = tid >> 2, kk = (tid & 3) * 8;
            const float* ap = A + (size_t)(m0 + m) * lda_m + k0 + kk;
            float4 a0 = *(const float4*)ap;
            float4 a1 = *(const float4*)(ap + 4);
            *(s8v*)&As[m][kk] = pack8(a0, a1);
        } else {
            int k = tid >> 3, m8 = (tid & 7) * 8;
            const float* ap = A + (size_t)(k0 + k) * lda_k + m0 + m8;
            float4 a0 = *(const float4*)ap;
            float4 a1 = *(const float4*)(ap + 4);
            float av[8] = {a0.x, a0.y, a0.z, a0.w, a1.x, a1.y, a1.z, a1.w};
            #pragma unroll
            for (int i = 0; i < 8; i++) As[m8 + i][k] = (unsigned short)f2bf(av[i]);
        }
        {
            int n = tid >> 2, kk = (tid & 3) * 8;
            s8v pv;
            if (n0 + n < N) {
                const float* wp = W + (size_t)(n0 + n) * ldw + k0 + kk;
                float4 w0 = *(const float4*)wp;
                float4 w1 = *(const float4*)(wp + 4);
                pv = pack8(w0, w1);
            } else {
                pv = (s8v){0, 0, 0, 0, 0, 0, 0, 0};
            }
            *(s8v*)&Ws[n][kk] = pv;
        }
        __syncthreads();
        s8v af[2], bf[2];
        #pragma unroll
        for (int i = 0; i < 2; i++) af[i] = *(const s8v*)&As[mo + i * 16 + r][quad * 8];
        #pragma unroll
        for (int j = 0; j < 2; j++) bf[j] = *(const s8v*)&Ws[no + j * 16 + r][quad * 8];
        #pragma unroll
        for (int i = 0; i < 2; i++)
            #pragma unroll
            for (int j = 0; j < 2; j++)
                acc[i][j] = __builtin_amdgcn_mfma_f32_16x16x32_bf16(af[i], bf[j], acc[i][j], 0, 0, 0);
        __syncthreads();
    }
    #pragma unroll
    for (int i = 0; i < 2; i++)
        #pragma unroll
        for (int j = 0; j < 2; j++)
            #pragma unroll
            for (int reg = 0; reg < 4; reg++) {
                int m = m0 + mo + i * 16 + quad * 4 + reg;
                int n = n0 + no + j * 16 + r;
                if (n >= N) continue;
                float v = acc[i][j][reg];
                if (bias) v += bias[n];
                if (fout) {
                    // fused sigmoid-gate + residual: A is cat2 [ssm|ssd], lda_m=512
                    float g = 1.0f / (1.0f + __expf(-v));
                    float ssm = A[(size_t)m * lda_m + n];
                    float ssd = A[(size_t)m * lda_m + 256 + n];
                    fout[(size_t)m * 256 + n] = xres[(size_t)m * 256 + n] + g * ssm + (1.0f - g) * ssd;
                } else {
                    float* cp = transC ? (C + (size_t)n * ldc + m) : (C + (size_t)m * ldc + n);
                    if (accum) v += *cp;
                    *cp = v;
                }
            }
}

// ---------------- small fp32 GEMM (K=16 dt projection); transC supported ----------------
__global__ __launch_bounds__(256) void gemm_f32(const float* __restrict__ A, int lda_m, int lda_k,
                                                const float* __restrict__ W, int ldw,
                                                const float* __restrict__ bias,
                                                float* __restrict__ C, int ldc,
                                                int M, int N, int K, int act, int accum, int transC) {
    __shared__ float As[16][72];
    __shared__ float Ws[16][72];
    int tid = threadIdx.x;
    int m0 = blockIdx.y * 64, n0 = blockIdx.x * 64;
    int tx = tid & 15, ty = tid >> 4;
    float acc[4][4] = {};
    for (int k0 = 0; k0 < K; k0 += 16) {
        {
            int ml = tid >> 2, kl = (tid & 3) * 4;
            const float4 av = *(const float4*)(A + (size_t)(m0 + ml) * lda_m + k0 + kl);
            As[kl + 0][ml] = av.x; As[kl + 1][ml] = av.y;
            As[kl + 2][ml] = av.z; As[kl + 3][ml] = av.w;
        }
        {
            int nl = tid >> 2, kl = (tid & 3) * 4;
            float4 wv;
            if (n0 + nl < N) wv = *(const float4*)(W + (size_t)(n0 + nl) * ldw + k0 + kl);
            else wv = make_float4(0.f, 0.f, 0.f, 0.f);
            Ws[kl + 0][nl] = wv.x; Ws[kl + 1][nl] = wv.y;
            Ws[kl + 2][nl] = wv.z; Ws[kl + 3][nl] = wv.w;
        }
        __syncthreads();
        #pragma unroll
        for (int kk = 0; kk < 16; kk++) {
            float4 av = *(const float4*)&As[kk][ty * 4];
            float4 bv = *(const float4*)&Ws[kk][tx * 4];
            float a[4] = {av.x, av.y, av.z, av.w};
            float bb[4] = {bv.x, bv.y, bv.z, bv.w};
            #pragma unroll
            for (int im = 0; im < 4; im++)
                #pragma unroll
                for (int in = 0; in < 4; in++)
                    acc[im][in] = fmaf(a[im], bb[in], acc[im][in]);
        }
        __syncthreads();
    }
    #pragma unroll
    for (int in = 0; in < 4; in++) {
        int n = n0 + tx * 4 + in;
        if (n >= N) continue;
        #pragma unroll
        for (int im = 0; im < 4; im++) {
            int m = m0 + ty * 4 + im;
            float v = acc[im][in];
            if (bias) v += bias[n];
            if (act == 1) v = fmaxf(v, 0.0f) + log1pf(expf(-fabsf(v)));
            float* cp = transC ? (C + (size_t)n * ldc + m) : (C + (size_t)m * ldc + n);
            if (accum) v += *cp;
            *cp = v;
        }
    }
}

// ======== chunk-parallel selective scan (time-major operands) ========
// Pass 1 (ILP form): h = sum_t exp(As*(Stot-S_t))*u_t*B_t ; P = exp(As*Stot)
__global__ __launch_bounds__(256) void scan_pass1(const float* __restrict__ xcT,
                                                  const float* __restrict__ dtmT,
                                                  const float* __restrict__ dbc,
                                                  const float* __restrict__ A_log,
                                                  float* __restrict__ hloc,
                                                  float* __restrict__ Pc) {
    int wave = blockIdx.x * 4 + (threadIdx.x >> 6);
    int lane = threadIdx.x & 63;
    int ch = wave & (NCH - 1);
    int c  = wave >> 11;
    int b = ch >> 9, d = ch & (DIm - 1);
    float As = -__expf(A_log[d * Ssz + lane]);
    int base_m = b * Lseq + c * CHK;
    float dt_vec = dtmT[(size_t)d * (Bsz * Lseq) + base_m + lane];
    float x_vec  = xcT [(size_t)d * (Bsz * Lseq) + base_m + lane];
    float ux = dt_vec * x_vec;
    // inclusive prefix sum of dt across lanes (lane = t)
    float S = dt_vec;
    #pragma unroll
    for (int m = 1; m < 64; m <<= 1) {
        float o = __shfl_up(S, m, 64);
        if (lane >= m) S += o;
    }
    float Stot = __shfl(S, 63, 64);
    const float* Bp = dbc + (size_t)base_m * 144 + DTRm + lane;
    float h0 = 0.f, h1 = 0.f, h2 = 0.f, h3 = 0.f;
    #pragma unroll 4
    for (int t = 0; t < CHK; t += 4) {
        float B0 = Bp[0], B1 = Bp[144], B2 = Bp[288], B3 = Bp[432];
        Bp += 576;
        float w0 = __expf(As * (Stot - __shfl(S, t, 64)))     * __shfl(ux, t, 64);
        float w1 = __expf(As * (Stot - __shfl(S, t + 1, 64))) * __shfl(ux, t + 1, 64);
        float w2 = __expf(As * (Stot - __shfl(S, t + 2, 64))) * __shfl(ux, t + 2, 64);
        float w3 = __expf(As * (Stot - __shfl(S, t + 3, 64))) * __shfl(ux, t + 3, 64);
        h0 = fmaf(w0, B0, h0); h1 = fmaf(w1, B1, h1);
        h2 = fmaf(w2, B2, h2); h3 = fmaf(w3, B3, h3);
    }
    size_t o = ((size_t)ch * NCHK + c) * Ssz + lane;
    hloc[o] = (h0 + h1) + (h2 + h3);
    Pc[o] = __expf(As * Stot);
}

__global__ __launch_bounds__(256) void scan_combine(const float* __restrict__ hloc,
                                                    const float* __restrict__ Pc,
                                                    float* __restrict__ Hinit) {
    int wave = blockIdx.x * 4 + (threadIdx.x >> 6);
    int lane = threadIdx.x & 63;
    size_t base = (size_t)wave * NCHK * Ssz + lane;
    float H = 0.0f;
    #pragma unroll
    for (int c = 0; c < NCHK; c++) {
        size_t o = base + (size_t)c * Ssz;
        Hinit[o] = H;
        H = fmaf(Pc[o], H, hloc[o]);
    }
}

__global__ __launch_bounds__(256) void scan_pass3(const float* __restrict__ xcT,
                                                  const float* __restrict__ dtmT,
                                                  const float* __restrict__ zT,
                                                  const float* __restrict__ dbc,
                                                  const float* __restrict__ A_log,
                                                  const float* __restrict__ D_ssm,
                                                  const float* __restrict__ Hinit,
                                                  float* __restrict__ yT) {
    __shared__ float hCs[4][16][68];
    int wid = threadIdx.x >> 6;
    int lane = threadIdx.x & 63;
    int wave = blockIdx.x * 4 + wid;
    int ch = wave & (NCH - 1);
    int c  = wave >> 11;
    int b = ch >> 9, d = ch & (DIm - 1);
    float As = -__expf(A_log[d * Ssz + lane]);
    float Dd = D_ssm[d];
    int base_m = b * Lseq + c * CHK;
    float dt_vec = dtmT[(size_t)d * (Bsz * Lseq) + base_m + lane];
    float x_vec  = xcT [(size_t)d * (Bsz * Lseq) + base_m + lane];
    float zown   = zT  [(size_t)d * (Bsz * Lseq) + base_m + lane];
    float ux = dt_vec * x_vec;
    const float* Bp = dbc + (size_t)base_m * 144 + DTRm + lane;
    const float* Cp = Bp + Ssz;
    float h = Hinit[((size_t)ch * NCHK + c) * Ssz + lane];
    float yred = 0.0f;
    int tl = lane >> 2;
    int so = (lane & 3) * 16;
    for (int tb = 0; tb < 4; tb++) {
        #pragma unroll
        for (int j = 0; j < 16; j++) {
            int t = tb * 16 + j;
            float Bt = *Bp; Bp += 144;
            float Ct = *Cp; Cp += 144;
            float dtv = __shfl(dt_vec, t, 64);
            float u   = __shfl(ux, t, 64);
            float dA = __expf(dtv * As);
            h = fmaf(dA, h, u * Bt);
            hCs[wid][j][lane] = h * Ct;
        }
        const float* bp = &hCs[wid][tl][so];
        float4 a0 = *(const float4*)(bp + 0);
        float4 a1 = *(const float4*)(bp + 4);
        float4 a2 = *(const float4*)(bp + 8);
        float4 a3 = *(const float4*)(bp + 12);
        float part = ((a0.x + a0.y) + (a0.z + a0.w)) + ((a1.x + a1.y) + (a1.z + a1.w))
                   + ((a2.x + a2.y) + (a2.z + a2.w)) + ((a3.x + a3.y) + (a3.z + a3.w));
        part += __shfl_xor(part, 1, 64);
        part += __shfl_xor(part, 2, 64);
        float got = __shfl(part, ((lane - tb * 16) << 2) & 63, 64);
        if ((lane >> 4) == tb) yred = got;
    }
    float yg = (yred + x_vec * Dd) * (zown / (1.0f + __expf(-zown)));
    yT[(size_t)d * (Bsz * Lseq) + base_m + lane] = yg;
}

// ======== linear-attention reformulation of the decay-masked SSD ========
__global__ __launch_bounds__(256) void attn_p1(const float* __restrict__ k,
                                               const float* __restrict__ v,
                                               const float* __restrict__ log_tau,
                                               float* __restrict__ loc) {
    __shared__ float Ksh[4][CHA][20];
    __shared__ float Vsh[4][CHA][16];
    int wid = threadIdx.x >> 6, lane = threadIdx.x & 63;
    int wave = blockIdx.x * 4 + wid;     // 0..2047
    int bh = wave >> 5;
    int c  = wave & 31;
    int b = bh >> 4, h = bh & 15;
    float inv_tau = __expf(-log_tau[h]);
    float rdec = __expf(-inv_tau);
    int t0 = c * CHA;
    int row = lane >> 1, hf = (lane & 1) * 8;
    const float* kp = k + ((size_t)(b * Lseq + t0 + row)) * Dm + h * HDm + hf;
    const float* vp = v + ((size_t)(b * Lseq + t0 + row)) * Dm + h * HDm + hf;
    *(float4*)&Ksh[wid][row][hf]     = *(const float4*)kp;
    *(float4*)&Ksh[wid][row][hf + 4] = *(const float4*)(kp + 4);
    *(float4*)&Vsh[wid][row][hf]     = *(const float4*)vp;
    *(float4*)&Vsh[wid][row][hf + 4] = *(const float4*)(vp + 4);
    int g = lane >> 4, cc = lane & 15;
    float4 U = {0.f, 0.f, 0.f, 0.f}, T = {0.f, 0.f, 0.f, 0.f};
    #pragma unroll 8
    for (int s = 0; s < CHA; s++) {
        float4 kf = *(const float4*)&Ksh[wid][s][4 * g];
        float vv = Vsh[wid][s][cc];
        float u0 = kf.x * vv, u1 = kf.y * vv, u2 = kf.z * vv, u3 = kf.w * vv;
        U.x += u0; U.y += u1; U.z += u2; U.w += u3;
        T.x = fmaf(rdec, T.x, u0); T.y = fmaf(rdec, T.y, u1);
        T.z = fmaf(rdec, T.z, u2); T.w = fmaf(rdec, T.w, u3);
    }
    float* op = loc + ((size_t)bh * NCA + c) * 512;
    *(float4*)(op + lane * 4) = U;
    *(float4*)(op + 256 + lane * 4) = T;
}

__global__ __launch_bounds__(256) void attn_p2(const float* __restrict__ loc,
                                               const float* __restrict__ log_tau,
                                               float* __restrict__ init,
                                               float* __restrict__ kvtot) {
    int bh = blockIdx.x, e = threadIdx.x;
    float inv_tau = __expf(-log_tau[bh & 15]);
    float rp = __expf(-(float)CHA * inv_tau);   // r^CHA
    const float* lp = loc + (size_t)bh * NCA * 512;
    float* ip = init + (size_t)bh * NCA * 512;
    float Ua = 0.f, Ta = 0.f;
    #pragma unroll 8
    for (int c = 0; c < NCA; c++) {
        ip[c * 512 + e] = Ua;
        Ua += lp[c * 512 + e];
        ip[c * 512 + 256 + e] = Ta;
        Ta = fmaf(rp, Ta, lp[c * 512 + 256 + e]);
    }
    kvtot[bh * 256 + e] = Ua;
}

__global__ __launch_bounds__(256) void attn_p3(const float* __restrict__ q,
                                               const float* __restrict__ k,
                                               const float* __restrict__ v,
                                               const float* __restrict__ log_tau,
                                               const float* __restrict__ init,
                                               const float* __restrict__ kvtot,
                                               float* __restrict__ out) {
    __shared__ float Ksh[4][CHA][20];
    __shared__ float Qsh[4][CHA][20];
    __shared__ float Vsh[4][CHA][16];
    __shared__ float Ysh[4][CHA][16];
    int wid = threadIdx.x >> 6, lane = threadIdx.x & 63;
    int wave = blockIdx.x * 4 + wid;
    int bh = wave >> 5;
    int c  = wave & 31;
    int b = bh >> 4, h = bh & 15;
    float inv_tau = __expf(-log_tau[h]);
    float rdec = __expf(-inv_tau);
    int t0 = c * CHA;
    int row = lane >> 1, hf = (lane & 1) * 8;
    const float* kp = k + ((size_t)(b * Lseq + t0 + row)) * Dm + h * HDm + hf;
    const float* vp = v + ((size_t)(b * Lseq + t0 + row)) * Dm + h * HDm + hf;
    const float* qp = q + ((size_t)(b * Lseq + t0 + row)) * Dm + h * HDm + hf;
    *(float4*)&Ksh[wid][row][hf]     = *(const float4*)kp;
    *(float4*)&Ksh[wid][row][hf + 4] = *(const float4*)(kp + 4);
    *(float4*)&Vsh[wid][row][hf]     = *(const float4*)vp;
    *(float4*)&Vsh[wid][row][hf + 4] = *(const float4*)(vp + 4);
    *(float4*)&Qsh[wid][row][hf]     = *(const float4*)qp;
    *(float4*)&Qsh[wid][row][hf + 4] = *(const float4*)(qp + 4);
    int g = lane >> 4, cc = lane & 15;
    size_t ibase = ((size_t)bh * NCA + c) * 512;
    float4 U  = *(const float4*)(init + ibase + lane * 4);
    float4 T  = *(const float4*)(init + ibase + 256 + lane * 4);
    float4 KV = *(const float4*)(kvtot + bh * 256 + lane * 4);
    float om = 1.0f - rdec;
    float geom = (om > 1e-8f) ? (1.0f - __expf(-inv_tau * (float)t0)) / om : (float)t0;
    #pragma unroll 4
    for (int s = 0; s < CHA; s++) {
        int i = t0 + s;
        geom = fmaf(geom, rdec, 1.0f);
        float4 kf = *(const float4*)&Ksh[wid][s][4 * g];
        float4 qf = *(const float4*)&Qsh[wid][s][4 * g];
        float vv = Vsh[wid][s][cc];
        float u0 = kf.x * vv, u1 = kf.y * vv, u2 = kf.z * vv, u3 = kf.w * vv;
        U.x += u0; U.y += u1; U.z += u2; U.w += u3;
        T.x = fmaf(rdec, T.x, u0); T.y = fmaf(rdec, T.y, u1);
        T.z = fmaf(rdec, T.z, u2); T.w = fmaf(rdec, T.w, u3);
        float p;
        p = qf.x * (KV.x - U.x + T.x);
        p = fmaf(qf.y, KV.y - U.y + T.y, p);
        p = fmaf(qf.z, KV.z - U.z + T.z, p);
        p = fmaf(qf.w, KV.w - U.w + T.w, p);
        p += __shfl_xor(p, 16, 64);
        p += __shfl_xor(p, 32, 64);
        float deno = fmaxf((float)(Lseq - 1 - i) + geom, 1e-6f);
        float yv = p * (0.25f / deno);
        if (lane < 16) Ysh[wid][s][lane] = yv;
    }
    float* op = out + ((size_t)(b * Lseq + t0 + row)) * Dm + h * HDm + hf;
    *(float4*)op       = *(const float4*)&Ysh[wid][row][hf];
    *(float4*)(op + 4) = *(const float4*)&Ysh[wid][row][hf + 4];
}

extern "C" void kernel_launch(void* const* d_in, const int* in_sizes, int n_in,
                              void* d_out, int out_size, void* d_ws, size_t ws_size,
                              hipStream_t stream) {
    const float* x        = (const float*)d_in[0];
    const float* ln_g     = (const float*)d_in[1];
    const float* ln_b     = (const float*)d_in[2];
    const float* mq_w     = (const float*)d_in[3];
    const float* mq_b     = (const float*)d_in[4];
    const float* fuse_w   = (const float*)d_in[5];
    const float* fuse_b   = (const float*)d_in[6];
    const float* in_proj_w= (const float*)d_in[7];
    const float* conv_w   = (const float*)d_in[8];
    const float* conv_b   = (const float*)d_in[9];
    const float* x_proj_w = (const float*)d_in[10];
    const float* dt_w     = (const float*)d_in[11];
    const float* dt_b     = (const float*)d_in[12];
    const float* A_log    = (const float*)d_in[13];
    const float* D_ssm    = (const float*)d_in[14];
    const float* out_w    = (const float*)d_in[15];
    const float* k_w      = (const float*)d_in[16];
    const float* k_b      = (const float*)d_in[17];
    const float* v_w      = (const float*)d_in[18];
    const float* v_b      = (const float*)d_in[19];
    const float* o_w      = (const float*)d_in[20];
    const float* o_b      = (const float*)d_in[21];
    const float* log_tau  = (const float*)d_in[22];
    const float* gate_w   = (const float*)d_in[23];
    const float* gate_b   = (const float*)d_in[24];
    float* outp = (float*)d_out;

    const int M = Bsz * Lseq;          // 4096
    float* ws = (float*)d_ws;
    size_t off = 0;
    float* xn    = ws + off; off += (size_t)M * Dm;
    float* xm    = ws + off; off += (size_t)M * DIm;      // in_proj first half, row-major
    float* zT    = ws + off; off += (size_t)DIm * M;      // in_proj second half, time-major
    float* xcT   = ws + off; off += (size_t)DIm * M;      // conv output, time-major
    float* dbc   = ws + off; off += (size_t)M * 144;
    float* dtmT  = ws + off; off += (size_t)DIm * M;      // dt, time-major
    float* yT    = ws + off; off += (size_t)DIm * M;
    float* xd2   = ws + off; off += (size_t)Bsz * 512 * Dm;
    float* xd4   = ws + off; off += (size_t)Bsz * 256 * Dm;
    float* xd8   = ws + off; off += (size_t)Bsz * 128 * Dm;
    float* qd2   = ws + off; off += (size_t)Bsz * 512 * Dm;
    float* qd4   = ws + off; off += (size_t)Bsz * 256 * Dm;
    float* qd8   = ws + off; off += (size_t)Bsz * 128 * Dm;
    float* qcat  = ws + off; off += (size_t)M * 4 * Dm;   // reused: attn states, then scan hloc/Pc
    float* qbuf  = ws + off; off += (size_t)M * Dm;       // reused (w/ kmat): Hinit
    float* kmat  = ws + off; off += (size_t)M * Dm;
    float* vmat  = ws + off; off += (size_t)M * Dm;
    float* attn  = ws + off; off += (size_t)M * Dm;
    float* cat2  = ws + off; off += (size_t)M * 2 * Dm;   // [ssm_o | ssd_o]; xc row-major aliases here
    float* xc    = cat2;    // row-major conv output, dead before cat2 is first written

    // 1. LayerNorm
    ln_kernel<<<M, 256, 0, stream>>>(x, ln_g, ln_b, xn);

    // 2. fused pooling (xd2/xd4/xd8 in one dispatch)
    halve3_kernel<<<(917504 + 255) / 256, 256, 0, stream>>>(xn, xd2, xd4, xd8);

    // 3. ALL K=256 projections in ONE dispatch: xm, zT, k, v, q0, qd2, qd4, qd8
    proj8<<<2016, 256, 0, stream>>>(xn, xd2, xd4, xd8, in_proj_w,
        k_w, k_b, v_w, v_b, mq_w, mq_b,
        xm, zT, kmat, vmat, qcat, qd2, qd4, qd8);

    // 4. fused interpolation into qcat segs 1..3, then fuse GEMM (K=1024)
    interp3_kernel<<<(3 * M * Dm + 255) / 256, 256, 0, stream>>>(qd2, qd4, qd8, qcat);
    gemm_bf16<<<dim3(4, 64), 256, 0, stream>>>(qcat, 4 * Dm, 1, fuse_w, 4 * Dm,
        fuse_b, qbuf, Dm, M, Dm, 4 * Dm, 0, 0, nullptr, nullptr);

    // 5. causal conv + SiLU (xc row-major into cat2 alias + xcT time-major)
    conv_silu_kernel<<<512, 256, 0, stream>>>(xm, conv_w, conv_b, xc, xcT);

    // 6. x_proj GEMM (N=144, K=512), reads xc row-major
    gemm_bf16<<<dim3(3, 64), 256, 0, stream>>>(xc, DIm, 1, x_proj_w, DIm,
        nullptr, dbc, 144, M, 144, DIm, 0, 0, nullptr, nullptr);

    // 7. dt GEMM + softplus (K=16, fp32), time-major output
    gemm_f32<<<dim3(8, 64), 256, 0, stream>>>(dbc, 144, 1, dt_w, DTRm,
        dt_b, dtmT, M, M, DIm, DTRm, 1, 0, 1);

    // 8. linear-attention (chunk-parallel, exact); states in dead qcat
    float* aloc  = qcat;
    float* ainit = qcat + (size_t)64 * NCA * 512;
    float* kvtot = qcat + (size_t)2 * 64 * NCA * 512;
    attn_p1<<<512, 256, 0, stream>>>(kmat, vmat, log_tau, aloc);
    attn_p2<<<64, 256, 0, stream>>>(aloc, log_tau, ainit, kvtot);
    attn_p3<<<512, 256, 0, stream>>>(qbuf, kmat, vmat, log_tau, ainit, kvtot, attn);
    gemm_bf16<<<dim3(4, 64), 256, 0, stream>>>(attn, Dm, 1, o_w, Dm, o_b,
        cat2 + 256, 2 * Dm, M, Dm, Dm, 0, 0, nullptr, nullptr);

    // 9. chunk-parallel selective scan (time-major operands; qcat free after attn_p3)
    float* hloc  = qcat;
    float* Pc    = qcat + (size_t)NCH * NCHK * Ssz;
    float* Hinit = qbuf;
    scan_pass1<<<(NCH * NCHK) / 4, 256, 0, stream>>>(xcT, dtmT, dbc, A_log, hloc, Pc);
    scan_combine<<<NCH / 4, 256, 0, stream>>>(hloc, Pc, Hinit);
    scan_pass3<<<(NCH * NCHK) / 4, 256, 0, stream>>>(xcT, dtmT, zT, dbc, A_log, D_ssm, Hinit, yT);

    // 10. out GEMM (A transposed storage yT (DI, B*L)) -> cat2 cols 0..255
    gemm_bf16<<<dim3(4, 64), 256, 0, stream>>>(yT, 1, M, out_w, DIm,
        nullptr, cat2, 2 * Dm, M, Dm, DIm, 0, 0, nullptr, nullptr);

    // 11. gate GEMM (K=512) with FUSED sigmoid-gate + residual epilogue -> d_out
    gemm_bf16<<<dim3(4, 64), 256, 0, stream>>>(cat2, 2 * Dm, 1, gate_w, 2 * Dm,
        gate_b, nullptr, 0, M, Dm, 2 * Dm, 0, 0, x, outp);
}

// Round 8
// 365.035 us; speedup vs baseline: 4.2152x; 1.1213x over previous
//
#include <hip/hip_runtime.h>
#include <math.h>

#define Bsz 4
#define Lseq 1024
#define Dm 256
#define Hh 16
#define HDm 16
#define DIm 512
#define Ssz 64
#define KCm 4
#define DTRm 16
#define NCH (Bsz * DIm)      // 2048 channels
#define CHK 64               // mamba-scan chunk length
#define NCHK (Lseq / CHK)    // 16 chunks
#define CHA 32               // attention-scan chunk length
#define NCA (Lseq / CHA)     // 32 chunks

typedef __attribute__((ext_vector_type(8))) short s8v;
typedef __attribute__((ext_vector_type(4))) float f4v;

static __device__ __forceinline__ float wave_sum(float v) {
    #pragma unroll
    for (int m = 32; m >= 1; m >>= 1) v += __shfl_xor(v, m, 64);
    return v;
}

// wave-uniform broadcast via scalar readlane (SALU, no LDS pipe)
static __device__ __forceinline__ float bcast(float v, int l) {
    return __uint_as_float(__builtin_amdgcn_readlane(__float_as_uint(v), l));
}

static __device__ __forceinline__ short f2bf(float f) {
    unsigned int u = __float_as_uint(f);
    u = (u + 0x7fffu + ((u >> 16) & 1u)) >> 16;
    return (short)u;
}

static __device__ __forceinline__ s8v pack8(float4 a, float4 b) {
    s8v v;
    v[0] = f2bf(a.x); v[1] = f2bf(a.y); v[2] = f2bf(a.z); v[3] = f2bf(a.w);
    v[4] = f2bf(b.x); v[5] = f2bf(b.y); v[6] = f2bf(b.z); v[7] = f2bf(b.w);
    return v;
}

// ---------------- LayerNorm ----------------
__global__ __launch_bounds__(256) void ln_kernel(const float* __restrict__ x,
                                                 const float* __restrict__ g,
                                                 const float* __restrict__ b,
                                                 float* __restrict__ xn) {
    int row = blockIdx.x;
    int tid = threadIdx.x;
    __shared__ float red[8];
    float v = x[(size_t)row * Dm + tid];
    float s = wave_sum(v);
    int wid = tid >> 6, lane = tid & 63;
    if (lane == 0) red[wid] = s;
    __syncthreads();
    float mean = (red[0] + red[1] + red[2] + red[3]) * (1.0f / Dm);
    float dv = v - mean;
    float s2 = wave_sum(dv * dv);
    if (lane == 0) red[4 + wid] = s2;
    __syncthreads();
    float var = (red[4] + red[5] + red[6] + red[7]) * (1.0f / Dm);
    float inv = rsqrtf(var + 1e-5f);
    xn[(size_t)row * Dm + tid] = dv * inv * g[tid] + b[tid];
}

// ---------------- fused 3-level avg-pool ----------------
__global__ void halve3_kernel(const float* __restrict__ xn, float* __restrict__ xd2,
                              float* __restrict__ xd4, float* __restrict__ xd8) {
    int idx = blockIdx.x * blockDim.x + threadIdx.x;
    if (idx < 524288) {                       // xd2 (B,512,256)
        int d = idx & 255, j = (idx >> 8) & 511, b = idx >> 17;
        const float* p = xn + ((size_t)(b * 1024 + 2 * j) * 256 + d);
        xd2[idx] = 0.5f * (p[0] + p[256]);
    } else if (idx < 786432) {                // xd4 (B,256,256)
        int i = idx - 524288;
        int d = i & 255, j = (i >> 8) & 255, b = i >> 16;
        const float* p = xn + ((size_t)(b * 1024 + 4 * j) * 256 + d);
        xd4[i] = 0.25f * ((p[0] + p[256]) + (p[512] + p[768]));
    } else if (idx < 917504) {                // xd8 (B,128,256)
        int i = idx - 786432;
        int d = i & 255, j = (i >> 8) & 127, b = i >> 15;
        const float* p = xn + ((size_t)(b * 1024 + 8 * j) * 256 + d);
        xd8[i] = 0.125f * (((p[0] + p[256]) + (p[512] + p[768]))
                         + ((p[1024] + p[1280]) + (p[1536] + p[1792])));
    }
}

// ---------------- causal depthwise conv + SiLU; writes xc (row-major) AND xcT (time-major) ----------------
__global__ __launch_bounds__(256) void conv_silu_kernel(const float* __restrict__ xm,
                                                        const float* __restrict__ cw,
                                                        const float* __restrict__ cb,
                                                        float* __restrict__ xc,
                                                        float* __restrict__ xcT) {
    __shared__ float tile[64][65];
    int blk = blockIdx.x;           // 512 blocks
    int cblk = blk & 7;
    int tblk = (blk >> 3) & 15;
    int b = blk >> 7;
    int c0 = cblk * 64, t0 = tblk * 64;
    int cc = threadIdx.x & 63;
    int tw = threadIdx.x >> 6;
    int c = c0 + cc;
    float w0 = cw[c * 4 + 0], w1 = cw[c * 4 + 1], w2 = cw[c * 4 + 2], w3 = cw[c * 4 + 3];
    float bias = cb[c];
    #pragma unroll 4
    for (int i = 0; i < 16; i++) {
        int tl = tw * 16 + i;
        int t = t0 + tl;
        const float* base = xm + ((size_t)(b * Lseq + t)) * DIm + c;
        float acc = bias + base[0] * w3;
        if (t >= 3) {
            acc += base[-3 * DIm] * w0 + base[-2 * DIm] * w1 + base[-1 * DIm] * w2;
        } else {
            if (t >= 1) acc += base[-1 * DIm] * w2;
            if (t >= 2) acc += base[-2 * DIm] * w1;
        }
        float r = acc / (1.0f + __expf(-acc));
        xc[((size_t)(b * Lseq + t)) * DIm + c] = r;
        tile[tl][cc] = r;
    }
    __syncthreads();
    int tcol = threadIdx.x & 63;
    int crow0 = threadIdx.x >> 6;
    #pragma unroll 4
    for (int j = 0; j < 16; j++) {
        int crow = crow0 * 16 + j;
        xcT[((size_t)(c0 + crow)) * (Bsz * Lseq) + b * Lseq + t0 + tcol] = tile[tcol][crow];
    }
}

// ======= batched projection GEMM: 8 outputs off xn/xd* in ONE dispatch (K=256) =======
__global__ __launch_bounds__(256) void proj8(const float* __restrict__ xn,
                                             const float* __restrict__ xd2,
                                             const float* __restrict__ xd4,
                                             const float* __restrict__ xd8,
                                             const float* __restrict__ in_proj_w,
                                             const float* __restrict__ k_w, const float* __restrict__ k_b,
                                             const float* __restrict__ v_w, const float* __restrict__ v_b,
                                             const float* __restrict__ mq_w, const float* __restrict__ mq_b,
                                             float* __restrict__ xm, float* __restrict__ zT,
                                             float* __restrict__ kmat, float* __restrict__ vmat,
                                             float* __restrict__ q0, float* __restrict__ qd2,
                                             float* __restrict__ qd4, float* __restrict__ qd8) {
    __shared__ unsigned short As[64][40];
    __shared__ unsigned short Ws[64][40];
    int bx = blockIdx.x;
    const float* A; const float* W; const float* bias; float* C;
    int ldc, transC = 0, n0, m0;
    if (bx < 512) {
        A = xn; W = in_proj_w; bias = nullptr; C = xm; ldc = DIm;
        n0 = (bx & 7) * 64; m0 = (bx >> 3) * 64;
    } else if (bx < 1024) {
        int l = bx - 512;
        A = xn; W = in_proj_w + 131072; bias = nullptr; C = zT; ldc = Bsz * Lseq; transC = 1;
        n0 = (l & 7) * 64; m0 = (l >> 3) * 64;
    } else if (bx < 1280) {
        int l = bx - 1024;
        A = xn; W = k_w; bias = k_b; C = kmat; ldc = Dm;
        n0 = (l & 3) * 64; m0 = (l >> 2) * 64;
    } else if (bx < 1536) {
        int l = bx - 1280;
        A = xn; W = v_w; bias = v_b; C = vmat; ldc = Dm;
        n0 = (l & 3) * 64; m0 = (l >> 2) * 64;
    } else if (bx < 1792) {
        int l = bx - 1536;
        A = xn; W = mq_w; bias = mq_b; C = q0; ldc = Dm;
        n0 = (l & 3) * 64; m0 = (l >> 2) * 64;
    } else if (bx < 1920) {
        int l = bx - 1792;
        A = xd2; W = mq_w + 65536; bias = mq_b + 256; C = qd2; ldc = Dm;
        n0 = (l & 3) * 64; m0 = (l >> 2) * 64;
    } else if (bx < 1984) {
        int l = bx - 1920;
        A = xd4; W = mq_w + 131072; bias = mq_b + 512; C = qd4; ldc = Dm;
        n0 = (l & 3) * 64; m0 = (l >> 2) * 64;
    } else {
        int l = bx - 1984;
        A = xd8; W = mq_w + 196608; bias = mq_b + 768; C = qd8; ldc = Dm;
        n0 = (l & 3) * 64; m0 = (l >> 2) * 64;
    }
    int tid = threadIdx.x;
    int wave = tid >> 6, lane = tid & 63;
    int quad = lane >> 4, r = lane & 15;
    int mo = (wave >> 1) * 32, no = (wave & 1) * 32;
    f4v acc[2][2];
    #pragma unroll
    for (int i = 0; i < 2; i++)
        #pragma unroll
        for (int j = 0; j < 2; j++) acc[i][j] = (f4v){0.f, 0.f, 0.f, 0.f};
    for (int k0 = 0; k0 < 256; k0 += 32) {
        {
            int m = tid >> 2, kk = (tid & 3) * 8;
            const float* ap = A + (size_t)(m0 + m) * 256 + k0 + kk;
            *(s8v*)&As[m][kk] = pack8(*(const float4*)ap, *(const float4*)(ap + 4));
        }
        {
            int n = tid >> 2, kk = (tid & 3) * 8;
            const float* wp = W + (size_t)(n0 + n) * 256 + k0 + kk;
            *(s8v*)&Ws[n][kk] = pack8(*(const float4*)wp, *(const float4*)(wp + 4));
        }
        __syncthreads();
        s8v af[2], bf[2];
        #pragma unroll
        for (int i = 0; i < 2; i++) af[i] = *(const s8v*)&As[mo + i * 16 + r][quad * 8];
        #pragma unroll
        for (int j = 0; j < 2; j++) bf[j] = *(const s8v*)&Ws[no + j * 16 + r][quad * 8];
        #pragma unroll
        for (int i = 0; i < 2; i++)
            #pragma unroll
            for (int j = 0; j < 2; j++)
                acc[i][j] = __builtin_amdgcn_mfma_f32_16x16x32_bf16(af[i], bf[j], acc[i][j], 0, 0, 0);
        __syncthreads();
    }
    #pragma unroll
    for (int i = 0; i < 2; i++)
        #pragma unroll
        for (int j = 0; j < 2; j++)
            #pragma unroll
            for (int reg = 0; reg < 4; reg++) {
                int m = m0 + mo + i * 16 + quad * 4 + reg;
                int n = n0 + no + j * 16 + r;
                float v = acc[i][j][reg];
                if (bias) v += bias[n];
                float* cp = transC ? (C + (size_t)n * ldc + m) : (C + (size_t)m * ldc + n);
                *cp = v;
            }
}

// ======= fuse GEMM with ON-THE-FLY interpolation staging (K=1024: q0 | lerp(qd2) | lerp(qd4) | lerp(qd8)) =======
__global__ __launch_bounds__(256) void fuse_gemm(const float* __restrict__ q0,
                                                 const float* __restrict__ qd2,
                                                 const float* __restrict__ qd4,
                                                 const float* __restrict__ qd8,
                                                 const float* __restrict__ fuse_w,
                                                 const float* __restrict__ fuse_b,
                                                 float* __restrict__ qbuf) {
    __shared__ unsigned short As[64][40];
    __shared__ unsigned short Ws[64][40];
    int tid = threadIdx.x;
    int wave = tid >> 6, lane = tid & 63;
    int quad = lane >> 4, r = lane & 15;
    int m0 = blockIdx.y * 64, n0 = blockIdx.x * 64;
    int mo = (wave >> 1) * 32, no = (wave & 1) * 32;
    f4v acc[2][2];
    #pragma unroll
    for (int i = 0; i < 2; i++)
        #pragma unroll
        for (int j = 0; j < 2; j++) acc[i][j] = (f4v){0.f, 0.f, 0.f, 0.f};

    for (int k0 = 0; k0 < 1024; k0 += 32) {
        {
            int m = tid >> 2, kk = (tid & 3) * 8;
            int kg = k0 + kk;
            int seg = kg >> 8, dcol = kg & 255;
            int mg = m0 + m;
            s8v pv;
            if (seg == 0) {
                const float* ap = q0 + (size_t)mg * 256 + dcol;
                pv = pack8(*(const float4*)ap, *(const float4*)(ap + 4));
            } else {
                int t = mg & 1023, b = mg >> 10;
                int Lin = 512 >> (seg - 1);
                const float* qd = (seg == 1) ? qd2 : (seg == 2) ? qd4 : qd8;
                float pos = (t + 0.5f) * ((float)Lin / 1024.0f) - 0.5f;
                pos = fminf(fmaxf(pos, 0.0f), (float)(Lin - 1));
                int lo = (int)floorf(pos);
                int hi = min(lo + 1, Lin - 1);
                float w = pos - (float)lo;
                const float* plo = qd + ((size_t)(b * Lin + lo)) * 256 + dcol;
                const float* phi = qd + ((size_t)(b * Lin + hi)) * 256 + dcol;
                float4 l0 = *(const float4*)plo, l1 = *(const float4*)(plo + 4);
                float4 h0 = *(const float4*)phi, h1 = *(const float4*)(phi + 4);
                float4 r0, r1;
                r0.x = l0.x + w * (h0.x - l0.x); r0.y = l0.y + w * (h0.y - l0.y);
                r0.z = l0.z + w * (h0.z - l0.z); r0.w = l0.w + w * (h0.w - l0.w);
                r1.x = l1.x + w * (h1.x - l1.x); r1.y = l1.y + w * (h1.y - l1.y);
                r1.z = l1.z + w * (h1.z - l1.z); r1.w = l1.w + w * (h1.w - l1.w);
                pv = pack8(r0, r1);
            }
            *(s8v*)&As[m][kk] = pv;
        }
        {
            int n = tid >> 2, kk = (tid & 3) * 8;
            const float* wp = fuse_w + (size_t)(n0 + n) * 1024 + k0 + kk;
            *(s8v*)&Ws[n][kk] = pack8(*(const float4*)wp, *(const float4*)(wp + 4));
        }
        __syncthreads();
        s8v af[2], bf[2];
        #pragma unroll
        for (int i = 0; i < 2; i++) af[i] = *(const s8v*)&As[mo + i * 16 + r][quad * 8];
        #pragma unroll
        for (int j = 0; j < 2; j++) bf[j] = *(const s8v*)&Ws[no + j * 16 + r][quad * 8];
        #pragma unroll
        for (int i = 0; i < 2; i++)
            #pragma unroll
            for (int j = 0; j < 2; j++)
                acc[i][j] = __builtin_amdgcn_mfma_f32_16x16x32_bf16(af[i], bf[j], acc[i][j], 0, 0, 0);
        __syncthreads();
    }
    #pragma unroll
    for (int i = 0; i < 2; i++)
        #pragma unroll
        for (int j = 0; j < 2; j++)
            #pragma unroll
            for (int reg = 0; reg < 4; reg++) {
                int m = m0 + mo + i * 16 + quad * 4 + reg;
                int n = n0 + no + j * 16 + r;
                qbuf[(size_t)m * 256 + n] = acc[i][j][reg] + fuse_b[n];
            }
}

// ======= batched o-GEMM + out-GEMM (one dispatch, 512 blocks) =======
__global__ __launch_bounds__(256) void post2(const float* __restrict__ attn,
                                             const float* __restrict__ o_w,
                                             const float* __restrict__ o_b,
                                             const float* __restrict__ yT,
                                             const float* __restrict__ out_w,
                                             float* __restrict__ cat2) {
    __shared__ unsigned short As[64][40];
    __shared__ unsigned short Ws[64][40];
    int bx = blockIdx.x;
    const float* A; const float* W; const float* bias; float* C;
    int lda_m, lda_k, ldw, K, n0, m0;
    if (bx < 256) {           // ssd: attn @ o_w^T + o_b -> cat2[:,256:]
        A = attn; lda_m = 256; lda_k = 1; W = o_w; ldw = 256; bias = o_b;
        C = cat2 + 256; K = 256;
        n0 = (bx & 3) * 64; m0 = (bx >> 2) * 64;
    } else {                  // ssm: yT^T @ out_w^T -> cat2[:,0:256]
        int l = bx - 256;
        A = yT; lda_m = 1; lda_k = Bsz * Lseq; W = out_w; ldw = DIm; bias = nullptr;
        C = cat2; K = DIm;
        n0 = (l & 3) * 64; m0 = (l >> 2) * 64;
    }
    int tid = threadIdx.x;
    int wave = tid >> 6, lane = tid & 63;
    int quad = lane >> 4, r = lane & 15;
    int mo = (wave >> 1) * 32, no = (wave & 1) * 32;
    f4v acc[2][2];
    #pragma unroll
    for (int i = 0; i < 2; i++)
        #pragma unroll
        for (int j = 0; j < 2; j++) acc[i][j] = (f4v){0.f, 0.f, 0.f, 0.f};
    for (int k0 = 0; k0 < K; k0 += 32) {
        if (lda_k == 1) {
            int m = tid >> 2, kk = (tid & 3) * 8;
            const float* ap = A + (size_t)(m0 + m) * lda_m + k0 + kk;
            *(s8v*)&As[m][kk] = pack8(*(const float4*)ap, *(const float4*)(ap + 4));
        } else {
            int k = tid >> 3, m8 = (tid & 7) * 8;
            const float* ap = A + (size_t)(k0 + k) * lda_k + m0 + m8;
            float4 a0 = *(const float4*)ap;
            float4 a1 = *(const float4*)(ap + 4);
            float av[8] = {a0.x, a0.y, a0.z, a0.w, a1.x, a1.y, a1.z, a1.w};
            #pragma unroll
            for (int i = 0; i < 8; i++) As[m8 + i][k] = (unsigned short)f2bf(av[i]);
        }
        {
            int n = tid >> 2, kk = (tid & 3) * 8;
            const float* wp = W + (size_t)(n0 + n) * ldw + k0 + kk;
            *(s8v*)&Ws[n][kk] = pack8(*(const float4*)wp, *(const float4*)(wp + 4));
        }
        __syncthreads();
        s8v af[2], bf[2];
        #pragma unroll
        for (int i = 0; i < 2; i++) af[i] = *(const s8v*)&As[mo + i * 16 + r][quad * 8];
        #pragma unroll
        for (int j = 0; j < 2; j++) bf[j] = *(const s8v*)&Ws[no + j * 16 + r][quad * 8];
        #pragma unroll
        for (int i = 0; i < 2; i++)
            #pragma unroll
            for (int j = 0; j < 2; j++)
                acc[i][j] = __builtin_amdgcn_mfma_f32_16x16x32_bf16(af[i], bf[j], acc[i][j], 0, 0, 0);
        __syncthreads();
    }
    #pragma unroll
    for (int i = 0; i < 2; i++)
        #pragma unroll
        for (int j = 0; j < 2; j++)
            #pragma unroll
            for (int reg = 0; reg < 4; reg++) {
                int m = m0 + mo + i * 16 + quad * 4 + reg;
                int n = n0 + no + j * 16 + r;
                float v = acc[i][j][reg];
                if (bias) v += bias[n];
                C[(size_t)m * 512 + n] = v;
            }
}

// ======= bf16 MFMA GEMM (generic; optional fused gate-final epilogue) =======
__global__ __launch_bounds__(256) void gemm_bf16(const float* __restrict__ A, int lda_m, int lda_k,
                                                 const float* __restrict__ W, int ldw,
                                                 const float* __restrict__ bias,
                                                 float* __restrict__ C, int ldc,
                                                 int M, int N, int K, int accum, int transC,
                                                 const float* __restrict__ xres,
                                                 float* __restrict__ fout) {
    __shared__ unsigned short As[64][40];
    __shared__ unsigned short Ws[64][40];
    int tid = threadIdx.x;
    int wave = tid >> 6, lane = tid & 63;
    int quad = lane >> 4, r = lane & 15;
    int m0 = blockIdx.y * 64, n0 = blockIdx.x * 64;
    int mo = (wave >> 1) * 32, no = (wave & 1) * 32;
    f4v acc[2][2];
    #pragma unroll
    for (int i = 0; i < 2; i++)
        #pragma unroll
        for (int j = 0; j < 2; j++) acc[i][j] = (f4v){0.f, 0.f, 0.f, 0.f};

    for (int k0 = 0; k0 < K; k0 += 32) {
        if (lda_k == 1) {
            int m = tid >> 2, kk = (tid & 3) * 8;
            const float* ap = A + (size_t)(m0 + m) * lda_m + k0 + kk;
            *(s8v*)&As[m][kk] = pack8(*(const float4*)ap, *(const float4*)(ap + 4));
        } else {
            int k = tid >> 3, m8 = (tid & 7) * 8;
            const float* ap = A + (size_t)(k0 + k) * lda_k + m0 + m8;
            float4 a0 = *(const float4*)ap;
            float4 a1 = *(const float4*)(ap + 4);
            float av[8] = {a0.x, a0.y, a0.z, a0.w, a1.x, a1.y, a1.z, a1.w};
            #pragma unroll
            for (int i = 0; i < 8; i++) As[m8 + i][k] = (unsigned short)f2bf(av[i]);
        }
        {
            int n = tid >> 2, kk = (tid & 3) * 8;
            s8v pv;
            if (n0 + n < N) {
                const float* wp = W + (size_t)(n0 + n) * ldw + k0 + kk;
                pv = pack8(*(const float4*)wp, *(const float4*)(wp + 4));
            } else {
                pv = (s8v){0, 0, 0, 0, 0, 0, 0, 0};
            }
            *(s8v*)&Ws[n][kk] = pv;
        }
        __syncthreads();
        s8v af[2], bf[2];
        #pragma unroll
        for (int i = 0; i < 2; i++) af[i] = *(const s8v*)&As[mo + i * 16 + r][quad * 8];
        #pragma unroll
        for (int j = 0; j < 2; j++) bf[j] = *(const s8v*)&Ws[no + j * 16 + r][quad * 8];
        #pragma unroll
        for (int i = 0; i < 2; i++)
            #pragma unroll
            for (int j = 0; j < 2; j++)
                acc[i][j] = __builtin_amdgcn_mfma_f32_16x16x32_bf16(af[i], bf[j], acc[i][j], 0, 0, 0);
        __syncthreads();
    }
    #pragma unroll
    for (int i = 0; i < 2; i++)
        #pragma unroll
        for (int j = 0; j < 2; j++)
            #pragma unroll
            for (int reg = 0; reg < 4; reg++) {
                int m = m0 + mo + i * 16 + quad * 4 + reg;
                int n = n0 + no + j * 16 + r;
                if (n >= N) continue;
                float v = acc[i][j][reg];
                if (bias) v += bias[n];
                if (fout) {
                    float g = 1.0f / (1.0f + __expf(-v));
                    float ssm = A[(size_t)m * lda_m + n];
                    float ssd = A[(size_t)m * lda_m + 256 + n];
                    fout[(size_t)m * 256 + n] = xres[(size_t)m * 256 + n] + g * ssm + (1.0f - g) * ssd;
                } else {
                    float* cp = transC ? (C + (size_t)n * ldc + m) : (C + (size_t)m * ldc + n);
                    if (accum) v += *cp;
                    *cp = v;
                }
            }
}

// ---------------- small fp32 GEMM (K=16 dt projection); transC supported ----------------
__global__ __launch_bounds__(256) void gemm_f32(const float* __restrict__ A, int lda_m, int lda_k,
                                                const float* __restrict__ W, int ldw,
                                                const float* __restrict__ bias,
                                                float* __restrict__ C, int ldc,
                                                int M, int N, int K, int act, int accum, int transC) {
    __shared__ float As[16][72];
    __shared__ float Ws[16][72];
    int tid = threadIdx.x;
    int m0 = blockIdx.y * 64, n0 = blockIdx.x * 64;
    int tx = tid & 15, ty = tid >> 4;
    float acc[4][4] = {};
    for (int k0 = 0; k0 < K; k0 += 16) {
        {
            int ml = tid >> 2, kl = (tid & 3) * 4;
            const float4 av = *(const float4*)(A + (size_t)(m0 + ml) * lda_m + k0 + kl);
            As[kl + 0][ml] = av.x; As[kl + 1][ml] = av.y;
            As[kl + 2][ml] = av.z; As[kl + 3][ml] = av.w;
        }
        {
            int nl = tid >> 2, kl = (tid & 3) * 4;
            float4 wv;
            if (n0 + nl < N) wv = *(const float4*)(W + (size_t)(n0 + nl) * ldw + k0 + kl);
            else wv = make_float4(0.f, 0.f, 0.f, 0.f);
            Ws[kl + 0][nl] = wv.x; Ws[kl + 1][nl] = wv.y;
            Ws[kl + 2][nl] = wv.z; Ws[kl + 3][nl] = wv.w;
        }
        __syncthreads();
        #pragma unroll
        for (int kk = 0; kk < 16; kk++) {
            float4 av = *(const float4*)&As[kk][ty * 4];
            float4 bv = *(const float4*)&Ws[kk][tx * 4];
            float a[4] = {av.x, av.y, av.z, av.w};
            float bb[4] = {bv.x, bv.y, bv.z, bv.w};
            #pragma unroll
            for (int im = 0; im < 4; im++)
                #pragma unroll
                for (int in = 0; in < 4; in++)
                    acc[im][in] = fmaf(a[im], bb[in], acc[im][in]);
        }
        __syncthreads();
    }
    #pragma unroll
    for (int in = 0; in < 4; in++) {
        int n = n0 + tx * 4 + in;
        if (n >= N) continue;
        #pragma unroll
        for (int im = 0; im < 4; im++) {
            int m = m0 + ty * 4 + im;
            float v = acc[im][in];
            if (bias) v += bias[n];
            if (act == 1) v = fmaxf(v, 0.0f) + log1pf(expf(-fabsf(v)));
            float* cp = transC ? (C + (size_t)n * ldc + m) : (C + (size_t)m * ldc + n);
            if (accum) v += *cp;
            *cp = v;
        }
    }
}

// ======== chunk-parallel selective scan (time-major operands, readlane broadcasts) ========
__global__ __launch_bounds__(256) void scan_pass1(const float* __restrict__ xcT,
                                                  const float* __restrict__ dtmT,
                                                  const float* __restrict__ dbc,
                                                  const float* __restrict__ A_log,
                                                  float* __restrict__ hloc,
                                                  float* __restrict__ Pc) {
    int wave = blockIdx.x * 4 + (threadIdx.x >> 6);
    int lane = threadIdx.x & 63;
    int ch = wave & (NCH - 1);
    int c  = wave >> 11;
    int b = ch >> 9, d = ch & (DIm - 1);
    float As = -__expf(A_log[d * Ssz + lane]);
    int base_m = b * Lseq + c * CHK;
    float dt_vec = dtmT[(size_t)d * (Bsz * Lseq) + base_m + lane];
    float x_vec  = xcT [(size_t)d * (Bsz * Lseq) + base_m + lane];
    float ux = dt_vec * x_vec;
    float S = dt_vec;
    #pragma unroll
    for (int m = 1; m < 64; m <<= 1) {
        float o = __shfl_up(S, m, 64);
        if (lane >= m) S += o;
    }
    float Stot = bcast(S, 63);
    const float* Bp = dbc + (size_t)base_m * 144 + DTRm + lane;
    float h0 = 0.f, h1 = 0.f, h2 = 0.f, h3 = 0.f;
    #pragma unroll 4
    for (int t = 0; t < CHK; t += 4) {
        float B0 = Bp[0], B1 = Bp[144], B2 = Bp[288], B3 = Bp[432];
        Bp += 576;
        float w0 = __expf(As * (Stot - bcast(S, t)))     * bcast(ux, t);
        float w1 = __expf(As * (Stot - bcast(S, t + 1))) * bcast(ux, t + 1);
        float w2 = __expf(As * (Stot - bcast(S, t + 2))) * bcast(ux, t + 2);
        float w3 = __expf(As * (Stot - bcast(S, t + 3))) * bcast(ux, t + 3);
        h0 = fmaf(w0, B0, h0); h1 = fmaf(w1, B1, h1);
        h2 = fmaf(w2, B2, h2); h3 = fmaf(w3, B3, h3);
    }
    size_t o = ((size_t)ch * NCHK + c) * Ssz + lane;
    hloc[o] = (h0 + h1) + (h2 + h3);
    Pc[o] = __expf(As * Stot);
}

__global__ __launch_bounds__(256) void scan_combine(const float* __restrict__ hloc,
                                                    const float* __restrict__ Pc,
                                                    float* __restrict__ Hinit) {
    int wave = blockIdx.x * 4 + (threadIdx.x >> 6);
    int lane = threadIdx.x & 63;
    size_t base = (size_t)wave * NCHK * Ssz + lane;
    float H = 0.0f;
    #pragma unroll
    for (int c = 0; c < NCHK; c++) {
        size_t o = base + (size_t)c * Ssz;
        Hinit[o] = H;
        H = fmaf(Pc[o], H, hloc[o]);
    }
}

__global__ __launch_bounds__(256) void scan_pass3(const float* __restrict__ xcT,
                                                  const float* __restrict__ dtmT,
                                                  const float* __restrict__ zT,
                                                  const float* __restrict__ dbc,
                                                  const float* __restrict__ A_log,
                                                  const float* __restrict__ D_ssm,
                                                  const float* __restrict__ Hinit,
                                                  float* __restrict__ yT) {
    __shared__ float hCs[4][16][68];
    int wid = threadIdx.x >> 6;
    int lane = threadIdx.x & 63;
    int wave = blockIdx.x * 4 + wid;
    int ch = wave & (NCH - 1);
    int c  = wave >> 11;
    int b = ch >> 9, d = ch & (DIm - 1);
    float As = -__expf(A_log[d * Ssz + lane]);
    float Dd = D_ssm[d];
    int base_m = b * Lseq + c * CHK;
    float dt_vec = dtmT[(size_t)d * (Bsz * Lseq) + base_m + lane];
    float x_vec  = xcT [(size_t)d * (Bsz * Lseq) + base_m + lane];
    float zown   = zT  [(size_t)d * (Bsz * Lseq) + base_m + lane];
    float ux = dt_vec * x_vec;
    const float* Bp = dbc + (size_t)base_m * 144 + DTRm + lane;
    const float* Cp = Bp + Ssz;
    float h = Hinit[((size_t)ch * NCHK + c) * Ssz + lane];
    float yred = 0.0f;
    int tl = lane >> 2;
    int so = (lane & 3) * 16;
    for (int tb = 0; tb < 4; tb++) {
        #pragma unroll
        for (int j = 0; j < 16; j++) {
            int t = tb * 16 + j;
            float Bt = *Bp; Bp += 144;
            float Ct = *Cp; Cp += 144;
            float dtv = bcast(dt_vec, t);
            float u   = bcast(ux, t);
            float dA = __expf(dtv * As);
            h = fmaf(dA, h, u * Bt);
            hCs[wid][j][lane] = h * Ct;
        }
        const float* bp = &hCs[wid][tl][so];
        float4 a0 = *(const float4*)(bp + 0);
        float4 a1 = *(const float4*)(bp + 4);
        float4 a2 = *(const float4*)(bp + 8);
        float4 a3 = *(const float4*)(bp + 12);
        float part = ((a0.x + a0.y) + (a0.z + a0.w)) + ((a1.x + a1.y) + (a1.z + a1.w))
                   + ((a2.x + a2.y) + (a2.z + a2.w)) + ((a3.x + a3.y) + (a3.z + a3.w));
        part += __shfl_xor(part, 1, 64);
        part += __shfl_xor(part, 2, 64);
        float got = __shfl(part, ((lane - tb * 16) << 2) & 63, 64);
        if ((lane >> 4) == tb) yred = got;
    }
    float yg = (yred + x_vec * Dd) * (zown / (1.0f + __expf(-zown)));
    yT[(size_t)d * (Bsz * Lseq) + base_m + lane] = yg;
}

// ======== linear-attention reformulation of the decay-masked SSD ========
__global__ __launch_bounds__(256) void attn_p1(const float* __restrict__ k,
                                               const float* __restrict__ v,
                                               const float* __restrict__ log_tau,
                                               float* __restrict__ loc) {
    __shared__ float Ksh[4][CHA][20];
    __shared__ float Vsh[4][CHA][16];
    int wid = threadIdx.x >> 6, lane = threadIdx.x & 63;
    int wave = blockIdx.x * 4 + wid;     // 0..2047
    int bh = wave >> 5;
    int c  = wave & 31;
    int b = bh >> 4, h = bh & 15;
    float inv_tau = __expf(-log_tau[h]);
    float rdec = __expf(-inv_tau);
    int t0 = c * CHA;
    int row = lane >> 1, hf = (lane & 1) * 8;
    const float* kp = k + ((size_t)(b * Lseq + t0 + row)) * Dm + h * HDm + hf;
    const float* vp = v + ((size_t)(b * Lseq + t0 + row)) * Dm + h * HDm + hf;
    *(float4*)&Ksh[wid][row][hf]     = *(const float4*)kp;
    *(float4*)&Ksh[wid][row][hf + 4] = *(const float4*)(kp + 4);
    *(float4*)&Vsh[wid][row][hf]     = *(const float4*)vp;
    *(float4*)&Vsh[wid][row][hf + 4] = *(const float4*)(vp + 4);
    int g = lane >> 4, cc = lane & 15;
    float4 U = {0.f, 0.f, 0.f, 0.f}, T = {0.f, 0.f, 0.f, 0.f};
    #pragma unroll 8
    for (int s = 0; s < CHA; s++) {
        float4 kf = *(const float4*)&Ksh[wid][s][4 * g];
        float vv = Vsh[wid][s][cc];
        float u0 = kf.x * vv, u1 = kf.y * vv, u2 = kf.z * vv, u3 = kf.w * vv;
        U.x += u0; U.y += u1; U.z += u2; U.w += u3;
        T.x = fmaf(rdec, T.x, u0); T.y = fmaf(rdec, T.y, u1);
        T.z = fmaf(rdec, T.z, u2); T.w = fmaf(rdec, T.w, u3);
    }
    float* op = loc + ((size_t)bh * NCA + c) * 512;
    *(float4*)(op + lane * 4) = U;
    *(float4*)(op + 256 + lane * 4) = T;
}

__global__ __launch_bounds__(256) void attn_p2(const float* __restrict__ loc,
                                               const float* __restrict__ log_tau,
                                               float* __restrict__ init,
                                               float* __restrict__ kvtot) {
    int bh = blockIdx.x, e = threadIdx.x;
    float inv_tau = __expf(-log_tau[bh & 15]);
    float rp = __expf(-(float)CHA * inv_tau);   // r^CHA
    const float* lp = loc + (size_t)bh * NCA * 512;
    float* ip = init + (size_t)bh * NCA * 512;
    float Ua = 0.f, Ta = 0.f;
    #pragma unroll 8
    for (int c = 0; c < NCA; c++) {
        ip[c * 512 + e] = Ua;
        Ua += lp[c * 512 + e];
        ip[c * 512 + 256 + e] = Ta;
        Ta = fmaf(rp, Ta, lp[c * 512 + 256 + e]);
    }
    kvtot[bh * 256 + e] = Ua;
}

__global__ __launch_bounds__(256) void attn_p3(const float* __restrict__ q,
                                               const float* __restrict__ k,
                                               const float* __restrict__ v,
                                               const float* __restrict__ log_tau,
                                               const float* __restrict__ init,
                                               const float* __restrict__ kvtot,
                                               float* __restrict__ out) {
    __shared__ float Ksh[4][CHA][20];
    __shared__ float Qsh[4][CHA][20];
    __shared__ float Vsh[4][CHA][16];
    __shared__ float Ysh[4][CHA][16];
    int wid = threadIdx.x >> 6, lane = threadIdx.x & 63;
    int wave = blockIdx.x * 4 + wid;
    int bh = wave >> 5;
    int c  = wave & 31;
    int b = bh >> 4, h = bh & 15;
    float inv_tau = __expf(-log_tau[h]);
    float rdec = __expf(-inv_tau);
    int t0 = c * CHA;
    int row = lane >> 1, hf = (lane & 1) * 8;
    const float* kp = k + ((size_t)(b * Lseq + t0 + row)) * Dm + h * HDm + hf;
    const float* vp = v + ((size_t)(b * Lseq + t0 + row)) * Dm + h * HDm + hf;
    const float* qp = q + ((size_t)(b * Lseq + t0 + row)) * Dm + h * HDm + hf;
    *(float4*)&Ksh[wid][row][hf]     = *(const float4*)kp;
    *(float4*)&Ksh[wid][row][hf + 4] = *(const float4*)(kp + 4);
    *(float4*)&Vsh[wid][row][hf]     = *(const float4*)vp;
    *(float4*)&Vsh[wid][row][hf + 4] = *(const float4*)(vp + 4);
    *(float4*)&Qsh[wid][row][hf]     = *(const float4*)qp;
    *(float4*)&Qsh[wid][row][hf + 4] = *(const float4*)(qp + 4);
    int g = lane >> 4, cc = lane & 15;
    size_t ibase = ((size_t)bh * NCA + c) * 512;
    float4 U  = *(const float4*)(init + ibase + lane * 4);
    float4 T  = *(const float4*)(init + ibase + 256 + lane * 4);
    float4 KV = *(const float4*)(kvtot + bh * 256 + lane * 4);
    float om = 1.0f - rdec;
    float geom = (om > 1e-8f) ? (1.0f - __expf(-inv_tau * (float)t0)) / om : (float)t0;
    #pragma unroll 4
    for (int s = 0; s < CHA; s++) {
        int i = t0 + s;
        geom = fmaf(geom, rdec, 1.0f);
        float4 kf = *(const float4*)&Ksh[wid][s][4 * g];
        float4 qf = *(const float4*)&Qsh[wid][s][4 * g];
        float vv = Vsh[wid][s][cc];
        float u0 = kf.x * vv, u1 = kf.y * vv, u2 = kf.z * vv, u3 = kf.w * vv;
        U.x += u0; U.y += u1; U.z += u2; U.w += u3;
        T.x = fmaf(rdec, T.x, u0); T.y = fmaf(rdec, T.y, u1);
        T.z = fmaf(rdec, T.z, u2); T.w = fmaf(rdec, T.w, u3);
        float p;
        p = qf.x * (KV.x - U.x + T.x);
        p = fmaf(qf.y, KV.y - U.y + T.y, p);
        p = fmaf(qf.z, KV.z - U.z + T.z, p);
        p = fmaf(qf.w, KV.w - U.w + T.w, p);
        p += __shfl_xor(p, 16, 64);
        p += __shfl_xor(p, 32, 64);
        float deno = fmaxf((float)(Lseq - 1 - i) + geom, 1e-6f);
        float yv = p * (0.25f / deno);
        if (lane < 16) Ysh[wid][s][lane] = yv;
    }
    float* op = out + ((size_t)(b * Lseq + t0 + row)) * Dm + h * HDm + hf;
    *(float4*)op       = *(const float4*)&Ysh[wid][row][hf];
    *(float4*)(op + 4) = *(const float4*)&Ysh[wid][row][hf + 4];
}

extern "C" void kernel_launch(void* const* d_in, const int* in_sizes, int n_in,
                              void* d_out, int out_size, void* d_ws, size_t ws_size,
                              hipStream_t stream) {
    const float* x        = (const float*)d_in[0];
    const float* ln_g     = (const float*)d_in[1];
    const float* ln_b     = (const float*)d_in[2];
    const float* mq_w     = (const float*)d_in[3];
    const float* mq_b     = (const float*)d_in[4];
    const float* fuse_w   = (const float*)d_in[5];
    const float* fuse_b   = (const float*)d_in[6];
    const float* in_proj_w= (const float*)d_in[7];
    const float* conv_w   = (const float*)d_in[8];
    const float* conv_b   = (const float*)d_in[9];
    const float* x_proj_w = (const float*)d_in[10];
    const float* dt_w     = (const float*)d_in[11];
    const float* dt_b     = (const float*)d_in[12];
    const float* A_log    = (const float*)d_in[13];
    const float* D_ssm    = (const float*)d_in[14];
    const float* out_w    = (const float*)d_in[15];
    const float* k_w      = (const float*)d_in[16];
    const float* k_b      = (const float*)d_in[17];
    const float* v_w      = (const float*)d_in[18];
    const float* v_b      = (const float*)d_in[19];
    const float* o_w      = (const float*)d_in[20];
    const float* o_b      = (const float*)d_in[21];
    const float* log_tau  = (const float*)d_in[22];
    const float* gate_w   = (const float*)d_in[23];
    const float* gate_b   = (const float*)d_in[24];
    float* outp = (float*)d_out;

    const int M = Bsz * Lseq;          // 4096
    float* ws = (float*)d_ws;
    size_t off = 0;
    float* xn    = ws + off; off += (size_t)M * Dm;
    float* xm    = ws + off; off += (size_t)M * DIm;      // in_proj first half, row-major
    float* zT    = ws + off; off += (size_t)DIm * M;      // in_proj second half, time-major
    float* xcT   = ws + off; off += (size_t)DIm * M;      // conv output, time-major
    float* dbc   = ws + off; off += (size_t)M * 144;
    float* dtmT  = ws + off; off += (size_t)DIm * M;      // dt, time-major
    float* yT    = ws + off; off += (size_t)DIm * M;
    float* xd2   = ws + off; off += (size_t)Bsz * 512 * Dm;
    float* xd4   = ws + off; off += (size_t)Bsz * 256 * Dm;
    float* xd8   = ws + off; off += (size_t)Bsz * 128 * Dm;
    float* qd2   = ws + off; off += (size_t)Bsz * 512 * Dm;
    float* qd4   = ws + off; off += (size_t)Bsz * 256 * Dm;
    float* qd8   = ws + off; off += (size_t)Bsz * 128 * Dm;
    float* qcat  = ws + off; off += (size_t)M * 4 * Dm;   // reused: q0, attn states, scan hloc/Pc
    float* qbuf  = ws + off; off += (size_t)M * Dm;       // reused (w/ kmat): Hinit
    float* kmat  = ws + off; off += (size_t)M * Dm;
    float* vmat  = ws + off; off += (size_t)M * Dm;
    float* attn  = ws + off; off += (size_t)M * Dm;
    float* cat2  = ws + off; off += (size_t)M * 2 * Dm;   // [ssm_o | ssd_o]; xc row-major aliases here
    float* xc    = cat2;    // row-major conv output, dead before cat2 is first written (post2)
    float* q0    = qcat;    // contiguous scale-1 q projection (dead after fuse_gemm)

    // 1. LayerNorm
    ln_kernel<<<M, 256, 0, stream>>>(x, ln_g, ln_b, xn);

    // 2. fused pooling (xd2/xd4/xd8 in one dispatch)
    halve3_kernel<<<(917504 + 255) / 256, 256, 0, stream>>>(xn, xd2, xd4, xd8);

    // 3. ALL K=256 projections in ONE dispatch: xm, zT, k, v, q0, qd2, qd4, qd8
    proj8<<<2016, 256, 0, stream>>>(xn, xd2, xd4, xd8, in_proj_w,
        k_w, k_b, v_w, v_b, mq_w, mq_b,
        xm, zT, kmat, vmat, q0, qd2, qd4, qd8);

    // 4. fuse GEMM with on-the-fly interpolation staging (K=1024)
    fuse_gemm<<<dim3(4, 64), 256, 0, stream>>>(q0, qd2, qd4, qd8, fuse_w, fuse_b, qbuf);

    // 5. causal conv + SiLU (xc row-major into cat2 alias + xcT time-major)
    conv_silu_kernel<<<512, 256, 0, stream>>>(xm, conv_w, conv_b, xc, xcT);

    // 6. x_proj GEMM (N=144, K=512), reads xc row-major
    gemm_bf16<<<dim3(3, 64), 256, 0, stream>>>(xc, DIm, 1, x_proj_w, DIm,
        nullptr, dbc, 144, M, 144, DIm, 0, 0, nullptr, nullptr);

    // 7. dt GEMM + softplus (K=16, fp32), time-major output
    gemm_f32<<<dim3(8, 64), 256, 0, stream>>>(dbc, 144, 1, dt_w, DTRm,
        dt_b, dtmT, M, M, DIm, DTRm, 1, 0, 1);

    // 8. linear-attention (chunk-parallel, exact); states in dead qcat (q0 dead after step 4)
    float* aloc  = qcat;
    float* ainit = qcat + (size_t)64 * NCA * 512;
    float* kvtot = qcat + (size_t)2 * 64 * NCA * 512;
    attn_p1<<<512, 256, 0, stream>>>(kmat, vmat, log_tau, aloc);
    attn_p2<<<64, 256, 0, stream>>>(aloc, log_tau, ainit, kvtot);
    attn_p3<<<512, 256, 0, stream>>>(qbuf, kmat, vmat, log_tau, ainit, kvtot, attn);

    // 9. chunk-parallel selective scan (time-major operands; qcat free after attn_p3)
    float* hloc  = qcat;
    float* Pc    = qcat + (size_t)NCH * NCHK * Ssz;
    float* Hinit = qbuf;
    scan_pass1<<<(NCH * NCHK) / 4, 256, 0, stream>>>(xcT, dtmT, dbc, A_log, hloc, Pc);
    scan_combine<<<NCH / 4, 256, 0, stream>>>(hloc, Pc, Hinit);
    scan_pass3<<<(NCH * NCHK) / 4, 256, 0, stream>>>(xcT, dtmT, zT, dbc, A_log, D_ssm, Hinit, yT);

    // 10. batched o-GEMM + out-GEMM into cat2 (one dispatch, 512 blocks)
    post2<<<512, 256, 0, stream>>>(attn, o_w, o_b, yT, out_w, cat2);

    // 11. gate GEMM (K=512) with FUSED sigmoid-gate + residual epilogue -> d_out
    gemm_bf16<<<dim3(4, 64), 256, 0, stream>>>(cat2, 2 * Dm, 1, gate_w, 2 * Dm,
        gate_b, nullptr, 0, M, Dm, 2 * Dm, 0, 0, x, outp);
}

// Round 9
// 321.548 us; speedup vs baseline: 4.7853x; 1.1352x over previous
//
#include <hip/hip_runtime.h>
#include <math.h>

#define Bsz 4
#define Lseq 1024
#define Dm 256
#define Hh 16
#define HDm 16
#define DIm 512
#define Ssz 64
#define KCm 4
#define DTRm 16
#define NCH (Bsz * DIm)      // 2048 channels
#define CHK 64               // mamba-scan chunk length
#define NCHK (Lseq / CHK)    // 16 chunks
#define CHA 16               // attention-scan chunk length
#define NCA (Lseq / CHA)     // 64 chunks

typedef __attribute__((ext_vector_type(8))) short s8v;
typedef __attribute__((ext_vector_type(4))) float f4v;

static __device__ __forceinline__ float wave_sum(float v) {
    #pragma unroll
    for (int m = 32; m >= 1; m >>= 1) v += __shfl_xor(v, m, 64);
    return v;
}

static __device__ __forceinline__ float bcast(float v, int l) {
    return __uint_as_float(__builtin_amdgcn_readlane(__float_as_uint(v), l));
}

static __device__ __forceinline__ short f2bf(float f) {
    unsigned int u = __float_as_uint(f);
    u = (u + 0x7fffu + ((u >> 16) & 1u)) >> 16;
    return (short)u;
}

static __device__ __forceinline__ s8v pack8(float4 a, float4 b) {
    s8v v;
    v[0] = f2bf(a.x); v[1] = f2bf(a.y); v[2] = f2bf(a.z); v[3] = f2bf(a.w);
    v[4] = f2bf(b.x); v[5] = f2bf(b.y); v[6] = f2bf(b.z); v[7] = f2bf(b.w);
    return v;
}

// ---------------- fused LayerNorm + 3-level pooling (8 rows/block, 2 rows/wave) ----------------
__global__ __launch_bounds__(256) void ln_pool(const float* __restrict__ x,
                                               const float* __restrict__ g,
                                               const float* __restrict__ bb,
                                               float* __restrict__ xn, float* __restrict__ xd2,
                                               float* __restrict__ xd4, float* __restrict__ xd8) {
    __shared__ float p2[4][256];
    int wid = threadIdx.x >> 6, lane = threadIdx.x & 63;
    int gr0 = blockIdx.x * 8;
    int b = gr0 >> 10, t0 = gr0 & 1023;
    float4 g4 = *(const float4*)(g + lane * 4);
    float4 b4 = *(const float4*)(bb + lane * 4);
    float4 res[2];
    #pragma unroll
    for (int rr = 0; rr < 2; rr++) {
        int row = gr0 + wid * 2 + rr;
        float4 xv = *(const float4*)(x + (size_t)row * 256 + lane * 4);
        float s = wave_sum(xv.x + xv.y + xv.z + xv.w);
        float mean = s * (1.0f / 256.0f);
        float d0 = xv.x - mean, d1 = xv.y - mean, d2 = xv.z - mean, d3 = xv.w - mean;
        float s2 = wave_sum(d0 * d0 + d1 * d1 + d2 * d2 + d3 * d3);
        float inv = rsqrtf(s2 * (1.0f / 256.0f) + 1e-5f);
        float4 r;
        r.x = d0 * inv * g4.x + b4.x; r.y = d1 * inv * g4.y + b4.y;
        r.z = d2 * inv * g4.z + b4.z; r.w = d3 * inv * g4.w + b4.w;
        *(float4*)(xn + (size_t)row * 256 + lane * 4) = r;
        res[rr] = r;
    }
    float4 a2;
    a2.x = 0.5f * (res[0].x + res[1].x); a2.y = 0.5f * (res[0].y + res[1].y);
    a2.z = 0.5f * (res[0].z + res[1].z); a2.w = 0.5f * (res[0].w + res[1].w);
    *(float4*)(xd2 + (size_t)(b * 512 + (t0 >> 1) + wid) * 256 + lane * 4) = a2;
    *(float4*)&p2[wid][lane * 4] = a2;
    __syncthreads();
    if (wid < 2) {
        float4 u = *(const float4*)&p2[2 * wid][lane * 4];
        float4 w = *(const float4*)&p2[2 * wid + 1][lane * 4];
        float4 m;
        m.x = 0.5f * (u.x + w.x); m.y = 0.5f * (u.y + w.y);
        m.z = 0.5f * (u.z + w.z); m.w = 0.5f * (u.w + w.w);
        *(float4*)(xd4 + (size_t)(b * 256 + (t0 >> 2) + wid) * 256 + lane * 4) = m;
    } else if (wid == 2) {
        float4 q0 = *(const float4*)&p2[0][lane * 4];
        float4 q1 = *(const float4*)&p2[1][lane * 4];
        float4 q2 = *(const float4*)&p2[2][lane * 4];
        float4 q3 = *(const float4*)&p2[3][lane * 4];
        float4 m;
        m.x = 0.25f * ((q0.x + q1.x) + (q2.x + q3.x));
        m.y = 0.25f * ((q0.y + q1.y) + (q2.y + q3.y));
        m.z = 0.25f * ((q0.z + q1.z) + (q2.z + q3.z));
        m.w = 0.25f * ((q0.w + q1.w) + (q2.w + q3.w));
        *(float4*)(xd8 + (size_t)(b * 128 + (t0 >> 3)) * 256 + lane * 4) = m;
    }
}

// ======= batched projection GEMM: 8 outputs off xn/xd* in ONE dispatch (K=256) =======
__global__ __launch_bounds__(256) void proj8(const float* __restrict__ xn,
                                             const float* __restrict__ xd2,
                                             const float* __restrict__ xd4,
                                             const float* __restrict__ xd8,
                                             const float* __restrict__ in_proj_w,
                                             const float* __restrict__ k_w, const float* __restrict__ k_b,
                                             const float* __restrict__ v_w, const float* __restrict__ v_b,
                                             const float* __restrict__ mq_w, const float* __restrict__ mq_b,
                                             float* __restrict__ xm, float* __restrict__ zT,
                                             float* __restrict__ kmat, float* __restrict__ vmat,
                                             float* __restrict__ q0, float* __restrict__ qd2,
                                             float* __restrict__ qd4, float* __restrict__ qd8) {
    __shared__ unsigned short As[64][40];
    __shared__ unsigned short Ws[64][40];
    int bx = blockIdx.x;
    const float* A; const float* W; const float* bias; float* C;
    int ldc, transC = 0, n0, m0;
    if (bx < 512) {
        A = xn; W = in_proj_w; bias = nullptr; C = xm; ldc = DIm;
        n0 = (bx & 7) * 64; m0 = (bx >> 3) * 64;
    } else if (bx < 1024) {
        int l = bx - 512;
        A = xn; W = in_proj_w + 131072; bias = nullptr; C = zT; ldc = Bsz * Lseq; transC = 1;
        n0 = (l & 7) * 64; m0 = (l >> 3) * 64;
    } else if (bx < 1280) {
        int l = bx - 1024;
        A = xn; W = k_w; bias = k_b; C = kmat; ldc = Dm;
        n0 = (l & 3) * 64; m0 = (l >> 2) * 64;
    } else if (bx < 1536) {
        int l = bx - 1280;
        A = xn; W = v_w; bias = v_b; C = vmat; ldc = Dm;
        n0 = (l & 3) * 64; m0 = (l >> 2) * 64;
    } else if (bx < 1792) {
        int l = bx - 1536;
        A = xn; W = mq_w; bias = mq_b; C = q0; ldc = Dm;
        n0 = (l & 3) * 64; m0 = (l >> 2) * 64;
    } else if (bx < 1920) {
        int l = bx - 1792;
        A = xd2; W = mq_w + 65536; bias = mq_b + 256; C = qd2; ldc = Dm;
        n0 = (l & 3) * 64; m0 = (l >> 2) * 64;
    } else if (bx < 1984) {
        int l = bx - 1920;
        A = xd4; W = mq_w + 131072; bias = mq_b + 512; C = qd4; ldc = Dm;
        n0 = (l & 3) * 64; m0 = (l >> 2) * 64;
    } else {
        int l = bx - 1984;
        A = xd8; W = mq_w + 196608; bias = mq_b + 768; C = qd8; ldc = Dm;
        n0 = (l & 3) * 64; m0 = (l >> 2) * 64;
    }
    int tid = threadIdx.x;
    int wave = tid >> 6, lane = tid & 63;
    int quad = lane >> 4, r = lane & 15;
    int mo = (wave >> 1) * 32, no = (wave & 1) * 32;
    f4v acc[2][2];
    #pragma unroll
    for (int i = 0; i < 2; i++)
        #pragma unroll
        for (int j = 0; j < 2; j++) acc[i][j] = (f4v){0.f, 0.f, 0.f, 0.f};
    for (int k0 = 0; k0 < 256; k0 += 32) {
        {
            int m = tid >> 2, kk = (tid & 3) * 8;
            const float* ap = A + (size_t)(m0 + m) * 256 + k0 + kk;
            *(s8v*)&As[m][kk] = pack8(*(const float4*)ap, *(const float4*)(ap + 4));
        }
        {
            int n = tid >> 2, kk = (tid & 3) * 8;
            const float* wp = W + (size_t)(n0 + n) * 256 + k0 + kk;
            *(s8v*)&Ws[n][kk] = pack8(*(const float4*)wp, *(const float4*)(wp + 4));
        }
        __syncthreads();
        s8v af[2], bf[2];
        #pragma unroll
        for (int i = 0; i < 2; i++) af[i] = *(const s8v*)&As[mo + i * 16 + r][quad * 8];
        #pragma unroll
        for (int j = 0; j < 2; j++) bf[j] = *(const s8v*)&Ws[no + j * 16 + r][quad * 8];
        #pragma unroll
        for (int i = 0; i < 2; i++)
            #pragma unroll
            for (int j = 0; j < 2; j++)
                acc[i][j] = __builtin_amdgcn_mfma_f32_16x16x32_bf16(af[i], bf[j], acc[i][j], 0, 0, 0);
        __syncthreads();
    }
    #pragma unroll
    for (int i = 0; i < 2; i++)
        #pragma unroll
        for (int j = 0; j < 2; j++)
            #pragma unroll
            for (int reg = 0; reg < 4; reg++) {
                int m = m0 + mo + i * 16 + quad * 4 + reg;
                int n = n0 + no + j * 16 + r;
                float v = acc[i][j][reg];
                if (bias) v += bias[n];
                float* cp = transC ? (C + (size_t)n * ldc + m) : (C + (size_t)m * ldc + n);
                *cp = v;
            }
}

// ======= mid2: fuse GEMM (blocks 0-255, on-the-fly interp) + conv+SiLU (blocks 256-767) =======
__global__ __launch_bounds__(256) void mid2(const float* __restrict__ q0,
                                            const float* __restrict__ qd2,
                                            const float* __restrict__ qd4,
                                            const float* __restrict__ qd8,
                                            const float* __restrict__ fuse_w,
                                            const float* __restrict__ fuse_b,
                                            float* __restrict__ qbuf,
                                            const float* __restrict__ xm,
                                            const float* __restrict__ cw,
                                            const float* __restrict__ cb,
                                            float* __restrict__ xc, float* __restrict__ xcT) {
    __shared__ __align__(16) char smem[16640];
    int bx = blockIdx.x;
    int tid = threadIdx.x;
    if (bx < 256) {
        unsigned short (*As)[40] = (unsigned short(*)[40])smem;
        unsigned short (*Ws)[40] = (unsigned short(*)[40])(smem + 5120);
        int wave = tid >> 6, lane = tid & 63;
        int quad = lane >> 4, r = lane & 15;
        int n0 = (bx & 3) * 64, m0 = (bx >> 2) * 64;
        int mo = (wave >> 1) * 32, no = (wave & 1) * 32;
        f4v acc[2][2];
        #pragma unroll
        for (int i = 0; i < 2; i++)
            #pragma unroll
            for (int j = 0; j < 2; j++) acc[i][j] = (f4v){0.f, 0.f, 0.f, 0.f};
        for (int k0 = 0; k0 < 1024; k0 += 32) {
            {
                int m = tid >> 2, kk = (tid & 3) * 8;
                int kg = k0 + kk;
                int seg = kg >> 8, dcol = kg & 255;
                int mg = m0 + m;
                s8v pv;
                if (seg == 0) {
                    const float* ap = q0 + (size_t)mg * 256 + dcol;
                    pv = pack8(*(const float4*)ap, *(const float4*)(ap + 4));
                } else {
                    int t = mg & 1023, b = mg >> 10;
                    int Lin = 512 >> (seg - 1);
                    const float* qd = (seg == 1) ? qd2 : (seg == 2) ? qd4 : qd8;
                    float pos = (t + 0.5f) * ((float)Lin / 1024.0f) - 0.5f;
                    pos = fminf(fmaxf(pos, 0.0f), (float)(Lin - 1));
                    int lo = (int)floorf(pos);
                    int hi = min(lo + 1, Lin - 1);
                    float w = pos - (float)lo;
                    const float* plo = qd + ((size_t)(b * Lin + lo)) * 256 + dcol;
                    const float* phi = qd + ((size_t)(b * Lin + hi)) * 256 + dcol;
                    float4 l0 = *(const float4*)plo, l1 = *(const float4*)(plo + 4);
                    float4 h0 = *(const float4*)phi, h1 = *(const float4*)(phi + 4);
                    float4 r0, r1;
                    r0.x = l0.x + w * (h0.x - l0.x); r0.y = l0.y + w * (h0.y - l0.y);
                    r0.z = l0.z + w * (h0.z - l0.z); r0.w = l0.w + w * (h0.w - l0.w);
                    r1.x = l1.x + w * (h1.x - l1.x); r1.y = l1.y + w * (h1.y - l1.y);
                    r1.z = l1.z + w * (h1.z - l1.z); r1.w = l1.w + w * (h1.w - l1.w);
                    pv = pack8(r0, r1);
                }
                *(s8v*)&As[m][kk] = pv;
            }
            {
                int n = tid >> 2, kk = (tid & 3) * 8;
                const float* wp = fuse_w + (size_t)(n0 + n) * 1024 + k0 + kk;
                *(s8v*)&Ws[n][kk] = pack8(*(const float4*)wp, *(const float4*)(wp + 4));
            }
            __syncthreads();
            s8v af[2], bf[2];
            #pragma unroll
            for (int i = 0; i < 2; i++) af[i] = *(const s8v*)&As[mo + i * 16 + r][quad * 8];
            #pragma unroll
            for (int j = 0; j < 2; j++) bf[j] = *(const s8v*)&Ws[no + j * 16 + r][quad * 8];
            #pragma unroll
            for (int i = 0; i < 2; i++)
                #pragma unroll
                for (int j = 0; j < 2; j++)
                    acc[i][j] = __builtin_amdgcn_mfma_f32_16x16x32_bf16(af[i], bf[j], acc[i][j], 0, 0, 0);
            __syncthreads();
        }
        #pragma unroll
        for (int i = 0; i < 2; i++)
            #pragma unroll
            for (int j = 0; j < 2; j++)
                #pragma unroll
                for (int reg = 0; reg < 4; reg++) {
                    int m = m0 + mo + i * 16 + quad * 4 + reg;
                    int n = n0 + no + j * 16 + r;
                    qbuf[(size_t)m * 256 + n] = acc[i][j][reg] + fuse_b[n];
                }
    } else {
        float (*tile)[65] = (float(*)[65])smem;
        int blk = bx - 256;
        int cblk = blk & 7;
        int tblk = (blk >> 3) & 15;
        int b = blk >> 7;
        int c0 = cblk * 64, t0 = tblk * 64;
        int cc = tid & 63;
        int tw = tid >> 6;
        int c = c0 + cc;
        float w0 = cw[c * 4 + 0], w1 = cw[c * 4 + 1], w2 = cw[c * 4 + 2], w3 = cw[c * 4 + 3];
        float bias = cb[c];
        #pragma unroll 4
        for (int i = 0; i < 16; i++) {
            int tl = tw * 16 + i;
            int t = t0 + tl;
            const float* base = xm + ((size_t)(b * Lseq + t)) * DIm + c;
            float acc = bias + base[0] * w3;
            if (t >= 3) {
                acc += base[-3 * DIm] * w0 + base[-2 * DIm] * w1 + base[-1 * DIm] * w2;
            } else {
                if (t >= 1) acc += base[-1 * DIm] * w2;
                if (t >= 2) acc += base[-2 * DIm] * w1;
            }
            float r = acc / (1.0f + __expf(-acc));
            xc[((size_t)(b * Lseq + t)) * DIm + c] = r;
            tile[tl][cc] = r;
        }
        __syncthreads();
        int tcol = tid & 63;
        int crow0 = tid >> 6;
        #pragma unroll 4
        for (int j = 0; j < 16; j++) {
            int crow = crow0 * 16 + j;
            xcT[((size_t)(c0 + crow)) * (Bsz * Lseq) + b * Lseq + t0 + tcol] = tile[tcol][crow];
        }
    }
}

// ======= xproj_ap1: x_proj GEMM (blocks 0-191) + attn pass1 (blocks 192-1215) =======
__global__ __launch_bounds__(256) void xproj_ap1(const float* __restrict__ xc,
                                                 const float* __restrict__ x_proj_w,
                                                 float* __restrict__ dbc,
                                                 const float* __restrict__ kmat,
                                                 const float* __restrict__ vmat,
                                                 const float* __restrict__ log_tau,
                                                 float* __restrict__ loc) {
    __shared__ __align__(16) char smem[10240];
    int bx = blockIdx.x;
    int tid = threadIdx.x;
    int wid = tid >> 6, lane = tid & 63;
    if (bx < 192) {
        unsigned short (*As)[40] = (unsigned short(*)[40])smem;
        unsigned short (*Ws)[40] = (unsigned short(*)[40])(smem + 5120);
        int quad = lane >> 4, r = lane & 15;
        int n0 = (bx % 3) * 64, m0 = (bx / 3) * 64;
        int mo = (wid >> 1) * 32, no = (wid & 1) * 32;
        f4v acc[2][2];
        #pragma unroll
        for (int i = 0; i < 2; i++)
            #pragma unroll
            for (int j = 0; j < 2; j++) acc[i][j] = (f4v){0.f, 0.f, 0.f, 0.f};
        for (int k0 = 0; k0 < 512; k0 += 32) {
            {
                int m = tid >> 2, kk = (tid & 3) * 8;
                const float* ap = xc + (size_t)(m0 + m) * 512 + k0 + kk;
                *(s8v*)&As[m][kk] = pack8(*(const float4*)ap, *(const float4*)(ap + 4));
            }
            {
                int n = tid >> 2, kk = (tid & 3) * 8;
                s8v pv;
                if (n0 + n < 144) {
                    const float* wp = x_proj_w + (size_t)(n0 + n) * 512 + k0 + kk;
                    pv = pack8(*(const float4*)wp, *(const float4*)(wp + 4));
                } else {
                    pv = (s8v){0, 0, 0, 0, 0, 0, 0, 0};
                }
                *(s8v*)&Ws[n][kk] = pv;
            }
            __syncthreads();
            s8v af[2], bf[2];
            #pragma unroll
            for (int i = 0; i < 2; i++) af[i] = *(const s8v*)&As[mo + i * 16 + r][quad * 8];
            #pragma unroll
            for (int j = 0; j < 2; j++) bf[j] = *(const s8v*)&Ws[no + j * 16 + r][quad * 8];
            #pragma unroll
            for (int i = 0; i < 2; i++)
                #pragma unroll
                for (int j = 0; j < 2; j++)
                    acc[i][j] = __builtin_amdgcn_mfma_f32_16x16x32_bf16(af[i], bf[j], acc[i][j], 0, 0, 0);
            __syncthreads();
        }
        #pragma unroll
        for (int i = 0; i < 2; i++)
            #pragma unroll
            for (int j = 0; j < 2; j++)
                #pragma unroll
                for (int reg = 0; reg < 4; reg++) {
                    int m = m0 + mo + i * 16 + quad * 4 + reg;
                    int n = n0 + no + j * 16 + r;
                    if (n >= 144) continue;
                    dbc[(size_t)m * 144 + n] = acc[i][j][reg];
                }
    } else {
        float (*Ksh)[CHA][20] = (float(*)[CHA][20])smem;
        float (*Vsh)[CHA][16] = (float(*)[CHA][16])(smem + 5120);
        int wv = (bx - 192) * 4 + wid;       // 0..4095
        int bh = wv >> 6, c = wv & 63;
        int b = bh >> 4, h = bh & 15;
        float inv_tau = __expf(-log_tau[h]);
        float rdec = __expf(-inv_tau);
        int t0 = c * CHA;
        int row = lane >> 2, q4 = (lane & 3) * 4;
        const float* kp = kmat + ((size_t)(b * Lseq + t0 + row)) * Dm + h * HDm + q4;
        const float* vp = vmat + ((size_t)(b * Lseq + t0 + row)) * Dm + h * HDm + q4;
        *(float4*)&Ksh[wid][row][q4] = *(const float4*)kp;
        *(float4*)&Vsh[wid][row][q4] = *(const float4*)vp;
        int g = lane >> 4, cc = lane & 15;
        float4 U = {0.f, 0.f, 0.f, 0.f}, T = {0.f, 0.f, 0.f, 0.f};
        #pragma unroll
        for (int s = 0; s < CHA; s++) {
            float4 kf = *(const float4*)&Ksh[wid][s][4 * g];
            float vv = Vsh[wid][s][cc];
            float u0 = kf.x * vv, u1 = kf.y * vv, u2 = kf.z * vv, u3 = kf.w * vv;
            U.x += u0; U.y += u1; U.z += u2; U.w += u3;
            T.x = fmaf(rdec, T.x, u0); T.y = fmaf(rdec, T.y, u1);
            T.z = fmaf(rdec, T.z, u2); T.w = fmaf(rdec, T.w, u3);
        }
        float* op = loc + ((size_t)bh * NCA + c) * 512;
        *(float4*)(op + lane * 4) = U;
        *(float4*)(op + 256 + lane * 4) = T;
    }
}

// ======= dt_ap2: dt GEMM+softplus (blocks 0-511) + attn pass2 in-place scan (blocks 512-575) =======
__global__ __launch_bounds__(256) void dt_ap2(const float* __restrict__ dbc,
                                              const float* __restrict__ dt_w,
                                              const float* __restrict__ dt_b,
                                              float* __restrict__ dtmT,
                                              float* __restrict__ loc,
                                              const float* __restrict__ log_tau,
                                              float* __restrict__ kvtot) {
    __shared__ __align__(16) char smem[9216];
    int bx = blockIdx.x;
    int tid = threadIdx.x;
    if (bx < 512) {
        float (*As)[72] = (float(*)[72])smem;
        float (*Ws)[72] = (float(*)[72])(smem + 4608);
        int m0 = (bx >> 3) * 64, n0 = (bx & 7) * 64;
        int tx = tid & 15, ty = tid >> 4;
        float acc[4][4] = {};
        {
            int ml = tid >> 2, kl = (tid & 3) * 4;
            const float4 av = *(const float4*)(dbc + (size_t)(m0 + ml) * 144 + kl);
            As[kl + 0][ml] = av.x; As[kl + 1][ml] = av.y;
            As[kl + 2][ml] = av.z; As[kl + 3][ml] = av.w;
        }
        {
            int nl = tid >> 2, kl = (tid & 3) * 4;
            float4 wv = *(const float4*)(dt_w + (size_t)(n0 + nl) * 16 + kl);
            Ws[kl + 0][nl] = wv.x; Ws[kl + 1][nl] = wv.y;
            Ws[kl + 2][nl] = wv.z; Ws[kl + 3][nl] = wv.w;
        }
        __syncthreads();
        #pragma unroll
        for (int kk = 0; kk < 16; kk++) {
            float4 av = *(const float4*)&As[kk][ty * 4];
            float4 bv = *(const float4*)&Ws[kk][tx * 4];
            float a[4] = {av.x, av.y, av.z, av.w};
            float bbv[4] = {bv.x, bv.y, bv.z, bv.w};
            #pragma unroll
            for (int im = 0; im < 4; im++)
                #pragma unroll
                for (int in = 0; in < 4; in++)
                    acc[im][in] = fmaf(a[im], bbv[in], acc[im][in]);
        }
        #pragma unroll
        for (int in = 0; in < 4; in++) {
            int n = n0 + tx * 4 + in;
            #pragma unroll
            for (int im = 0; im < 4; im++) {
                int m = m0 + ty * 4 + im;
                float v = acc[im][in] + dt_b[n];
                v = fmaxf(v, 0.0f) + log1pf(expf(-fabsf(v)));
                dtmT[(size_t)n * (Bsz * Lseq) + m] = v;
            }
        }
    } else {
        int bh = bx - 512, e = tid;
        float inv_tau = __expf(-log_tau[bh & 15]);
        float rp = __expf(-(float)CHA * inv_tau);
        float* lp = loc + (size_t)bh * NCA * 512;
        float Ua = 0.f, Ta = 0.f;
        #pragma unroll 8
        for (int c = 0; c < NCA; c++) {
            float tu = lp[c * 512 + e];
            lp[c * 512 + e] = Ua;
            Ua += tu;
            float tt = lp[c * 512 + 256 + e];
            lp[c * 512 + 256 + e] = Ta;
            Ta = fmaf(rp, Ta, tt);
        }
        kvtot[bh * 256 + e] = Ua;
    }
}

// ======= sp1_ap3: scan pass1 (blocks 0-8191) + attn pass3 (blocks 8192-9215) =======
__global__ __launch_bounds__(256) void sp1_ap3(const float* __restrict__ xcT,
                                               const float* __restrict__ dtmT,
                                               const float* __restrict__ dbc,
                                               const float* __restrict__ A_log,
                                               float* __restrict__ hloc,
                                               float* __restrict__ Pc,
                                               const float* __restrict__ q,
                                               const float* __restrict__ kmat,
                                               const float* __restrict__ vmat,
                                               const float* __restrict__ log_tau,
                                               const float* __restrict__ init,
                                               const float* __restrict__ kvtot,
                                               float* __restrict__ attn_out) {
    __shared__ __align__(16) char smem[18432];
    int bx = blockIdx.x;
    int tid = threadIdx.x;
    int wid = tid >> 6, lane = tid & 63;
    if (bx < 8192) {
        int wave = bx * 4 + wid;
        int ch = wave & (NCH - 1);
        int c  = wave >> 11;
        int b = ch >> 9, d = ch & (DIm - 1);
        float As = -__expf(A_log[d * Ssz + lane]);
        int base_m = b * Lseq + c * CHK;
        float dt_vec = dtmT[(size_t)d * (Bsz * Lseq) + base_m + lane];
        float x_vec  = xcT [(size_t)d * (Bsz * Lseq) + base_m + lane];
        float ux = dt_vec * x_vec;
        float S = dt_vec;
        #pragma unroll
        for (int m = 1; m < 64; m <<= 1) {
            float o = __shfl_up(S, m, 64);
            if (lane >= m) S += o;
        }
        float Stot = bcast(S, 63);
        const float* Bp = dbc + (size_t)base_m * 144 + DTRm + lane;
        float h0 = 0.f, h1 = 0.f, h2 = 0.f, h3 = 0.f;
        #pragma unroll 4
        for (int t = 0; t < CHK; t += 4) {
            float B0 = Bp[0], B1 = Bp[144], B2 = Bp[288], B3 = Bp[432];
            Bp += 576;
            float w0 = __expf(As * (Stot - bcast(S, t)))     * bcast(ux, t);
            float w1 = __expf(As * (Stot - bcast(S, t + 1))) * bcast(ux, t + 1);
            float w2 = __expf(As * (Stot - bcast(S, t + 2))) * bcast(ux, t + 2);
            float w3 = __expf(As * (Stot - bcast(S, t + 3))) * bcast(ux, t + 3);
            h0 = fmaf(w0, B0, h0); h1 = fmaf(w1, B1, h1);
            h2 = fmaf(w2, B2, h2); h3 = fmaf(w3, B3, h3);
        }
        size_t o = ((size_t)ch * NCHK + c) * Ssz + lane;
        hloc[o] = (h0 + h1) + (h2 + h3);
        Pc[o] = __expf(As * Stot);
    } else {
        float (*Ksh)[CHA][20] = (float(*)[CHA][20])smem;
        float (*Qsh)[CHA][20] = (float(*)[CHA][20])(smem + 5120);
        float (*Vsh)[CHA][16] = (float(*)[CHA][16])(smem + 10240);
        float (*Ysh)[CHA][16] = (float(*)[CHA][16])(smem + 14336);
        int wv = (bx - 8192) * 4 + wid;
        int bh = wv >> 6, c = wv & 63;
        int b = bh >> 4, h = bh & 15;
        float inv_tau = __expf(-log_tau[h]);
        float rdec = __expf(-inv_tau);
        int t0 = c * CHA;
        int row = lane >> 2, q4 = (lane & 3) * 4;
        const float* kp = kmat + ((size_t)(b * Lseq + t0 + row)) * Dm + h * HDm + q4;
        const float* vp = vmat + ((size_t)(b * Lseq + t0 + row)) * Dm + h * HDm + q4;
        const float* qp = q    + ((size_t)(b * Lseq + t0 + row)) * Dm + h * HDm + q4;
        *(float4*)&Ksh[wid][row][q4] = *(const float4*)kp;
        *(float4*)&Vsh[wid][row][q4] = *(const float4*)vp;
        *(float4*)&Qsh[wid][row][q4] = *(const float4*)qp;
        int g = lane >> 4, cc = lane & 15;
        size_t ibase = ((size_t)bh * NCA + c) * 512;
        float4 U  = *(const float4*)(init + ibase + lane * 4);
        float4 T  = *(const float4*)(init + ibase + 256 + lane * 4);
        float4 KV = *(const float4*)(kvtot + bh * 256 + lane * 4);
        float om = 1.0f - rdec;
        float geom = (om > 1e-8f) ? (1.0f - __expf(-inv_tau * (float)t0)) / om : (float)t0;
        #pragma unroll
        for (int s = 0; s < CHA; s++) {
            int i = t0 + s;
            geom = fmaf(geom, rdec, 1.0f);
            float4 kf = *(const float4*)&Ksh[wid][s][4 * g];
            float4 qf = *(const float4*)&Qsh[wid][s][4 * g];
            float vv = Vsh[wid][s][cc];
            float u0 = kf.x * vv, u1 = kf.y * vv, u2 = kf.z * vv, u3 = kf.w * vv;
            U.x += u0; U.y += u1; U.z += u2; U.w += u3;
            T.x = fmaf(rdec, T.x, u0); T.y = fmaf(rdec, T.y, u1);
            T.z = fmaf(rdec, T.z, u2); T.w = fmaf(rdec, T.w, u3);
            float p;
            p = qf.x * (KV.x - U.x + T.x);
            p = fmaf(qf.y, KV.y - U.y + T.y, p);
            p = fmaf(qf.z, KV.z - U.z + T.z, p);
            p = fmaf(qf.w, KV.w - U.w + T.w, p);
            p += __shfl_xor(p, 16, 64);
            p += __shfl_xor(p, 32, 64);
            float deno = fmaxf((float)(Lseq - 1 - i) + geom, 1e-6f);
            float yv = p * (0.25f / deno);
            if (lane < 16) Ysh[wid][s][lane] = yv;
        }
        float* op = attn_out + ((size_t)(b * Lseq + t0 + row)) * Dm + h * HDm + q4;
        *(float4*)op = *(const float4*)&Ysh[wid][row][q4];
    }
}

// ---------------- in-place chunk combine: hloc becomes Hinit (exclusive scan) ----------------
__global__ __launch_bounds__(256) void scan_combine(float* __restrict__ hloc,
                                                    const float* __restrict__ Pc) {
    int wave = blockIdx.x * 4 + (threadIdx.x >> 6);
    int lane = threadIdx.x & 63;
    size_t base = (size_t)wave * NCHK * Ssz + lane;
    float H = 0.0f;
    #pragma unroll
    for (int c = 0; c < NCHK; c++) {
        size_t o = base + (size_t)c * Ssz;
        float p = Pc[o];
        float hl = hloc[o];
        hloc[o] = H;
        H = fmaf(p, H, hl);
    }
}

__global__ __launch_bounds__(256) void scan_pass3(const float* __restrict__ xcT,
                                                  const float* __restrict__ dtmT,
                                                  const float* __restrict__ zT,
                                                  const float* __restrict__ dbc,
                                                  const float* __restrict__ A_log,
                                                  const float* __restrict__ D_ssm,
                                                  const float* __restrict__ Hinit,
                                                  float* __restrict__ yT) {
    __shared__ float hCs[4][16][68];
    int wid = threadIdx.x >> 6;
    int lane = threadIdx.x & 63;
    int wave = blockIdx.x * 4 + wid;
    int ch = wave & (NCH - 1);
    int c  = wave >> 11;
    int b = ch >> 9, d = ch & (DIm - 1);
    float As = -__expf(A_log[d * Ssz + lane]);
    float Dd = D_ssm[d];
    int base_m = b * Lseq + c * CHK;
    float dt_vec = dtmT[(size_t)d * (Bsz * Lseq) + base_m + lane];
    float x_vec  = xcT [(size_t)d * (Bsz * Lseq) + base_m + lane];
    float zown   = zT  [(size_t)d * (Bsz * Lseq) + base_m + lane];
    float ux = dt_vec * x_vec;
    const float* Bp = dbc + (size_t)base_m * 144 + DTRm + lane;
    const float* Cp = Bp + Ssz;
    float h = Hinit[((size_t)ch * NCHK + c) * Ssz + lane];
    float yred = 0.0f;
    int tl = lane >> 2;
    int so = (lane & 3) * 16;
    for (int tb = 0; tb < 4; tb++) {
        #pragma unroll
        for (int j = 0; j < 16; j++) {
            int t = tb * 16 + j;
            float Bt = *Bp; Bp += 144;
            float Ct = *Cp; Cp += 144;
            float dtv = bcast(dt_vec, t);
            float u   = bcast(ux, t);
            float dA = __expf(dtv * As);
            h = fmaf(dA, h, u * Bt);
            hCs[wid][j][lane] = h * Ct;
        }
        const float* bp = &hCs[wid][tl][so];
        float4 a0 = *(const float4*)(bp + 0);
        float4 a1 = *(const float4*)(bp + 4);
        float4 a2 = *(const float4*)(bp + 8);
        float4 a3 = *(const float4*)(bp + 12);
        float part = ((a0.x + a0.y) + (a0.z + a0.w)) + ((a1.x + a1.y) + (a1.z + a1.w))
                   + ((a2.x + a2.y) + (a2.z + a2.w)) + ((a3.x + a3.y) + (a3.z + a3.w));
        part += __shfl_xor(part, 1, 64);
        part += __shfl_xor(part, 2, 64);
        float got = __shfl(part, ((lane - tb * 16) << 2) & 63, 64);
        if ((lane >> 4) == tb) yred = got;
    }
    float yg = (yred + x_vec * Dd) * (zown / (1.0f + __expf(-zown)));
    yT[(size_t)d * (Bsz * Lseq) + base_m + lane] = yg;
}

// ======= batched o-GEMM + out-GEMM (one dispatch, 512 blocks) =======
__global__ __launch_bounds__(256) void post2(const float* __restrict__ attn,
                                             const float* __restrict__ o_w,
                                             const float* __restrict__ o_b,
                                             const float* __restrict__ yT,
                                             const float* __restrict__ out_w,
                                             float* __restrict__ cat2) {
    __shared__ unsigned short As[64][40];
    __shared__ unsigned short Ws[64][40];
    int bx = blockIdx.x;
    const float* A; const float* W; const float* bias; float* C;
    int lda_m, lda_k, ldw, K, n0, m0;
    if (bx < 256) {
        A = attn; lda_m = 256; lda_k = 1; W = o_w; ldw = 256; bias = o_b;
        C = cat2 + 256; K = 256;
        n0 = (bx & 3) * 64; m0 = (bx >> 2) * 64;
    } else {
        int l = bx - 256;
        A = yT; lda_m = 1; lda_k = Bsz * Lseq; W = out_w; ldw = DIm; bias = nullptr;
        C = cat2; K = DIm;
        n0 = (l & 3) * 64; m0 = (l >> 2) * 64;
    }
    int tid = threadIdx.x;
    int wave = tid >> 6, lane = tid & 63;
    int quad = lane >> 4, r = lane & 15;
    int mo = (wave >> 1) * 32, no = (wave & 1) * 32;
    f4v acc[2][2];
    #pragma unroll
    for (int i = 0; i < 2; i++)
        #pragma unroll
        for (int j = 0; j < 2; j++) acc[i][j] = (f4v){0.f, 0.f, 0.f, 0.f};
    for (int k0 = 0; k0 < K; k0 += 32) {
        if (lda_k == 1) {
            int m = tid >> 2, kk = (tid & 3) * 8;
            const float* ap = A + (size_t)(m0 + m) * lda_m + k0 + kk;
            *(s8v*)&As[m][kk] = pack8(*(const float4*)ap, *(const float4*)(ap + 4));
        } else {
            int k = tid >> 3, m8 = (tid & 7) * 8;
            const float* ap = A + (size_t)(k0 + k) * lda_k + m0 + m8;
            float4 a0 = *(const float4*)ap;
            float4 a1 = *(const float4*)(ap + 4);
            float av[8] = {a0.x, a0.y, a0.z, a0.w, a1.x, a1.y, a1.z, a1.w};
            #pragma unroll
            for (int i = 0; i < 8; i++) As[m8 + i][k] = (unsigned short)f2bf(av[i]);
        }
        {
            int n = tid >> 2, kk = (tid & 3) * 8;
            const float* wp = W + (size_t)(n0 + n) * ldw + k0 + kk;
            *(s8v*)&Ws[n][kk] = pack8(*(const float4*)wp, *(const float4*)(wp + 4));
        }
        __syncthreads();
        s8v af[2], bf[2];
        #pragma unroll
        for (int i = 0; i < 2; i++) af[i] = *(const s8v*)&As[mo + i * 16 + r][quad * 8];
        #pragma unroll
        for (int j = 0; j < 2; j++) bf[j] = *(const s8v*)&Ws[no + j * 16 + r][quad * 8];
        #pragma unroll
        for (int i = 0; i < 2; i++)
            #pragma unroll
            for (int j = 0; j < 2; j++)
                acc[i][j] = __builtin_amdgcn_mfma_f32_16x16x32_bf16(af[i], bf[j], acc[i][j], 0, 0, 0);
        __syncthreads();
    }
    #pragma unroll
    for (int i = 0; i < 2; i++)
        #pragma unroll
        for (int j = 0; j < 2; j++)
            #pragma unroll
            for (int reg = 0; reg < 4; reg++) {
                int m = m0 + mo + i * 16 + quad * 4 + reg;
                int n = n0 + no + j * 16 + r;
                float v = acc[i][j][reg];
                if (bias) v += bias[n];
                C[(size_t)m * 512 + n] = v;
            }
}

// ======= gate GEMM (K=512) with fused sigmoid-gate + residual epilogue =======
__global__ __launch_bounds__(256) void gate_gemm(const float* __restrict__ cat2,
                                                 const float* __restrict__ gate_w,
                                                 const float* __restrict__ gate_b,
                                                 const float* __restrict__ xres,
                                                 float* __restrict__ fout) {
    __shared__ unsigned short As[64][40];
    __shared__ unsigned short Ws[64][40];
    int tid = threadIdx.x;
    int wave = tid >> 6, lane = tid & 63;
    int quad = lane >> 4, r = lane & 15;
    int m0 = blockIdx.y * 64, n0 = blockIdx.x * 64;
    int mo = (wave >> 1) * 32, no = (wave & 1) * 32;
    f4v acc[2][2];
    #pragma unroll
    for (int i = 0; i < 2; i++)
        #pragma unroll
        for (int j = 0; j < 2; j++) acc[i][j] = (f4v){0.f, 0.f, 0.f, 0.f};
    for (int k0 = 0; k0 < 512; k0 += 32) {
        {
            int m = tid >> 2, kk = (tid & 3) * 8;
            const float* ap = cat2 + (size_t)(m0 + m) * 512 + k0 + kk;
            *(s8v*)&As[m][kk] = pack8(*(const float4*)ap, *(const float4*)(ap + 4));
        }
        {
            int n = tid >> 2, kk = (tid & 3) * 8;
            const float* wp = gate_w + (size_t)(n0 + n) * 512 + k0 + kk;
            *(s8v*)&Ws[n][kk] = pack8(*(const float4*)wp, *(const float4*)(wp + 4));
        }
        __syncthreads();
        s8v af[2], bf[2];
        #pragma unroll
        for (int i = 0; i < 2; i++) af[i] = *(const s8v*)&As[mo + i * 16 + r][quad * 8];
        #pragma unroll
        for (int j = 0; j < 2; j++) bf[j] = *(const s8v*)&Ws[no + j * 16 + r][quad * 8];
        #pragma unroll
        for (int i = 0; i < 2; i++)
            #pragma unroll
            for (int j = 0; j < 2; j++)
                acc[i][j] = __builtin_amdgcn_mfma_f32_16x16x32_bf16(af[i], bf[j], acc[i][j], 0, 0, 0);
        __syncthreads();
    }
    #pragma unroll
    for (int i = 0; i < 2; i++)
        #pragma unroll
        for (int j = 0; j < 2; j++)
            #pragma unroll
            for (int reg = 0; reg < 4; reg++) {
                int m = m0 + mo + i * 16 + quad * 4 + reg;
                int n = n0 + no + j * 16 + r;
                float v = acc[i][j][reg] + gate_b[n];
                float gg = 1.0f / (1.0f + __expf(-v));
                float ssm = cat2[(size_t)m * 512 + n];
                float ssd = cat2[(size_t)m * 512 + 256 + n];
                fout[(size_t)m * 256 + n] = xres[(size_t)m * 256 + n] + gg * ssm + (1.0f - gg) * ssd;
            }
}

extern "C" void kernel_launch(void* const* d_in, const int* in_sizes, int n_in,
                              void* d_out, int out_size, void* d_ws, size_t ws_size,
                              hipStream_t stream) {
    const float* x        = (const float*)d_in[0];
    const float* ln_g     = (const float*)d_in[1];
    const float* ln_b     = (const float*)d_in[2];
    const float* mq_w     = (const float*)d_in[3];
    const float* mq_b     = (const float*)d_in[4];
    const float* fuse_w   = (const float*)d_in[5];
    const float* fuse_b   = (const float*)d_in[6];
    const float* in_proj_w= (const float*)d_in[7];
    const float* conv_w   = (const float*)d_in[8];
    const float* conv_b   = (const float*)d_in[9];
    const float* x_proj_w = (const float*)d_in[10];
    const float* dt_w     = (const float*)d_in[11];
    const float* dt_b     = (const float*)d_in[12];
    const float* A_log    = (const float*)d_in[13];
    const float* D_ssm    = (const float*)d_in[14];
    const float* out_w    = (const float*)d_in[15];
    const float* k_w      = (const float*)d_in[16];
    const float* k_b      = (const float*)d_in[17];
    const float* v_w      = (const float*)d_in[18];
    const float* v_b      = (const float*)d_in[19];
    const float* o_w      = (const float*)d_in[20];
    const float* o_b      = (const float*)d_in[21];
    const float* log_tau  = (const float*)d_in[22];
    const float* gate_w   = (const float*)d_in[23];
    const float* gate_b   = (const float*)d_in[24];
    float* outp = (float*)d_out;

    const int M = Bsz * Lseq;          // 4096
    float* ws = (float*)d_ws;
    size_t off = 0;
    float* xn    = ws + off; off += (size_t)M * Dm;
    float* xm    = ws + off; off += (size_t)M * DIm;      // in_proj xm; later: attn U/T states (loc, 2M)
    float* zT    = ws + off; off += (size_t)DIm * M;
    float* xcT   = ws + off; off += (size_t)DIm * M;
    float* dbc   = ws + off; off += (size_t)M * 144;
    float* dtmT  = ws + off; off += (size_t)DIm * M;
    float* yT    = ws + off; off += (size_t)DIm * M;
    float* xd2   = ws + off; off += (size_t)Bsz * 512 * Dm;  // pooled; later: kvtot
    float* xd4   = ws + off; off += (size_t)Bsz * 256 * Dm;
    float* xd8   = ws + off; off += (size_t)Bsz * 128 * Dm;
    float* qd2   = ws + off; off += (size_t)Bsz * 512 * Dm;
    float* qd4   = ws + off; off += (size_t)Bsz * 256 * Dm;
    float* qd8   = ws + off; off += (size_t)Bsz * 128 * Dm;
    float* qcat  = ws + off; off += (size_t)M * 4 * Dm;   // q0; later: hloc (2M) + Pc (2M)
    float* qbuf  = ws + off; off += (size_t)M * Dm;
    float* kmat  = ws + off; off += (size_t)M * Dm;
    float* vmat  = ws + off; off += (size_t)M * Dm;
    float* attn  = ws + off; off += (size_t)M * Dm;
    float* cat2  = ws + off; off += (size_t)M * 2 * Dm;   // xc row-major aliases here until post2
    float* xc    = cat2;
    float* q0    = qcat;
    float* loc   = xm;                                    // attn chunk states (in-place scanned)
    float* kvtot = xd2;                                   // 16K floats
    float* hloc  = qcat;                                  // becomes Hinit in-place
    float* Pc    = qcat + (size_t)NCH * NCHK * Ssz;

    // 1. fused LayerNorm + pooling
    ln_pool<<<512, 256, 0, stream>>>(x, ln_g, ln_b, xn, xd2, xd4, xd8);

    // 2. all K=256 projections in one dispatch
    proj8<<<2016, 256, 0, stream>>>(xn, xd2, xd4, xd8, in_proj_w,
        k_w, k_b, v_w, v_b, mq_w, mq_b,
        xm, zT, kmat, vmat, q0, qd2, qd4, qd8);

    // 3. fuse GEMM + conv/SiLU in one dispatch
    mid2<<<768, 256, 0, stream>>>(q0, qd2, qd4, qd8, fuse_w, fuse_b, qbuf,
        xm, conv_w, conv_b, xc, xcT);

    // 4. x_proj GEMM + attn pass1 (kvT states into dead xm)
    xproj_ap1<<<1216, 256, 0, stream>>>(xc, x_proj_w, dbc, kmat, vmat, log_tau, loc);

    // 5. dt GEMM + attn pass2 (in-place exclusive scan of loc; totals into kvtot)
    dt_ap2<<<576, 256, 0, stream>>>(dbc, dt_w, dt_b, dtmT, loc, log_tau, kvtot);

    // 6. scan pass1 + attn pass3 (attn output done here)
    sp1_ap3<<<9216, 256, 0, stream>>>(xcT, dtmT, dbc, A_log, hloc, Pc,
        qbuf, kmat, vmat, log_tau, loc, kvtot, attn);

    // 7. in-place chunk combine (hloc -> Hinit)
    scan_combine<<<512, 256, 0, stream>>>(hloc, Pc);

    // 8. scan pass3
    scan_pass3<<<8192, 256, 0, stream>>>(xcT, dtmT, zT, dbc, A_log, D_ssm, hloc, yT);

    // 9. batched o-GEMM + out-GEMM into cat2
    post2<<<512, 256, 0, stream>>>(attn, o_w, o_b, yT, out_w, cat2);

    // 10. gate GEMM with fused sigmoid-gate + residual -> d_out
    gate_gemm<<<dim3(4, 64), 256, 0, stream>>>(cat2, gate_w, gate_b, x, outp);
}

// Round 10
// 295.316 us; speedup vs baseline: 5.2103x; 1.0888x over previous
//
#include <hip/hip_runtime.h>
#include <math.h>

#define Bsz 4
#define Lseq 1024
#define Dm 256
#define Hh 16
#define HDm 16
#define DIm 512
#define Ssz 64
#define KCm 4
#define DTRm 16
#define NCH (Bsz * DIm)
#define CHK 64
#define NCHK (Lseq / CHK)
#define CHA 16
#define NCA (Lseq / CHA)

typedef __attribute__((ext_vector_type(8))) short s8v;
typedef __attribute__((ext_vector_type(4))) short s4v;
typedef __attribute__((ext_vector_type(4))) float f4v;
typedef unsigned short u16;

static __device__ __forceinline__ float wave_sum(float v) {
    #pragma unroll
    for (int m = 32; m >= 1; m >>= 1) v += __shfl_xor(v, m, 64);
    return v;
}

static __device__ __forceinline__ float bcast(float v, int l) {
    return __uint_as_float(__builtin_amdgcn_readlane(__float_as_uint(v), l));
}

static __device__ __forceinline__ short f2bf(float f) {
    unsigned int u = __float_as_uint(f);
    u = (u + 0x7fffu + ((u >> 16) & 1u)) >> 16;
    return (short)u;
}

static __device__ __forceinline__ float bf2f(u16 u) {
    return __uint_as_float(((unsigned int)u) << 16);
}

static __device__ __forceinline__ s8v pack8(float4 a, float4 b) {
    s8v v;
    v[0] = f2bf(a.x); v[1] = f2bf(a.y); v[2] = f2bf(a.z); v[3] = f2bf(a.w);
    v[4] = f2bf(b.x); v[5] = f2bf(b.y); v[6] = f2bf(b.z); v[7] = f2bf(b.w);
    return v;
}

static __device__ __forceinline__ s4v pack4(float4 a) {
    s4v v;
    v[0] = f2bf(a.x); v[1] = f2bf(a.y); v[2] = f2bf(a.z); v[3] = f2bf(a.w);
    return v;
}

// ---- ln_pool: LayerNorm + 3-level pooling (blocks 0-511) + weight fp32->bf16 cvt (blocks 512-1155) ----
__global__ __launch_bounds__(256) void ln_pool(const float* __restrict__ x,
                                               const float* __restrict__ g,
                                               const float* __restrict__ bb,
                                               u16* __restrict__ xnb, u16* __restrict__ xd2b,
                                               u16* __restrict__ xd4b, u16* __restrict__ xd8b,
                                               const float* __restrict__ in_proj_w,
                                               const float* __restrict__ k_w,
                                               const float* __restrict__ v_w,
                                               const float* __restrict__ mq_w,
                                               const float* __restrict__ fuse_w,
                                               const float* __restrict__ x_proj_w,
                                               const float* __restrict__ out_w,
                                               const float* __restrict__ o_w,
                                               const float* __restrict__ gate_w,
                                               u16* __restrict__ wbf) {
    int bx = blockIdx.x;
    int tid = threadIdx.x;
    if (bx < 512) {
        __shared__ float p2[4][256];
        int wid = tid >> 6, lane = tid & 63;
        int gr0 = bx * 8;
        int b = gr0 >> 10, t0 = gr0 & 1023;
        float4 g4 = *(const float4*)(g + lane * 4);
        float4 b4 = *(const float4*)(bb + lane * 4);
        float4 res[2];
        #pragma unroll
        for (int rr = 0; rr < 2; rr++) {
            int row = gr0 + wid * 2 + rr;
            float4 xv = *(const float4*)(x + (size_t)row * 256 + lane * 4);
            float s = wave_sum(xv.x + xv.y + xv.z + xv.w);
            float mean = s * (1.0f / 256.0f);
            float d0 = xv.x - mean, d1 = xv.y - mean, d2 = xv.z - mean, d3 = xv.w - mean;
            float s2 = wave_sum(d0 * d0 + d1 * d1 + d2 * d2 + d3 * d3);
            float inv = rsqrtf(s2 * (1.0f / 256.0f) + 1e-5f);
            float4 r;
            r.x = d0 * inv * g4.x + b4.x; r.y = d1 * inv * g4.y + b4.y;
            r.z = d2 * inv * g4.z + b4.z; r.w = d3 * inv * g4.w + b4.w;
            *(s4v*)(xnb + (size_t)row * 256 + lane * 4) = pack4(r);
            res[rr] = r;
        }
        float4 a2;
        a2.x = 0.5f * (res[0].x + res[1].x); a2.y = 0.5f * (res[0].y + res[1].y);
        a2.z = 0.5f * (res[0].z + res[1].z); a2.w = 0.5f * (res[0].w + res[1].w);
        *(s4v*)(xd2b + (size_t)(b * 512 + (t0 >> 1) + wid) * 256 + lane * 4) = pack4(a2);
        *(float4*)&p2[wid][lane * 4] = a2;
        __syncthreads();
        if (wid < 2) {
            float4 u = *(const float4*)&p2[2 * wid][lane * 4];
            float4 w = *(const float4*)&p2[2 * wid + 1][lane * 4];
            float4 m;
            m.x = 0.5f * (u.x + w.x); m.y = 0.5f * (u.y + w.y);
            m.z = 0.5f * (u.z + w.z); m.w = 0.5f * (u.w + w.w);
            *(s4v*)(xd4b + (size_t)(b * 256 + (t0 >> 2) + wid) * 256 + lane * 4) = pack4(m);
        } else if (wid == 2) {
            float4 q0 = *(const float4*)&p2[0][lane * 4];
            float4 q1 = *(const float4*)&p2[1][lane * 4];
            float4 q2 = *(const float4*)&p2[2][lane * 4];
            float4 q3 = *(const float4*)&p2[3][lane * 4];
            float4 m;
            m.x = 0.25f * ((q0.x + q1.x) + (q2.x + q3.x));
            m.y = 0.25f * ((q0.y + q1.y) + (q2.y + q3.y));
            m.z = 0.25f * ((q0.z + q1.z) + (q2.z + q3.z));
            m.w = 0.25f * ((q0.w + q1.w) + (q2.w + q3.w));
            *(s4v*)(xd8b + (size_t)(b * 128 + (t0 >> 3)) * 256 + lane * 4) = pack4(m);
        }
    } else {
        int l = bx - 512;
        const float* src; u16* dst; int base;
        if (l < 128)      { src = in_proj_w; dst = wbf;           base = l; }
        else if (l < 160) { src = k_w;      dst = wbf + 262144;   base = l - 128; }
        else if (l < 192) { src = v_w;      dst = wbf + 327680;   base = l - 160; }
        else if (l < 320) { src = mq_w;     dst = wbf + 393216;   base = l - 192; }
        else if (l < 448) { src = fuse_w;   dst = wbf + 655360;   base = l - 320; }
        else if (l < 484) { src = x_proj_w; dst = wbf + 917504;   base = l - 448; }
        else if (l < 548) { src = out_w;    dst = wbf + 991232;   base = l - 484; }
        else if (l < 580) { src = o_w;      dst = wbf + 1122304;  base = l - 548; }
        else              { src = gate_w;   dst = wbf + 1187840;  base = l - 580; }
        int idx = base * 2048 + tid * 8;
        const float* sp = src + idx;
        *(s8v*)(dst + idx) = pack8(*(const float4*)sp, *(const float4*)(sp + 4));
    }
}

// ======= proj8: 8 K=256 projections, bf16 operands =======
__global__ __launch_bounds__(256) void proj8(const u16* __restrict__ xnb,
                                             const u16* __restrict__ xd2b,
                                             const u16* __restrict__ xd4b,
                                             const u16* __restrict__ xd8b,
                                             const u16* __restrict__ wbf,
                                             const float* __restrict__ k_b,
                                             const float* __restrict__ v_b,
                                             const float* __restrict__ mq_b,
                                             u16* __restrict__ xmb, float* __restrict__ zT,
                                             float* __restrict__ kmat, float* __restrict__ vmat,
                                             u16* __restrict__ q0b, u16* __restrict__ qd2b,
                                             u16* __restrict__ qd4b, u16* __restrict__ qd8b) {
    __shared__ u16 As[64][40];
    __shared__ u16 Ws[64][40];
    int bx = blockIdx.x;
    const u16* A; const u16* W; const float* bias;
    float* Cf = nullptr; u16* Cb = nullptr;
    int ldc, transC = 0, n0, m0;
    if (bx < 512) {
        A = xnb; W = wbf; bias = nullptr; Cb = xmb; ldc = DIm;
        n0 = (bx & 7) * 64; m0 = (bx >> 3) * 64;
    } else if (bx < 1024) {
        int l = bx - 512;
        A = xnb; W = wbf + 131072; bias = nullptr; Cf = zT; ldc = Bsz * Lseq; transC = 1;
        n0 = (l & 7) * 64; m0 = (l >> 3) * 64;
    } else if (bx < 1280) {
        int l = bx - 1024;
        A = xnb; W = wbf + 262144; bias = k_b; Cf = kmat; ldc = Dm;
        n0 = (l & 3) * 64; m0 = (l >> 2) * 64;
    } else if (bx < 1536) {
        int l = bx - 1280;
        A = xnb; W = wbf + 327680; bias = v_b; Cf = vmat; ldc = Dm;
        n0 = (l & 3) * 64; m0 = (l >> 2) * 64;
    } else if (bx < 1792) {
        int l = bx - 1536;
        A = xnb; W = wbf + 393216; bias = mq_b; Cb = q0b; ldc = Dm;
        n0 = (l & 3) * 64; m0 = (l >> 2) * 64;
    } else if (bx < 1920) {
        int l = bx - 1792;
        A = xd2b; W = wbf + 393216 + 65536; bias = mq_b + 256; Cb = qd2b; ldc = Dm;
        n0 = (l & 3) * 64; m0 = (l >> 2) * 64;
    } else if (bx < 1984) {
        int l = bx - 1920;
        A = xd4b; W = wbf + 393216 + 131072; bias = mq_b + 512; Cb = qd4b; ldc = Dm;
        n0 = (l & 3) * 64; m0 = (l >> 2) * 64;
    } else {
        int l = bx - 1984;
        A = xd8b; W = wbf + 393216 + 196608; bias = mq_b + 768; Cb = qd8b; ldc = Dm;
        n0 = (l & 3) * 64; m0 = (l >> 2) * 64;
    }
    int tid = threadIdx.x;
    int wave = tid >> 6, lane = tid & 63;
    int quad = lane >> 4, r = lane & 15;
    int mo = (wave >> 1) * 32, no = (wave & 1) * 32;
    f4v acc[2][2];
    #pragma unroll
    for (int i = 0; i < 2; i++)
        #pragma unroll
        for (int j = 0; j < 2; j++) acc[i][j] = (f4v){0.f, 0.f, 0.f, 0.f};
    for (int k0 = 0; k0 < 256; k0 += 32) {
        {
            int m = tid >> 2, kk = (tid & 3) * 8;
            *(s8v*)&As[m][kk] = *(const s8v*)(A + (size_t)(m0 + m) * 256 + k0 + kk);
        }
        {
            int n = tid >> 2, kk = (tid & 3) * 8;
            *(s8v*)&Ws[n][kk] = *(const s8v*)(W + (size_t)(n0 + n) * 256 + k0 + kk);
        }
        __syncthreads();
        s8v af[2], bf[2];
        #pragma unroll
        for (int i = 0; i < 2; i++) af[i] = *(const s8v*)&As[mo + i * 16 + r][quad * 8];
        #pragma unroll
        for (int j = 0; j < 2; j++) bf[j] = *(const s8v*)&Ws[no + j * 16 + r][quad * 8];
        #pragma unroll
        for (int i = 0; i < 2; i++)
            #pragma unroll
            for (int j = 0; j < 2; j++)
                acc[i][j] = __builtin_amdgcn_mfma_f32_16x16x32_bf16(af[i], bf[j], acc[i][j], 0, 0, 0);
        __syncthreads();
    }
    #pragma unroll
    for (int i = 0; i < 2; i++)
        #pragma unroll
        for (int j = 0; j < 2; j++)
            #pragma unroll
            for (int reg = 0; reg < 4; reg++) {
                int m = m0 + mo + i * 16 + quad * 4 + reg;
                int n = n0 + no + j * 16 + r;
                float v = acc[i][j][reg];
                if (bias) v += bias[n];
                if (Cb) Cb[(size_t)m * ldc + n] = (u16)f2bf(v);
                else {
                    float* cp = transC ? (Cf + (size_t)n * ldc + m) : (Cf + (size_t)m * ldc + n);
                    *cp = v;
                }
            }
}

// ======= mid2: fuse GEMM (blocks 0-255, on-the-fly interp, bf16) + conv+SiLU (blocks 256-767) =======
__global__ __launch_bounds__(256) void mid2(const u16* __restrict__ q0b,
                                            const u16* __restrict__ qd2b,
                                            const u16* __restrict__ qd4b,
                                            const u16* __restrict__ qd8b,
                                            const u16* __restrict__ w_fuse,
                                            const float* __restrict__ fuse_b,
                                            float* __restrict__ qbuf,
                                            const u16* __restrict__ xmb,
                                            const float* __restrict__ cw,
                                            const float* __restrict__ cb,
                                            u16* __restrict__ xcb, float* __restrict__ xcT) {
    __shared__ __align__(16) char smem[16640];
    int bx = blockIdx.x;
    int tid = threadIdx.x;
    if (bx < 256) {
        u16 (*As)[40] = (u16(*)[40])smem;
        u16 (*Ws)[40] = (u16(*)[40])(smem + 5120);
        int wave = tid >> 6, lane = tid & 63;
        int quad = lane >> 4, r = lane & 15;
        int n0 = (bx & 3) * 64, m0 = (bx >> 2) * 64;
        int mo = (wave >> 1) * 32, no = (wave & 1) * 32;
        f4v acc[2][2];
        #pragma unroll
        for (int i = 0; i < 2; i++)
            #pragma unroll
            for (int j = 0; j < 2; j++) acc[i][j] = (f4v){0.f, 0.f, 0.f, 0.f};
        for (int k0 = 0; k0 < 1024; k0 += 32) {
            {
                int m = tid >> 2, kk = (tid & 3) * 8;
                int kg = k0 + kk;
                int seg = kg >> 8, dcol = kg & 255;
                int mg = m0 + m;
                s8v pv;
                if (seg == 0) {
                    pv = *(const s8v*)(q0b + (size_t)mg * 256 + dcol);
                } else {
                    int t = mg & 1023, b = mg >> 10;
                    int Lin = 512 >> (seg - 1);
                    const u16* qd = (seg == 1) ? qd2b : (seg == 2) ? qd4b : qd8b;
                    float pos = (t + 0.5f) * ((float)Lin / 1024.0f) - 0.5f;
                    pos = fminf(fmaxf(pos, 0.0f), (float)(Lin - 1));
                    int lo = (int)floorf(pos);
                    int hi = min(lo + 1, Lin - 1);
                    float w = pos - (float)lo;
                    s8v lv = *(const s8v*)(qd + ((size_t)(b * Lin + lo)) * 256 + dcol);
                    s8v hv = *(const s8v*)(qd + ((size_t)(b * Lin + hi)) * 256 + dcol);
                    #pragma unroll
                    for (int i = 0; i < 8; i++) {
                        float lf = bf2f((u16)lv[i]), hf = bf2f((u16)hv[i]);
                        pv[i] = f2bf(lf + w * (hf - lf));
                    }
                }
                *(s8v*)&As[m][kk] = pv;
            }
            {
                int n = tid >> 2, kk = (tid & 3) * 8;
                *(s8v*)&Ws[n][kk] = *(const s8v*)(w_fuse + (size_t)(n0 + n) * 1024 + k0 + kk);
            }
            __syncthreads();
            s8v af[2], bf[2];
            #pragma unroll
            for (int i = 0; i < 2; i++) af[i] = *(const s8v*)&As[mo + i * 16 + r][quad * 8];
            #pragma unroll
            for (int j = 0; j < 2; j++) bf[j] = *(const s8v*)&Ws[no + j * 16 + r][quad * 8];
            #pragma unroll
            for (int i = 0; i < 2; i++)
                #pragma unroll
                for (int j = 0; j < 2; j++)
                    acc[i][j] = __builtin_amdgcn_mfma_f32_16x16x32_bf16(af[i], bf[j], acc[i][j], 0, 0, 0);
            __syncthreads();
        }
        #pragma unroll
        for (int i = 0; i < 2; i++)
            #pragma unroll
            for (int j = 0; j < 2; j++)
                #pragma unroll
                for (int reg = 0; reg < 4; reg++) {
                    int m = m0 + mo + i * 16 + quad * 4 + reg;
                    int n = n0 + no + j * 16 + r;
                    qbuf[(size_t)m * 256 + n] = acc[i][j][reg] + fuse_b[n];
                }
    } else {
        float (*tile)[65] = (float(*)[65])smem;
        int blk = bx - 256;
        int cblk = blk & 7;
        int tblk = (blk >> 3) & 15;
        int b = blk >> 7;
        int c0 = cblk * 64, t0 = tblk * 64;
        int cc = tid & 63;
        int tw = tid >> 6;
        int c = c0 + cc;
        float w0 = cw[c * 4 + 0], w1 = cw[c * 4 + 1], w2 = cw[c * 4 + 2], w3 = cw[c * 4 + 3];
        float bias = cb[c];
        #pragma unroll 4
        for (int i = 0; i < 16; i++) {
            int tl = tw * 16 + i;
            int t = t0 + tl;
            const u16* base = xmb + ((size_t)(b * Lseq + t)) * DIm + c;
            float acc = bias + bf2f(base[0]) * w3;
            if (t >= 3) {
                acc += bf2f(base[-3 * DIm]) * w0 + bf2f(base[-2 * DIm]) * w1 + bf2f(base[-1 * DIm]) * w2;
            } else {
                if (t >= 1) acc += bf2f(base[-1 * DIm]) * w2;
                if (t >= 2) acc += bf2f(base[-2 * DIm]) * w1;
            }
            float r = acc / (1.0f + __expf(-acc));
            xcb[((size_t)(b * Lseq + t)) * DIm + c] = (u16)f2bf(r);
            tile[tl][cc] = r;
        }
        __syncthreads();
        int tcol = tid & 63;
        int crow0 = tid >> 6;
        #pragma unroll 4
        for (int j = 0; j < 16; j++) {
            int crow = crow0 * 16 + j;
            xcT[((size_t)(c0 + crow)) * (Bsz * Lseq) + b * Lseq + t0 + tcol] = tile[tcol][crow];
        }
    }
}

// ======= xproj_ap1: x_proj GEMM (blocks 0-191, bf16) + attn pass1 (blocks 192-1215) =======
__global__ __launch_bounds__(256) void xproj_ap1(const u16* __restrict__ xcb,
                                                 const u16* __restrict__ w_xp,
                                                 float* __restrict__ dbc,
                                                 const float* __restrict__ kmat,
                                                 const float* __restrict__ vmat,
                                                 const float* __restrict__ log_tau,
                                                 float* __restrict__ loc) {
    __shared__ __align__(16) char smem[10240];
    int bx = blockIdx.x;
    int tid = threadIdx.x;
    int wid = tid >> 6, lane = tid & 63;
    if (bx < 192) {
        u16 (*As)[40] = (u16(*)[40])smem;
        u16 (*Ws)[40] = (u16(*)[40])(smem + 5120);
        int quad = lane >> 4, r = lane & 15;
        int n0 = (bx % 3) * 64, m0 = (bx / 3) * 64;
        int mo = (wid >> 1) * 32, no = (wid & 1) * 32;
        f4v acc[2][2];
        #pragma unroll
        for (int i = 0; i < 2; i++)
            #pragma unroll
            for (int j = 0; j < 2; j++) acc[i][j] = (f4v){0.f, 0.f, 0.f, 0.f};
        for (int k0 = 0; k0 < 512; k0 += 32) {
            {
                int m = tid >> 2, kk = (tid & 3) * 8;
                *(s8v*)&As[m][kk] = *(const s8v*)(xcb + (size_t)(m0 + m) * 512 + k0 + kk);
            }
            {
                int n = tid >> 2, kk = (tid & 3) * 8;
                s8v pv;
                if (n0 + n < 144) pv = *(const s8v*)(w_xp + (size_t)(n0 + n) * 512 + k0 + kk);
                else pv = (s8v){0, 0, 0, 0, 0, 0, 0, 0};
                *(s8v*)&Ws[n][kk] = pv;
            }
            __syncthreads();
            s8v af[2], bf[2];
            #pragma unroll
            for (int i = 0; i < 2; i++) af[i] = *(const s8v*)&As[mo + i * 16 + r][quad * 8];
            #pragma unroll
            for (int j = 0; j < 2; j++) bf[j] = *(const s8v*)&Ws[no + j * 16 + r][quad * 8];
            #pragma unroll
            for (int i = 0; i < 2; i++)
                #pragma unroll
                for (int j = 0; j < 2; j++)
                    acc[i][j] = __builtin_amdgcn_mfma_f32_16x16x32_bf16(af[i], bf[j], acc[i][j], 0, 0, 0);
            __syncthreads();
        }
        #pragma unroll
        for (int i = 0; i < 2; i++)
            #pragma unroll
            for (int j = 0; j < 2; j++)
                #pragma unroll
                for (int reg = 0; reg < 4; reg++) {
                    int m = m0 + mo + i * 16 + quad * 4 + reg;
                    int n = n0 + no + j * 16 + r;
                    if (n >= 144) continue;
                    dbc[(size_t)m * 144 + n] = acc[i][j][reg];
                }
    } else {
        float (*Ksh)[CHA][20] = (float(*)[CHA][20])smem;
        float (*Vsh)[CHA][16] = (float(*)[CHA][16])(smem + 5120);
        int wv = (bx - 192) * 4 + wid;
        int bh = wv >> 6, c = wv & 63;
        int b = bh >> 4, h = bh & 15;
        float inv_tau = __expf(-log_tau[h]);
        float rdec = __expf(-inv_tau);
        int t0 = c * CHA;
        int row = lane >> 2, q4 = (lane & 3) * 4;
        const float* kp = kmat + ((size_t)(b * Lseq + t0 + row)) * Dm + h * HDm + q4;
        const float* vp = vmat + ((size_t)(b * Lseq + t0 + row)) * Dm + h * HDm + q4;
        *(float4*)&Ksh[wid][row][q4] = *(const float4*)kp;
        *(float4*)&Vsh[wid][row][q4] = *(const float4*)vp;
        int g = lane >> 4, cc = lane & 15;
        float4 U = {0.f, 0.f, 0.f, 0.f}, T = {0.f, 0.f, 0.f, 0.f};
        #pragma unroll
        for (int s = 0; s < CHA; s++) {
            float4 kf = *(const float4*)&Ksh[wid][s][4 * g];
            float vv = Vsh[wid][s][cc];
            float u0 = kf.x * vv, u1 = kf.y * vv, u2 = kf.z * vv, u3 = kf.w * vv;
            U.x += u0; U.y += u1; U.z += u2; U.w += u3;
            T.x = fmaf(rdec, T.x, u0); T.y = fmaf(rdec, T.y, u1);
            T.z = fmaf(rdec, T.z, u2); T.w = fmaf(rdec, T.w, u3);
        }
        float* op = loc + ((size_t)bh * NCA + c) * 512;
        *(float4*)(op + lane * 4) = U;
        *(float4*)(op + 256 + lane * 4) = T;
    }
}

// ======= dt_ap2: dt GEMM+softplus (blocks 0-511) + attn pass2 in-place scan (blocks 512-575) =======
__global__ __launch_bounds__(256) void dt_ap2(const float* __restrict__ dbc,
                                              const float* __restrict__ dt_w,
                                              const float* __restrict__ dt_b,
                                              float* __restrict__ dtmT,
                                              float* __restrict__ loc,
                                              const float* __restrict__ log_tau,
                                              float* __restrict__ kvtot) {
    __shared__ __align__(16) char smem[9216];
    int bx = blockIdx.x;
    int tid = threadIdx.x;
    if (bx < 512) {
        float (*As)[72] = (float(*)[72])smem;
        float (*Ws)[72] = (float(*)[72])(smem + 4608);
        int m0 = (bx >> 3) * 64, n0 = (bx & 7) * 64;
        int tx = tid & 15, ty = tid >> 4;
        float acc[4][4] = {};
        {
            int ml = tid >> 2, kl = (tid & 3) * 4;
            const float4 av = *(const float4*)(dbc + (size_t)(m0 + ml) * 144 + kl);
            As[kl + 0][ml] = av.x; As[kl + 1][ml] = av.y;
            As[kl + 2][ml] = av.z; As[kl + 3][ml] = av.w;
        }
        {
            int nl = tid >> 2, kl = (tid & 3) * 4;
            float4 wv = *(const float4*)(dt_w + (size_t)(n0 + nl) * 16 + kl);
            Ws[kl + 0][nl] = wv.x; Ws[kl + 1][nl] = wv.y;
            Ws[kl + 2][nl] = wv.z; Ws[kl + 3][nl] = wv.w;
        }
        __syncthreads();
        #pragma unroll
        for (int kk = 0; kk < 16; kk++) {
            float4 av = *(const float4*)&As[kk][ty * 4];
            float4 bv = *(const float4*)&Ws[kk][tx * 4];
            float a[4] = {av.x, av.y, av.z, av.w};
            float bbv[4] = {bv.x, bv.y, bv.z, bv.w};
            #pragma unroll
            for (int im = 0; im < 4; im++)
                #pragma unroll
                for (int in = 0; in < 4; in++)
                    acc[im][in] = fmaf(a[im], bbv[in], acc[im][in]);
        }
        #pragma unroll
        for (int in = 0; in < 4; in++) {
            int n = n0 + tx * 4 + in;
            #pragma unroll
            for (int im = 0; im < 4; im++) {
                int m = m0 + ty * 4 + im;
                float v = acc[im][in] + dt_b[n];
                v = fmaxf(v, 0.0f) + log1pf(expf(-fabsf(v)));
                dtmT[(size_t)n * (Bsz * Lseq) + m] = v;
            }
        }
    } else {
        int bh = bx - 512, e = tid;
        float inv_tau = __expf(-log_tau[bh & 15]);
        float rp = __expf(-(float)CHA * inv_tau);
        float* lp = loc + (size_t)bh * NCA * 512;
        float Ua = 0.f, Ta = 0.f;
        #pragma unroll 8
        for (int c = 0; c < NCA; c++) {
            float tu = lp[c * 512 + e];
            lp[c * 512 + e] = Ua;
            Ua += tu;
            float tt = lp[c * 512 + 256 + e];
            lp[c * 512 + 256 + e] = Ta;
            Ta = fmaf(rp, Ta, tt);
        }
        kvtot[bh * 256 + e] = Ua;
    }
}

// ======= sp1_ap3: scan pass1 (blocks 0-8191) + attn pass3 (blocks 8192-9215, bf16 out) =======
__global__ __launch_bounds__(256) void sp1_ap3(const float* __restrict__ xcT,
                                               const float* __restrict__ dtmT,
                                               const float* __restrict__ dbc,
                                               const float* __restrict__ A_log,
                                               float* __restrict__ hloc,
                                               float* __restrict__ Pc,
                                               const float* __restrict__ q,
                                               const float* __restrict__ kmat,
                                               const float* __restrict__ vmat,
                                               const float* __restrict__ log_tau,
                                               const float* __restrict__ init,
                                               const float* __restrict__ kvtot,
                                               u16* __restrict__ attnb) {
    __shared__ __align__(16) char smem[18432];
    int bx = blockIdx.x;
    int tid = threadIdx.x;
    int wid = tid >> 6, lane = tid & 63;
    if (bx < 8192) {
        int wave = bx * 4 + wid;
        int ch = wave & (NCH - 1);
        int c  = wave >> 11;
        int b = ch >> 9, d = ch & (DIm - 1);
        float As = -__expf(A_log[d * Ssz + lane]);
        int base_m = b * Lseq + c * CHK;
        float dt_vec = dtmT[(size_t)d * (Bsz * Lseq) + base_m + lane];
        float x_vec  = xcT [(size_t)d * (Bsz * Lseq) + base_m + lane];
        float ux = dt_vec * x_vec;
        float S = dt_vec;
        #pragma unroll
        for (int m = 1; m < 64; m <<= 1) {
            float o = __shfl_up(S, m, 64);
            if (lane >= m) S += o;
        }
        float Stot = bcast(S, 63);
        const float* Bp = dbc + (size_t)base_m * 144 + DTRm + lane;
        float h0 = 0.f, h1 = 0.f, h2 = 0.f, h3 = 0.f;
        #pragma unroll 4
        for (int t = 0; t < CHK; t += 4) {
            float B0 = Bp[0], B1 = Bp[144], B2 = Bp[288], B3 = Bp[432];
            Bp += 576;
            float w0 = __expf(As * (Stot - bcast(S, t)))     * bcast(ux, t);
            float w1 = __expf(As * (Stot - bcast(S, t + 1))) * bcast(ux, t + 1);
            float w2 = __expf(As * (Stot - bcast(S, t + 2))) * bcast(ux, t + 2);
            float w3 = __expf(As * (Stot - bcast(S, t + 3))) * bcast(ux, t + 3);
            h0 = fmaf(w0, B0, h0); h1 = fmaf(w1, B1, h1);
            h2 = fmaf(w2, B2, h2); h3 = fmaf(w3, B3, h3);
        }
        size_t o = ((size_t)ch * NCHK + c) * Ssz + lane;
        hloc[o] = (h0 + h1) + (h2 + h3);
        Pc[o] = __expf(As * Stot);
    } else {
        float (*Ksh)[CHA][20] = (float(*)[CHA][20])smem;
        float (*Qsh)[CHA][20] = (float(*)[CHA][20])(smem + 5120);
        float (*Vsh)[CHA][16] = (float(*)[CHA][16])(smem + 10240);
        float (*Ysh)[CHA][16] = (float(*)[CHA][16])(smem + 14336);
        int wv = (bx - 8192) * 4 + wid;
        int bh = wv >> 6, c = wv & 63;
        int b = bh >> 4, h = bh & 15;
        float inv_tau = __expf(-log_tau[h]);
        float rdec = __expf(-inv_tau);
        int t0 = c * CHA;
        int row = lane >> 2, q4 = (lane & 3) * 4;
        const float* kp = kmat + ((size_t)(b * Lseq + t0 + row)) * Dm + h * HDm + q4;
        const float* vp = vmat + ((size_t)(b * Lseq + t0 + row)) * Dm + h * HDm + q4;
        const float* qp = q    + ((size_t)(b * Lseq + t0 + row)) * Dm + h * HDm + q4;
        *(float4*)&Ksh[wid][row][q4] = *(const float4*)kp;
        *(float4*)&Vsh[wid][row][q4] = *(const float4*)vp;
        *(float4*)&Qsh[wid][row][q4] = *(const float4*)qp;
        int g = lane >> 4, cc = lane & 15;
        size_t ibase = ((size_t)bh * NCA + c) * 512;
        float4 U  = *(const float4*)(init + ibase + lane * 4);
        float4 T  = *(const float4*)(init + ibase + 256 + lane * 4);
        float4 KV = *(const float4*)(kvtot + bh * 256 + lane * 4);
        float om = 1.0f - rdec;
        float geom = (om > 1e-8f) ? (1.0f - __expf(-inv_tau * (float)t0)) / om : (float)t0;
        #pragma unroll
        for (int s = 0; s < CHA; s++) {
            int i = t0 + s;
            geom = fmaf(geom, rdec, 1.0f);
            float4 kf = *(const float4*)&Ksh[wid][s][4 * g];
            float4 qf = *(const float4*)&Qsh[wid][s][4 * g];
            float vv = Vsh[wid][s][cc];
            float u0 = kf.x * vv, u1 = kf.y * vv, u2 = kf.z * vv, u3 = kf.w * vv;
            U.x += u0; U.y += u1; U.z += u2; U.w += u3;
            T.x = fmaf(rdec, T.x, u0); T.y = fmaf(rdec, T.y, u1);
            T.z = fmaf(rdec, T.z, u2); T.w = fmaf(rdec, T.w, u3);
            float p;
            p = qf.x * (KV.x - U.x + T.x);
            p = fmaf(qf.y, KV.y - U.y + T.y, p);
            p = fmaf(qf.z, KV.z - U.z + T.z, p);
            p = fmaf(qf.w, KV.w - U.w + T.w, p);
            p += __shfl_xor(p, 16, 64);
            p += __shfl_xor(p, 32, 64);
            float deno = fmaxf((float)(Lseq - 1 - i) + geom, 1e-6f);
            float yv = p * (0.25f / deno);
            if (lane < 16) Ysh[wid][s][lane] = yv;
        }
        float4 yv4 = *(const float4*)&Ysh[wid][row][q4];
        *(s4v*)(attnb + ((size_t)(b * Lseq + t0 + row)) * Dm + h * HDm + q4) = pack4(yv4);
    }
}

// ======= comb_ssd: in-place chunk combine (blocks 0-511) + ssd o-GEMM (blocks 512-767) =======
__global__ __launch_bounds__(256) void comb_ssd(float* __restrict__ hloc,
                                                const float* __restrict__ Pc,
                                                const u16* __restrict__ attnb,
                                                const u16* __restrict__ w_o,
                                                const float* __restrict__ o_b,
                                                u16* __restrict__ cat2b) {
    __shared__ u16 As[64][40];
    __shared__ u16 Ws[64][40];
    int bx = blockIdx.x;
    int tid = threadIdx.x;
    if (bx < 512) {
        int wave = bx * 4 + (tid >> 6);
        int lane = tid & 63;
        size_t base = (size_t)wave * NCHK * Ssz + lane;
        float H = 0.0f;
        #pragma unroll
        for (int c = 0; c < NCHK; c++) {
            size_t o = base + (size_t)c * Ssz;
            float p = Pc[o];
            float hl = hloc[o];
            hloc[o] = H;
            H = fmaf(p, H, hl);
        }
    } else {
        int l = bx - 512;
        int wave = tid >> 6, lane = tid & 63;
        int quad = lane >> 4, r = lane & 15;
        int n0 = (l & 3) * 64, m0 = (l >> 2) * 64;
        int mo = (wave >> 1) * 32, no = (wave & 1) * 32;
        f4v acc[2][2];
        #pragma unroll
        for (int i = 0; i < 2; i++)
            #pragma unroll
            for (int j = 0; j < 2; j++) acc[i][j] = (f4v){0.f, 0.f, 0.f, 0.f};
        for (int k0 = 0; k0 < 256; k0 += 32) {
            {
                int m = tid >> 2, kk = (tid & 3) * 8;
                *(s8v*)&As[m][kk] = *(const s8v*)(attnb + (size_t)(m0 + m) * 256 + k0 + kk);
            }
            {
                int n = tid >> 2, kk = (tid & 3) * 8;
                *(s8v*)&Ws[n][kk] = *(const s8v*)(w_o + (size_t)(n0 + n) * 256 + k0 + kk);
            }
            __syncthreads();
            s8v af[2], bf[2];
            #pragma unroll
            for (int i = 0; i < 2; i++) af[i] = *(const s8v*)&As[mo + i * 16 + r][quad * 8];
            #pragma unroll
            for (int j = 0; j < 2; j++) bf[j] = *(const s8v*)&Ws[no + j * 16 + r][quad * 8];
            #pragma unroll
            for (int i = 0; i < 2; i++)
                #pragma unroll
                for (int j = 0; j < 2; j++)
                    acc[i][j] = __builtin_amdgcn_mfma_f32_16x16x32_bf16(af[i], bf[j], acc[i][j], 0, 0, 0);
            __syncthreads();
        }
        #pragma unroll
        for (int i = 0; i < 2; i++)
            #pragma unroll
            for (int j = 0; j < 2; j++)
                #pragma unroll
                for (int reg = 0; reg < 4; reg++) {
                    int m = m0 + mo + i * 16 + quad * 4 + reg;
                    int n = n0 + no + j * 16 + r;
                    cat2b[(size_t)m * 512 + 256 + n] = (u16)f2bf(acc[i][j][reg] + o_b[n]);
                }
    }
}

__global__ __launch_bounds__(256) void scan_pass3(const float* __restrict__ xcT,
                                                  const float* __restrict__ dtmT,
                                                  const float* __restrict__ zT,
                                                  const float* __restrict__ dbc,
                                                  const float* __restrict__ A_log,
                                                  const float* __restrict__ D_ssm,
                                                  const float* __restrict__ Hinit,
                                                  u16* __restrict__ yTb) {
    __shared__ float hCs[4][16][68];
    int wid = threadIdx.x >> 6;
    int lane = threadIdx.x & 63;
    int wave = blockIdx.x * 4 + wid;
    int ch = wave & (NCH - 1);
    int c  = wave >> 11;
    int b = ch >> 9, d = ch & (DIm - 1);
    float As = -__expf(A_log[d * Ssz + lane]);
    float Dd = D_ssm[d];
    int base_m = b * Lseq + c * CHK;
    float dt_vec = dtmT[(size_t)d * (Bsz * Lseq) + base_m + lane];
    float x_vec  = xcT [(size_t)d * (Bsz * Lseq) + base_m + lane];
    float zown   = zT  [(size_t)d * (Bsz * Lseq) + base_m + lane];
    float ux = dt_vec * x_vec;
    const float* Bp = dbc + (size_t)base_m * 144 + DTRm + lane;
    const float* Cp = Bp + Ssz;
    float h = Hinit[((size_t)ch * NCHK + c) * Ssz + lane];
    float yred = 0.0f;
    int tl = lane >> 2;
    int so = (lane & 3) * 16;
    for (int tb = 0; tb < 4; tb++) {
        #pragma unroll
        for (int j = 0; j < 16; j++) {
            int t = tb * 16 + j;
            float Bt = *Bp; Bp += 144;
            float Ct = *Cp; Cp += 144;
            float dtv = bcast(dt_vec, t);
            float u   = bcast(ux, t);
            float dA = __expf(dtv * As);
            h = fmaf(dA, h, u * Bt);
            hCs[wid][j][lane] = h * Ct;
        }
        const float* bp = &hCs[wid][tl][so];
        float4 a0 = *(const float4*)(bp + 0);
        float4 a1 = *(const float4*)(bp + 4);
        float4 a2 = *(const float4*)(bp + 8);
        float4 a3 = *(const float4*)(bp + 12);
        float part = ((a0.x + a0.y) + (a0.z + a0.w)) + ((a1.x + a1.y) + (a1.z + a1.w))
                   + ((a2.x + a2.y) + (a2.z + a2.w)) + ((a3.x + a3.y) + (a3.z + a3.w));
        part += __shfl_xor(part, 1, 64);
        part += __shfl_xor(part, 2, 64);
        float got = __shfl(part, ((lane - tb * 16) << 2) & 63, 64);
        if ((lane >> 4) == tb) yred = got;
    }
    float yg = (yred + x_vec * Dd) * (zown / (1.0f + __expf(-zown)));
    yTb[(size_t)d * (Bsz * Lseq) + base_m + lane] = (u16)f2bf(yg);
}

// ======= outg: out-GEMM yT^T @ out_w^T -> cat2 ssm half (256 blocks) =======
__global__ __launch_bounds__(256) void outg(const u16* __restrict__ yTb,
                                            const u16* __restrict__ w_out,
                                            u16* __restrict__ cat2b) {
    __shared__ u16 As[64][40];
    __shared__ u16 Ws[64][40];
    int bx = blockIdx.x;
    int tid = threadIdx.x;
    int wave = tid >> 6, lane = tid & 63;
    int quad = lane >> 4, r = lane & 15;
    int n0 = (bx & 3) * 64, m0 = (bx >> 2) * 64;
    int mo = (wave >> 1) * 32, no = (wave & 1) * 32;
    f4v acc[2][2];
    #pragma unroll
    for (int i = 0; i < 2; i++)
        #pragma unroll
        for (int j = 0; j < 2; j++) acc[i][j] = (f4v){0.f, 0.f, 0.f, 0.f};
    for (int k0 = 0; k0 < 512; k0 += 32) {
        {
            int k = tid >> 3, m8 = (tid & 7) * 8;
            s8v av = *(const s8v*)(yTb + (size_t)(k0 + k) * (Bsz * Lseq) + m0 + m8);
            #pragma unroll
            for (int i = 0; i < 8; i++) As[m8 + i][k] = (u16)av[i];
        }
        {
            int n = tid >> 2, kk = (tid & 3) * 8;
            *(s8v*)&Ws[n][kk] = *(const s8v*)(w_out + (size_t)(n0 + n) * 512 + k0 + kk);
        }
        __syncthreads();
        s8v af[2], bf[2];
        #pragma unroll
        for (int i = 0; i < 2; i++) af[i] = *(const s8v*)&As[mo + i * 16 + r][quad * 8];
        #pragma unroll
        for (int j = 0; j < 2; j++) bf[j] = *(const s8v*)&Ws[no + j * 16 + r][quad * 8];
        #pragma unroll
        for (int i = 0; i < 2; i++)
            #pragma unroll
            for (int j = 0; j < 2; j++)
                acc[i][j] = __builtin_amdgcn_mfma_f32_16x16x32_bf16(af[i], bf[j], acc[i][j], 0, 0, 0);
        __syncthreads();
    }
    #pragma unroll
    for (int i = 0; i < 2; i++)
        #pragma unroll
        for (int j = 0; j < 2; j++)
            #pragma unroll
            for (int reg = 0; reg < 4; reg++) {
                int m = m0 + mo + i * 16 + quad * 4 + reg;
                int n = n0 + no + j * 16 + r;
                cat2b[(size_t)m * 512 + n] = (u16)f2bf(acc[i][j][reg]);
            }
}

// ======= gate GEMM (K=512, bf16) with fused sigmoid-gate + residual epilogue =======
__global__ __launch_bounds__(256) void gate_gemm(const u16* __restrict__ cat2b,
                                                 const u16* __restrict__ w_gate,
                                                 const float* __restrict__ gate_b,
                                                 const float* __restrict__ xres,
                                                 float* __restrict__ fout) {
    __shared__ u16 As[64][40];
    __shared__ u16 Ws[64][40];
    int tid = threadIdx.x;
    int wave = tid >> 6, lane = tid & 63;
    int quad = lane >> 4, r = lane & 15;
    int m0 = blockIdx.y * 64, n0 = blockIdx.x * 64;
    int mo = (wave >> 1) * 32, no = (wave & 1) * 32;
    f4v acc[2][2];
    #pragma unroll
    for (int i = 0; i < 2; i++)
        #pragma unroll
        for (int j = 0; j < 2; j++) acc[i][j] = (f4v){0.f, 0.f, 0.f, 0.f};
    for (int k0 = 0; k0 < 512; k0 += 32) {
        {
            int m = tid >> 2, kk = (tid & 3) * 8;
            *(s8v*)&As[m][kk] = *(const s8v*)(cat2b + (size_t)(m0 + m) * 512 + k0 + kk);
        }
        {
            int n = tid >> 2, kk = (tid & 3) * 8;
            *(s8v*)&Ws[n][kk] = *(const s8v*)(w_gate + (size_t)(n0 + n) * 512 + k0 + kk);
        }
        __syncthreads();
        s8v af[2], bf[2];
        #pragma unroll
        for (int i = 0; i < 2; i++) af[i] = *(const s8v*)&As[mo + i * 16 + r][quad * 8];
        #pragma unroll
        for (int j = 0; j < 2; j++) bf[j] = *(const s8v*)&Ws[no + j * 16 + r][quad * 8];
        #pragma unroll
        for (int i = 0; i < 2; i++)
            #pragma unroll
            for (int j = 0; j < 2; j++)
                acc[i][j] = __builtin_amdgcn_mfma_f32_16x16x32_bf16(af[i], bf[j], acc[i][j], 0, 0, 0);
        __syncthreads();
    }
    #pragma unroll
    for (int i = 0; i < 2; i++)
        #pragma unroll
        for (int j = 0; j < 2; j++)
            #pragma unroll
            for (int reg = 0; reg < 4; reg++) {
                int m = m0 + mo + i * 16 + quad * 4 + reg;
                int n = n0 + no + j * 16 + r;
                float v = acc[i][j][reg] + gate_b[n];
                float gg = 1.0f / (1.0f + __expf(-v));
                float ssm = bf2f(cat2b[(size_t)m * 512 + n]);
                float ssd = bf2f(cat2b[(size_t)m * 512 + 256 + n]);
                fout[(size_t)m * 256 + n] = xres[(size_t)m * 256 + n] + gg * ssm + (1.0f - gg) * ssd;
            }
}

extern "C" void kernel_launch(void* const* d_in, const int* in_sizes, int n_in,
                              void* d_out, int out_size, void* d_ws, size_t ws_size,
                              hipStream_t stream) {
    const float* x        = (const float*)d_in[0];
    const float* ln_g     = (const float*)d_in[1];
    const float* ln_b     = (const float*)d_in[2];
    const float* mq_w     = (const float*)d_in[3];
    const float* mq_b     = (const float*)d_in[4];
    const float* fuse_w   = (const float*)d_in[5];
    const float* fuse_b   = (const float*)d_in[6];
    const float* in_proj_w= (const float*)d_in[7];
    const float* conv_w   = (const float*)d_in[8];
    const float* conv_b   = (const float*)d_in[9];
    const float* x_proj_w = (const float*)d_in[10];
    const float* dt_w     = (const float*)d_in[11];
    const float* dt_b     = (const float*)d_in[12];
    const float* A_log    = (const float*)d_in[13];
    const float* D_ssm    = (const float*)d_in[14];
    const float* out_w    = (const float*)d_in[15];
    const float* k_w      = (const float*)d_in[16];
    const float* k_b      = (const float*)d_in[17];
    const float* v_w      = (const float*)d_in[18];
    const float* v_b      = (const float*)d_in[19];
    const float* o_w      = (const float*)d_in[20];
    const float* o_b      = (const float*)d_in[21];
    const float* log_tau  = (const float*)d_in[22];
    const float* gate_w   = (const float*)d_in[23];
    const float* gate_b   = (const float*)d_in[24];
    float* outp = (float*)d_out;

    const int M = Bsz * Lseq;
    float* ws = (float*)d_ws;
    size_t off = 0;
    float* zT    = ws + off; off += (size_t)DIm * M;
    float* xcT   = ws + off; off += (size_t)DIm * M;
    float* dtmT  = ws + off; off += (size_t)DIm * M;
    float* dbc   = ws + off; off += (size_t)M * 144;
    float* qbuf  = ws + off; off += (size_t)M * Dm;
    float* kmat  = ws + off; off += (size_t)M * Dm;
    float* vmat  = ws + off; off += (size_t)M * Dm;
    float* loc   = ws + off; off += (size_t)64 * NCA * 512;
    float* hloc  = ws + off; off += (size_t)NCH * NCHK * Ssz;
    float* Pc    = ws + off; off += (size_t)NCH * NCHK * Ssz;
    float* kvtot = ws + off; off += (size_t)64 * 256;
    u16* ub = (u16*)(ws + off);
    size_t uo = 0;
    u16* xnb  = ub + uo; uo += (size_t)M * Dm;
    u16* xmb  = ub + uo; uo += (size_t)M * DIm;
    u16* xd2b = ub + uo; uo += (size_t)2048 * Dm;
    u16* xd4b = ub + uo; uo += (size_t)1024 * Dm;
    u16* xd8b = ub + uo; uo += (size_t)512 * Dm;
    u16* q0b  = ub + uo; uo += (size_t)M * Dm;
    u16* qd2b = ub + uo; uo += (size_t)2048 * Dm;
    u16* qd4b = ub + uo; uo += (size_t)1024 * Dm;
    u16* qd8b = ub + uo; uo += (size_t)512 * Dm;
    u16* attnb= ub + uo; uo += (size_t)M * Dm;
    u16* cat2b= ub + uo; uo += (size_t)M * 2 * Dm;
    u16* yTb  = ub + uo; uo += (size_t)DIm * M;
    u16* wbf  = ub + uo; uo += 1318912;
    u16* xcb  = cat2b;   // alias: conv's row-major bf16 output, dead before comb_ssd writes cat2b

    // 1. LN + pooling + weight conversion (one dispatch)
    ln_pool<<<1156, 256, 0, stream>>>(x, ln_g, ln_b, xnb, xd2b, xd4b, xd8b,
        in_proj_w, k_w, v_w, mq_w, fuse_w, x_proj_w, out_w, o_w, gate_w, wbf);

    // 2. all K=256 projections (bf16)
    proj8<<<2016, 256, 0, stream>>>(xnb, xd2b, xd4b, xd8b, wbf,
        k_b, v_b, mq_b, xmb, zT, kmat, vmat, q0b, qd2b, qd4b, qd8b);

    // 3. fuse GEMM + conv/SiLU
    mid2<<<768, 256, 0, stream>>>(q0b, qd2b, qd4b, qd8b, wbf + 655360, fuse_b, qbuf,
        xmb, conv_w, conv_b, xcb, xcT);

    // 4. x_proj GEMM + attn pass1
    xproj_ap1<<<1216, 256, 0, stream>>>(xcb, wbf + 917504, dbc, kmat, vmat, log_tau, loc);

    // 5. dt GEMM + attn pass2 (in-place)
    dt_ap2<<<576, 256, 0, stream>>>(dbc, dt_w, dt_b, dtmT, loc, log_tau, kvtot);

    // 6. scan pass1 + attn pass3
    sp1_ap3<<<9216, 256, 0, stream>>>(xcT, dtmT, dbc, A_log, hloc, Pc,
        qbuf, kmat, vmat, log_tau, loc, kvtot, attnb);

    // 7. chunk combine (in-place) + ssd o-GEMM (overlapped)
    comb_ssd<<<768, 256, 0, stream>>>(hloc, Pc, attnb, wbf + 1122304, o_b, cat2b);

    // 8. scan pass3 (yT as bf16)
    scan_pass3<<<8192, 256, 0, stream>>>(xcT, dtmT, zT, dbc, A_log, D_ssm, hloc, yTb);

    // 9. out-GEMM -> cat2 ssm half
    outg<<<256, 256, 0, stream>>>(yTb, wbf + 991232, cat2b);

    // 10. gate GEMM with fused sigmoid-gate + residual -> d_out
    gate_gemm<<<dim3(4, 64), 256, 0, stream>>>(cat2b, wbf + 1187840, gate_b, x, outp);
}